// Round 18
// baseline (680.046 us; speedup 1.0000x reference)
//
#include <hip/hip_runtime.h>
#include <cstddef>
#include <cstdint>

typedef unsigned int uint;
typedef unsigned short ushort;
typedef __attribute__((ext_vector_type(4))) float f32x4;
typedef __attribute__((ext_vector_type(8))) short short8;

// ---------- bf16 helpers (storage = ushort) ----------
__device__ __forceinline__ ushort f2b(float v) {
  uint x = __float_as_uint(v);
  return (ushort)((x + 0x7fffu + ((x >> 16) & 1u)) >> 16);  // RNE
}
__device__ __forceinline__ float b2f(ushort u) { return __uint_as_float(((uint)u) << 16); }
__device__ __forceinline__ float b2f_lo(uint u) { return __uint_as_float(u << 16); }
__device__ __forceinline__ float b2f_hi(uint u) { return __uint_as_float(u & 0xffff0000u); }
__device__ __forceinline__ uint pk2(float lo, float hi) {
  return (uint)f2b(lo) | ((uint)f2b(hi) << 16);
}
__device__ __forceinline__ uint pkadd(uint a, uint b) {
  return pk2(b2f_lo(a) + b2f_lo(b), b2f_hi(a) + b2f_hi(b));
}

__device__ __forceinline__ int lowerb(const int* __restrict__ ids, int M, int v) {
  int lo = 0, hi = M;
  while (lo < hi) { int mid = (lo + hi) >> 1; if (ids[mid] < v) lo = mid + 1; else hi = mid; }
  return lo;
}

// one fill to rule them all: zeroes a contiguous 16B-aligned region
__global__ void fillz16(uint4* p, int n16) {
  int i = blockIdx.x * 256 + threadIdx.x;
  if (i < n16) p[i] = make_uint4(0, 0, 0, 0);
}

// ---------- CSR build, P and R merged per phase ----------
__global__ void hist_dst2(const int* __restrict__ dstP, int* __restrict__ cntP,
                          const int* __restrict__ dstR, int* __restrict__ cntR,
                          int E, int EB) {
  int b = blockIdx.x;
  const int* dst; int* cnt;
  if (b < EB) { dst = dstP; cnt = cntP; } else { dst = dstR; cnt = cntR; b -= EB; }
  int e = b * 256 + threadIdx.x;
  if (e < E) atomicAdd(&cnt[dst[e]], 1);
}

__global__ void scan_local2(const int* __restrict__ cntP, int* __restrict__ rowP, int* __restrict__ bsP,
                            const int* __restrict__ cntR, int* __restrict__ rowR, int* __restrict__ bsR,
                            int N, int NB) {
  __shared__ int tmp[256];
  int b = blockIdx.x;
  const int* cnt; int* rowptr; int* bs;
  if (b < NB) { cnt = cntP; rowptr = rowP; bs = bsP; }
  else        { cnt = cntR; rowptr = rowR; bs = bsR; b -= NB; }
  int t = threadIdx.x;
  int i = b * 256 + t;
  int v = (i < N) ? cnt[i] : 0;
  tmp[t] = v;
  __syncthreads();
  for (int ofs = 1; ofs < 256; ofs <<= 1) {
    int u = (t >= ofs) ? tmp[t - ofs] : 0;
    __syncthreads();
    tmp[t] += u;
    __syncthreads();
  }
  if (i < N) rowptr[i] = tmp[t] - v;          // exclusive
  if (t == 255) bs[b] = tmp[255];
}

__global__ void scan_block2(int* __restrict__ bsP, int* __restrict__ bsR, int n) {
  __shared__ int tmp[256];
  int* bs = (blockIdx.x == 0) ? bsP : bsR;
  int t = threadIdx.x;
  int v = (t < n) ? bs[t] : 0;
  tmp[t] = v;
  __syncthreads();
  for (int ofs = 1; ofs < 256; ofs <<= 1) {
    int u = (t >= ofs) ? tmp[t - ofs] : 0;
    __syncthreads();
    tmp[t] += u;
    __syncthreads();
  }
  if (t < n) bs[t] = tmp[t] - v;              // exclusive
}

__global__ void scan_add2(int* __restrict__ rowP, int* __restrict__ curP, const int* __restrict__ bsP,
                          int* __restrict__ rowR, int* __restrict__ curR, const int* __restrict__ bsR,
                          int N, int E, int NB) {
  int b = blockIdx.x;
  int* rowptr; int* cursor; const int* bs;
  if (b < NB) { rowptr = rowP; cursor = curP; bs = bsP; }
  else        { rowptr = rowR; cursor = curR; bs = bsR; b -= NB; }
  int i = b * 256 + threadIdx.x;
  if (i < N) {
    int v = rowptr[i] + bs[b];
    rowptr[i] = v;
    cursor[i] = v;
  }
  if (i == 0) rowptr[N] = E;
}

__global__ void scatter_idx2(
    const int* __restrict__ dstP, const int* __restrict__ srcP, int* __restrict__ curP,
    int* __restrict__ epP, int* __restrict__ ivP, int* __restrict__ spP, int* __restrict__ dpP,
    const int* __restrict__ dstR, const int* __restrict__ srcR, int* __restrict__ curR,
    int* __restrict__ epR, int* __restrict__ ivR, int* __restrict__ spR, int* __restrict__ dpR,
    int E, int EB) {
  int b = blockIdx.x;
  const int *dst, *src; int *cur, *ep, *iv, *sp, *dp;
  if (b < EB) { dst = dstP; src = srcP; cur = curP; ep = epP; iv = ivP; sp = spP; dp = dpP; }
  else { dst = dstR; src = srcR; cur = curR; ep = epR; iv = ivR; sp = spR; dp = dpR; b -= EB; }
  int e = b * 256 + threadIdx.x;
  if (e < E) {
    int d = dst[e];
    int p = atomicAdd(&cur[d], 1);
    ep[p] = e;
    iv[e] = p;
    sp[p] = src[e];
    dp[p] = d;
  }
}

// ---------- prep: 4x W[128][128] fp32 -> transposed, bf16, XOR-swizzled ----------
__global__ void prep_w4(const float* __restrict__ W0, const float* __restrict__ W1,
                        const float* __restrict__ W2, const float* __restrict__ W3,
                        ushort* __restrict__ T0, ushort* __restrict__ T1,
                        ushort* __restrict__ T2, ushort* __restrict__ T3) {
  const float* W = (blockIdx.x == 0) ? W0 : (blockIdx.x == 1) ? W1 : (blockIdx.x == 2) ? W2 : W3;
  ushort* T      = (blockIdx.x == 0) ? T0 : (blockIdx.x == 1) ? T1 : (blockIdx.x == 2) ? T2 : T3;
  int t = threadIdx.x;        // 256 threads
  int n = t >> 1;
  int k0 = (t & 1) * 64;
  uint sw = (uint)(n & 7) << 3;
  for (int kk = 0; kk < 64; ++kk) {
    int k = k0 + kk;
    T[n * 128 + (k ^ sw)] = f2b(W[k * 128 + n]);
  }
}

// ---------- per-graph counts, node+edge merged ----------
__global__ void seg_cnt2(const int* __restrict__ nid, int N, int* __restrict__ cn,
                         const int* __restrict__ eid, int E, int* __restrict__ ce,
                         int G, int GB1) {
  int b = blockIdx.x;
  if (b < GB1) {
    int g = b * 256 + threadIdx.x;
    if (g < G) cn[g] = lowerb(nid, N, g + 1) - lowerb(nid, N, g);
  } else {
    int g = (b - GB1) * 256 + threadIdx.x;
    if (g < G) ce[g] = lowerb(eid, E, g + 1) - lowerb(eid, E, g);
  }
}

// ---------- fused triple GEMM (node linears): stage A once, 3 weights ----------
__global__ __launch_bounds__(256) void gemm3_k128(
    const ushort* __restrict__ X,
    const ushort* __restrict__ Wt0, const float* __restrict__ b0, ushort* __restrict__ Y0, int ldy0,
    const ushort* __restrict__ Wt1, const float* __restrict__ b1, ushort* __restrict__ Y1, int ldy1,
    const ushort* __restrict__ Wt2, const float* __restrict__ b2, ushort* __restrict__ Y2, int ldy2,
    int M) {
  __shared__ ushort As[128 * 128];
  int t = threadIdx.x;
  int row0 = blockIdx.x * 128;

  { // stage A: linear bf16 copy, swizzled store
    int r = t >> 1;
    int k0h = (t & 1) * 64;
    int grow = row0 + r;
    uint sw = (uint)(r & 7) << 3;
    if (grow < M) {
      const ushort* xr = X + (size_t)grow * 128;
#pragma unroll
      for (int c = 0; c < 8; ++c) {
        int k0 = k0h + c * 8;
        *(uint4*)(As + r * 128 + (k0 ^ sw)) = *(const uint4*)(xr + k0);
      }
    } else {
      uint4 z = make_uint4(0, 0, 0, 0);
#pragma unroll
      for (int c = 0; c < 8; ++c) {
        int k0 = k0h + c * 8;
        *(uint4*)(As + r * 128 + (k0 ^ sw)) = z;
      }
    }
  }
  __syncthreads();

  int lane = t & 63;
  int wid = t >> 6;
  int wr = wid >> 1, wc = wid & 1;
  uint swl = (uint)(lane & 7) << 3;

#pragma unroll
  for (int w = 0; w < 3; ++w) {
    const ushort* Wt = (w == 0) ? Wt0 : (w == 1) ? Wt1 : Wt2;
    const float* bb  = (w == 0) ? b0  : (w == 1) ? b1  : b2;
    ushort* Y        = (w == 0) ? Y0  : (w == 1) ? Y1  : Y2;
    int ldy          = (w == 0) ? ldy0 : (w == 1) ? ldy1 : ldy2;

    f32x4 acc[4][4];
#pragma unroll
    for (int n4 = 0; n4 < 4; ++n4) {
      float bv = bb[wc * 64 + n4 * 16 + (lane & 15)];
#pragma unroll
      for (int m4 = 0; m4 < 4; ++m4) acc[m4][n4] = (f32x4){bv, bv, bv, bv};
    }
#pragma unroll
    for (int kk = 0; kk < 4; ++kk) {
      int kidx = kk * 32 + 8 * (lane >> 4);
      short8 af[4], bfr[4];
#pragma unroll
      for (int m4 = 0; m4 < 4; ++m4) {
        int rm = wr * 64 + m4 * 16 + (lane & 15);
        af[m4] = *(const short8*)(As + rm * 128 + (kidx ^ swl));
      }
#pragma unroll
      for (int n4 = 0; n4 < 4; ++n4) {
        int cn = wc * 64 + n4 * 16 + (lane & 15);
        bfr[n4] = *(const short8*)(Wt + cn * 128 + (kidx ^ swl));   // direct from L2
      }
#pragma unroll
      for (int m4 = 0; m4 < 4; ++m4)
#pragma unroll
        for (int n4 = 0; n4 < 4; ++n4)
          acc[m4][n4] = __builtin_amdgcn_mfma_f32_16x16x32_bf16(af[m4], bfr[n4], acc[m4][n4], 0, 0, 0);
    }
    int coln = wc * 64 + (lane & 15);
#pragma unroll
    for (int m4 = 0; m4 < 4; ++m4) {
      int rb = row0 + wr * 64 + m4 * 16 + ((lane >> 4) << 2);
#pragma unroll
      for (int n4 = 0; n4 < 4; ++n4) {
        int cc = coln + n4 * 16;
#pragma unroll
        for (int i = 0; i < 4; ++i)
          if (rb + i < M) Y[(size_t)(rb + i) * ldy + cc] = f2b(acc[m4][n4][i]);
      }
    }
  }
}

// ---------- fused edge GEMM + edge-stage (egat2), LDS time-shared ----------
static constexpr int NST = 132;
__global__ __launch_bounds__(256) void gemm_edge_fused(
    ushort* ebp, const ushort* __restrict__ Wt, const float* __restrict__ b,
    const ushort* __restrict__ f_nin, const ushort* __restrict__ f_nj,
    const int* __restrict__ src_perm, const int* __restrict__ dst_perm,
    const float* __restrict__ attn, float* __restrict__ ex, int E) {
  __shared__ ushort Buf[64 * NST];   // 16.9 KB, As then NN
  int t = threadIdx.x;
  int row0 = blockIdx.x * 64;
  int r = t >> 2, q = t & 3;
  int grow_st = row0 + r;
  uint sw = (uint)(r & 7) << 3;

  { // phase A: stage As (swizzled, stride 128)
    if (grow_st < E) {
      const ushort* xr = ebp + (size_t)grow_st * 128;
#pragma unroll
      for (int c = 0; c < 4; ++c) {
        int k0 = q * 32 + c * 8;
        *(uint4*)(Buf + r * 128 + (k0 ^ sw)) = *(const uint4*)(xr + k0);
      }
    } else {
      uint4 z = make_uint4(0, 0, 0, 0);
#pragma unroll
      for (int c = 0; c < 4; ++c) {
        int k0 = q * 32 + c * 8;
        *(uint4*)(Buf + r * 128 + (k0 ^ sw)) = z;
      }
    }
  }
  __syncthreads();

  int lane = t & 63;
  int wid = t >> 6;
  int wr = wid >> 1, wc = wid & 1;     // 2x2 waves of 32 rows x 64 cols
  uint swl = (uint)(lane & 7) << 3;

  f32x4 acc[2][4];
#pragma unroll
  for (int n4 = 0; n4 < 4; ++n4) {
    float bv = b[wc * 64 + n4 * 16 + (lane & 15)];
#pragma unroll
    for (int m4 = 0; m4 < 2; ++m4) acc[m4][n4] = (f32x4){bv, bv, bv, bv};
  }
#pragma unroll
  for (int kk = 0; kk < 4; ++kk) {
    int kidx = kk * 32 + 8 * (lane >> 4);
    short8 af[2], bfr[4];
#pragma unroll
    for (int m4 = 0; m4 < 2; ++m4) {
      int rm = wr * 32 + m4 * 16 + (lane & 15);
      af[m4] = *(const short8*)(Buf + rm * 128 + (kidx ^ swl));
    }
#pragma unroll
    for (int n4 = 0; n4 < 4; ++n4) {
      int cn = wc * 64 + n4 * 16 + (lane & 15);
      bfr[n4] = *(const short8*)(Wt + cn * 128 + (kidx ^ swl));   // direct from L2
    }
#pragma unroll
    for (int m4 = 0; m4 < 2; ++m4)
#pragma unroll
      for (int n4 = 0; n4 < 4; ++n4)
        acc[m4][n4] = __builtin_amdgcn_mfma_f32_16x16x32_bf16(af[m4], bfr[n4], acc[m4][n4], 0, 0, 0);
  }
  __syncthreads();                      // As reads done

  { // phase B: restage Buf as NN = bf16(ni+nj), stride NST
    if (grow_st < E) {
      int s = src_perm[grow_st], d = dst_perm[grow_st];
      const ushort* nir = f_nin + (size_t)s * 256;
      const ushort* njr = f_nj + (size_t)d * 128;
#pragma unroll
      for (int c = 0; c < 4; ++c) {
        int k0 = q * 32 + c * 8;
        uint4 ua = *(const uint4*)(nir + k0);
        uint4 ub = *(const uint4*)(njr + k0);
        uint4 o;
        o.x = pkadd(ua.x, ub.x); o.y = pkadd(ua.y, ub.y);
        o.z = pkadd(ua.z, ub.z); o.w = pkadd(ua.w, ub.w);
        *(uint4*)(Buf + r * NST + k0) = o;
      }
    }
  }
  __syncthreads();

  float at4[4];
#pragma unroll
  for (int n4 = 0; n4 < 4; ++n4) at4[n4] = attn[wc * 64 + n4 * 16 + (lane & 15)];

#pragma unroll
  for (int m4 = 0; m4 < 2; ++m4) {
#pragma unroll
    for (int i = 0; i < 4; ++i) {
      int row = wr * 32 + m4 * 16 + ((lane >> 4) << 2) + i;
      int grow = row0 + row;
      float ph0 = 0.f, ph1 = 0.f;
      if (grow < E) {
#pragma unroll
        for (int n4 = 0; n4 < 4; ++n4) {
          int col = wc * 64 + n4 * 16 + (lane & 15);
          float v = acc[m4][n4][i] + b2f(Buf[row * NST + col]);
          v = v >= 0.f ? v : 0.01f * v;
          ebp[(size_t)grow * 128 + col] = f2b(v);
          float p = v * at4[n4];
          if (n4 < 2) ph0 += p; else ph1 += p;
        }
      }
      ph0 += __shfl_xor(ph0, 1); ph0 += __shfl_xor(ph0, 2);
      ph0 += __shfl_xor(ph0, 4); ph0 += __shfl_xor(ph0, 8);
      ph1 += __shfl_xor(ph1, 1); ph1 += __shfl_xor(ph1, 2);
      ph1 += __shfl_xor(ph1, 4); ph1 += __shfl_xor(ph1, 8);
      if ((lane & 15) == 0 && grow < E) {
        ex[(size_t)grow * 4 + wc * 2 + 0] = __expf(ph0);
        ex[(size_t)grow * 4 + wc * 2 + 1] = __expf(ph1);
      }
    }
  }
}

// ---------- layer-1 node linears, packed uint stores ----------
// 128 thr: thread t -> col pair 2*(t&63), row group t>>6 (8 rows of 16).
__global__ __launch_bounds__(128) void lin3_packed(const float* __restrict__ X,
    const float* __restrict__ W1, const float* __restrict__ b1,
    const float* __restrict__ W2, const float* __restrict__ b2,
    const float* __restrict__ W3, const float* __restrict__ b3,
    ushort* __restrict__ Ynin, ushort* __restrict__ Ynj, int M) {
  constexpr int K = 17;
  __shared__ float xs[16 * K];
  int t = threadIdx.x;
  int cp = t & 63;             // column pair -> cols 2cp, 2cp+1
  int rg = t >> 6;             // 0/1 -> rows rg*8..rg*8+7
  int row0 = blockIdx.x * 16;
  int nr = M - row0; if (nr > 16) nr = 16;
  for (int i = t; i < nr * K; i += 128) xs[i] = X[(size_t)row0 * K + i];
  __syncthreads();
  float2 B1 = *(const float2*)(b1 + 2 * cp);
  float2 B2 = *(const float2*)(b2 + 2 * cp);
  float2 B3 = *(const float2*)(b3 + 2 * cp);
  float a1x[8], a1y[8], a2x[8], a2y[8], a3x[8], a3y[8];
#pragma unroll
  for (int r = 0; r < 8; ++r) {
    a1x[r] = B1.x; a1y[r] = B1.y;
    a2x[r] = B2.x; a2y[r] = B2.y;
    a3x[r] = B3.x; a3y[r] = B3.y;
  }
#pragma unroll
  for (int k = 0; k < K; ++k) {
    float2 w1 = *(const float2*)(W1 + k * 128 + 2 * cp);
    float2 w2 = *(const float2*)(W2 + k * 128 + 2 * cp);
    float2 w3 = *(const float2*)(W3 + k * 128 + 2 * cp);
#pragma unroll
    for (int r = 0; r < 8; ++r) {
      float x = xs[(rg * 8 + r) * K + k];
      a1x[r] = fmaf(x, w1.x, a1x[r]); a1y[r] = fmaf(x, w1.y, a1y[r]);
      a2x[r] = fmaf(x, w2.x, a2x[r]); a2y[r] = fmaf(x, w2.y, a2y[r]);
      a3x[r] = fmaf(x, w3.x, a3x[r]); a3y[r] = fmaf(x, w3.y, a3y[r]);
    }
  }
#pragma unroll
  for (int r = 0; r < 8; ++r) {
    int row = rg * 8 + r;
    if (row < nr) {
      size_t n = (size_t)(row0 + row);
      ((uint*)(Ynin + n * 256))[cp]       = pk2(a1x[r], a1y[r]);  // f_ni
      ((uint*)(Ynin + n * 256 + 128))[cp] = pk2(a3x[r], a3y[r]);  // f_node
      ((uint*)(Ynj + n * 128))[cp]        = pk2(a2x[r], a2y[r]);
    }
  }
}

// ---------- layer-1 edge linear (K=15), perm order, packed uint stores ----------
__global__ __launch_bounds__(128) void lin1_packed(const float* __restrict__ X,
    const float* __restrict__ W, const float* __restrict__ b,
    const int* __restrict__ eperm, ushort* __restrict__ Y, int M) {
  constexpr int K = 15;
  __shared__ float xs[16 * K];
  __shared__ int es[16];
  int t = threadIdx.x;
  int cp = t & 63;
  int rg = t >> 6;
  int row0 = blockIdx.x * 16;
  int nr = M - row0; if (nr > 16) nr = 16;
  if (t < nr) es[t] = eperm[row0 + t];
  __syncthreads();
  for (int i = t; i < nr * K; i += 128) {
    int r = i / K, c = i - r * K;
    xs[i] = X[(size_t)es[r] * K + c];
  }
  __syncthreads();
  float2 BB = *(const float2*)(b + 2 * cp);
  float ax[8], ay[8];
#pragma unroll
  for (int r = 0; r < 8; ++r) { ax[r] = BB.x; ay[r] = BB.y; }
#pragma unroll
  for (int k = 0; k < K; ++k) {
    float2 w = *(const float2*)(W + k * 128 + 2 * cp);
#pragma unroll
    for (int r = 0; r < 8; ++r) {
      float x = xs[(rg * 8 + r) * K + k];
      ax[r] = fmaf(x, w.x, ax[r]);
      ay[r] = fmaf(x, w.y, ay[r]);
    }
  }
#pragma unroll
  for (int r = 0; r < 8; ++r) {
    int row = rg * 8 + r;
    if (row < nr)
      ((uint*)(Y + (size_t)(row0 + row) * 128))[cp] = pk2(ax[r], ay[r]);
  }
}

// ---------- layer-1 fused edge+aggregate (CSR over dst) ----------
__global__ void egat_gather(const ushort* __restrict__ f_nin,   // [N][256] = ni | node
                            const ushort* __restrict__ f_nj,    // [N][128]
                            ushort* ebp,                         // [E][128] perm order, in/out
                            const int* __restrict__ src_perm,
                            const int* __restrict__ rowptr,
                            const float* __restrict__ attn,
                            ushort* __restrict__ nb, int N) {
  int d = blockIdx.x * 4 + (threadIdx.x >> 6);
  if (d >= N) return;
  int lane = threadIdx.x & 63;
  int lo = rowptr[d], hi = rowptr[d + 1];
  int h = lane >> 4;
  float2 at = *(const float2*)(attn + h * 32 + (lane & 15) * 2);
  uint unj = *((const uint*)(f_nj + (size_t)d * 128) + lane);
  float nj0 = b2f_lo(unj), nj1 = b2f_hi(unj);
  float acc0 = 0.f, acc1 = 0.f, exsum = 0.f;
  for (int i = lo; i < hi; ++i) {
    int s = src_perm[i];
    const uint* pn = (const uint*)(f_nin + (size_t)s * 256);
    uint uni = pn[lane];        // f_ni[s]
    uint und = pn[64 + lane];   // f_node[s]
    uint* ep = (uint*)(ebp + (size_t)i * 128) + lane;
    uint ue = *ep;
    float v0 = b2f_lo(ue) + b2f_lo(uni) + nj0;
    float v1 = b2f_hi(ue) + b2f_hi(uni) + nj1;
    v0 = v0 >= 0.f ? v0 : 0.01f * v0;
    v1 = v1 >= 0.f ? v1 : 0.01f * v1;
    *ep = pk2(v0, v1);
    float p = v0 * at.x + v1 * at.y;
    p += __shfl_xor(p, 1);
    p += __shfl_xor(p, 2);
    p += __shfl_xor(p, 4);
    p += __shfl_xor(p, 8);            // all 16 lanes of head h hold the logit
    float ev = __expf(p);             // softmax shift-invariant; logits O(1)
    exsum += ev;
    acc0 = fmaf(b2f_lo(und), ev, acc0);
    acc1 = fmaf(b2f_hi(und), ev, acc1);
  }
  float inv = exsum > 0.f ? 1.f / exsum : 0.f;
  ((uint*)(nb + (size_t)d * 128))[lane] = pk2(acc0 * inv, acc1 * inv);
}

// ---------- light per-node combine (egat2): nb[d] = sum(f_node*ex)/sum(ex) ----------
__global__ void egat_gather2(const ushort* __restrict__ f_nin,
                             const float* __restrict__ ex,
                             const int* __restrict__ src_perm,
                             const int* __restrict__ rowptr,
                             ushort* __restrict__ nb, int N) {
  int d = blockIdx.x * 4 + (threadIdx.x >> 6);
  if (d >= N) return;
  int lane = threadIdx.x & 63;
  int lo = rowptr[d], hi = rowptr[d + 1];
  int h = lane >> 4;
  float acc0 = 0.f, acc1 = 0.f, exsum = 0.f;
  for (int i = lo; i < hi; ++i) {
    float ev = ex[(size_t)i * 4 + h];
    int s = src_perm[i];
    uint und = *((const uint*)(f_nin + (size_t)s * 256 + 128) + lane);  // f_node
    exsum += ev;
    acc0 = fmaf(b2f_lo(und), ev, acc0);
    acc1 = fmaf(b2f_hi(und), ev, acc1);
  }
  float inv = exsum > 0.f ? 1.f / exsum : 0.f;
  ((uint*)(nb + (size_t)d * 128))[lane] = pk2(acc0 * inv, acc1 * inv);
}

// ---------- node segsum (seq) + edge segsum (invperm gather), MERGED ----------
__global__ __launch_bounds__(256) void segsum_both(
    const ushort* __restrict__ nbX, const int* __restrict__ nid, int N, float* __restrict__ Sn,
    const ushort* __restrict__ ebX, const int* __restrict__ invperm,
    const int* __restrict__ eid, int E, float* __restrict__ Se, int NBn) {
  int t = threadIdx.x & 63;
  int wv = threadIdx.x >> 6;
  if ((int)blockIdx.x < NBn) {
    int r0 = (blockIdx.x * 4 + wv) * 32;
    if (r0 >= N) return;
    int r1 = r0 + 32; if (r1 > N) r1 = N;
    float a0 = 0.f, a1 = 0.f;
    int cur = nid[r0];
    for (int r = r0; r < r1; ++r) {
      int id = nid[r];
      if (id != cur) {
        atomicAdd(&Sn[(size_t)cur * 128 + 2 * t], a0);
        atomicAdd(&Sn[(size_t)cur * 128 + 2 * t + 1], a1);
        a0 = a1 = 0.f; cur = id;
      }
      uint u = *((const uint*)(nbX + (size_t)r * 128) + t);
      a0 += b2f_lo(u); a1 += b2f_hi(u);
    }
    atomicAdd(&Sn[(size_t)cur * 128 + 2 * t], a0);
    atomicAdd(&Sn[(size_t)cur * 128 + 2 * t + 1], a1);
  } else {
    int b = blockIdx.x - NBn;
    int r0 = (b * 4 + wv) * 16;
    if (r0 >= E) return;
    int r1 = r0 + 16; if (r1 > E) r1 = E;
    float a0 = 0.f, a1 = 0.f;
    int cur = eid[r0];
    for (int r = r0; r < r1; ++r) {
      int id = eid[r];
      if (id != cur) {
        atomicAdd(&Se[(size_t)cur * 128 + 2 * t], a0);
        atomicAdd(&Se[(size_t)cur * 128 + 2 * t + 1], a1);
        a0 = a1 = 0.f; cur = id;
      }
      uint u = *((const uint*)(ebX + (size_t)invperm[r] * 128) + t);
      a0 += b2f_lo(u); a1 += b2f_hi(u);
    }
    atomicAdd(&Se[(size_t)cur * 128 + 2 * t], a0);
    atomicAdd(&Se[(size_t)cur * 128 + 2 * t + 1], a1);
  }
}

// ---------- diff linears, node+edge MERGED: out[g] = (SP-SR)@W + cnt*b ----------
__global__ void diff_linear2(const float* __restrict__ SnP, const float* __restrict__ SnR,
                             const int* __restrict__ cn,
                             const float* __restrict__ Wn, const float* __restrict__ bn,
                             const float* __restrict__ SeP, const float* __restrict__ SeR,
                             const int* __restrict__ ce,
                             const float* __restrict__ We, const float* __restrict__ be,
                             float* __restrict__ out, int G) {
  int g = blockIdx.x;
  int t = threadIdx.x;
  bool is_e = g >= G; if (is_e) g -= G;
  const float* SP = is_e ? SeP : SnP;
  const float* SR = is_e ? SeR : SnR;
  const int* cnt  = is_e ? ce  : cn;
  const float* W  = is_e ? We  : Wn;
  const float* b  = is_e ? be  : bn;
  int coloff = is_e ? 128 : 0;
  __shared__ float xs[128];
  xs[t] = SP[(size_t)g * 128 + t] - SR[(size_t)g * 128 + t];
  __syncthreads();
  float acc = (float)cnt[g] * b[t];
  for (int k = 0; k < 128; ++k) acc = fmaf(xs[k], W[k * 128 + t], acc);
  out[(size_t)g * 256 + coloff + t] = acc;
}

template<int K, int NC, bool RELU>
__global__ void mlp_linear(const float* __restrict__ X, const float* __restrict__ W,
                           const float* __restrict__ b, float* __restrict__ Y) {
  int g = blockIdx.x;
  int t = threadIdx.x;
  __shared__ float xs[K];
  for (int i = t; i < K; i += NC) xs[i] = X[(size_t)g * K + i];
  __syncthreads();
  float acc = b[t];
  for (int k = 0; k < K; ++k) acc = fmaf(xs[k], W[k * NC + t], acc);
  if (RELU) acc = fmaxf(acc, 0.f);
  Y[(size_t)g * NC + t] = acc;
}

__global__ void mlp_final(const float* __restrict__ X, const float* __restrict__ W,
                          const float* __restrict__ b, float* __restrict__ out, int G) {
  int g = blockIdx.x * blockDim.x + threadIdx.x;
  if (g >= G) return;
  float acc = b[0];
  for (int k = 0; k < 256; ++k) acc = fmaf(X[(size_t)g * 256 + k], W[k], acc);
  out[g] = acc;
}

struct LayerW {
  const float *Wni, *bni, *Wnj, *bnj, *Wf, *bf, *Wnode, *bnode, *attn;
};

extern "C" void kernel_launch(void* const* d_in, const int* in_sizes, int n_in,
                              void* d_out, int out_size, void* d_ws, size_t ws_size,
                              hipStream_t stream) {
  const float* hR = (const float*)d_in[0];
  const float* eR = (const float*)d_in[1];
  const float* hP = (const float*)d_in[2];
  const float* eP = (const float*)d_in[3];
  const int* srcR = (const int*)d_in[4];
  const int* dstR = (const int*)d_in[5];
  const int* srcP = (const int*)d_in[6];
  const int* dstP = (const int*)d_in[7];
  const int* nid  = (const int*)d_in[8];
  const int* eid  = (const int*)d_in[9];
  LayerW w1 { (const float*)d_in[10], (const float*)d_in[11], (const float*)d_in[12],
              (const float*)d_in[13], (const float*)d_in[14], (const float*)d_in[15],
              (const float*)d_in[16], (const float*)d_in[17], (const float*)d_in[18] };
  LayerW w2 { (const float*)d_in[19], (const float*)d_in[20], (const float*)d_in[21],
              (const float*)d_in[22], (const float*)d_in[23], (const float*)d_in[24],
              (const float*)d_in[25], (const float*)d_in[26], (const float*)d_in[27] };
  const float* Wa_n = (const float*)d_in[28];
  const float* ba_n = (const float*)d_in[29];
  const float* Wa_e = (const float*)d_in[30];
  const float* ba_e = (const float*)d_in[31];
  const float* Wm1  = (const float*)d_in[32];
  const float* bm1  = (const float*)d_in[33];
  const float* Wm2  = (const float*)d_in[34];
  const float* bm2  = (const float*)d_in[35];
  const float* Wm3  = (const float*)d_in[36];
  const float* bm3  = (const float*)d_in[37];

  const int N = in_sizes[0] / 17;   // 60000
  const int E = in_sizes[4];        // 240000
  const int G = out_size;           // 1024

  // ---- workspace carve-up ----
  char* base = (char*)d_ws;
  size_t off = 0;
  auto alloc = [&](size_t bytes) { char* p = base + off; off += (bytes + 255) & ~(size_t)255; return p; };
  ushort* nb     = (ushort*)alloc((size_t)N * 128 * 2);   // node state bf16
  ushort* f_nin  = (ushort*)alloc((size_t)N * 256 * 2);   // [ni | node] fused rows
  ushort* f_nj   = (ushort*)alloc((size_t)N * 128 * 2);
  ushort* ebp    = (ushort*)alloc((size_t)E * 128 * 2);   // edge state bf16, dst-CSR order
  float*  ex     = (float*)alloc((size_t)E * 4 * 4);      // per-edge exp(logit), egat2 path
  int*    rowptrP = (int*)alloc((size_t)(N + 1) * 4);
  int*    rowptrR = (int*)alloc((size_t)(N + 1) * 4);
  int*    epermP  = (int*)alloc((size_t)E * 4);
  int*    epermR  = (int*)alloc((size_t)E * 4);
  int*    invpermP = (int*)alloc((size_t)E * 4);
  int*    invpermR = (int*)alloc((size_t)E * 4);
  int*    srcpermP = (int*)alloc((size_t)E * 4);
  int*    srcpermR = (int*)alloc((size_t)E * 4);
  int*    dstpermP = (int*)alloc((size_t)E * 4);
  int*    dstpermR = (int*)alloc((size_t)E * 4);
  int*    cursorP = (int*)alloc((size_t)N * 4);
  int*    cursorR = (int*)alloc((size_t)N * 4);
  int*    blocksumP = (int*)alloc(1024 * 4);
  int*    blocksumR = (int*)alloc(1024 * 4);
  ushort* Wt_ni  = (ushort*)alloc(128 * 128 * 2);
  ushort* Wt_nj  = (ushort*)alloc(128 * 128 * 2);
  ushort* Wt_f   = (ushort*)alloc(128 * 128 * 2);
  ushort* Wt_nd  = (ushort*)alloc(128 * 128 * 2);
  // ---- contiguous zero region: cntP, cntR, SnP, SnR, SeP, SeR ----
  size_t zoff0 = off;
  int*    cntP   = (int*)alloc((size_t)N * 4);
  int*    cntR   = (int*)alloc((size_t)N * 4);
  float*  SnP    = (float*)alloc((size_t)G * 128 * 4);
  float*  SnR    = (float*)alloc((size_t)G * 128 * 4);
  float*  SeP    = (float*)alloc((size_t)G * 128 * 4);
  float*  SeR    = (float*)alloc((size_t)G * 128 * 4);
  size_t zoff1 = off;
  float*  Gf     = (float*)alloc((size_t)G * 256 * 4);
  float*  x1     = (float*)alloc((size_t)G * 512 * 4);
  float*  x2     = (float*)alloc((size_t)G * 256 * 4);
  int*    cnt_n  = (int*)alloc((size_t)G * 4);
  int*    cnt_e  = (int*)alloc((size_t)G * 4);
  if (off > ws_size) return;  // graceful fail

  const int EB = (E + 255) / 256;   // 938
  const int NB = (N + 255) / 256;   // 235 <= 256, fits scan_block

  // ---- 1: zero cntP/cntR + all S accumulators in one launch ----
  int n16 = (int)((zoff1 - zoff0) / 16);
  fillz16<<<(n16 + 255) / 256, 256, 0, stream>>>((uint4*)(base + zoff0), n16);

  // ---- 2-6: CSR builds, P and R in parallel grids ----
  hist_dst2<<<2 * EB, 256, 0, stream>>>(dstP, cntP, dstR, cntR, E, EB);
  scan_local2<<<2 * NB, 256, 0, stream>>>(cntP, rowptrP, blocksumP, cntR, rowptrR, blocksumR, N, NB);
  scan_block2<<<2, 256, 0, stream>>>(blocksumP, blocksumR, NB);
  scan_add2<<<2 * NB, 256, 0, stream>>>(rowptrP, cursorP, blocksumP, rowptrR, cursorR, blocksumR, N, E, NB);
  scatter_idx2<<<2 * EB, 256, 0, stream>>>(dstP, srcP, cursorP, epermP, invpermP, srcpermP, dstpermP,
                                           dstR, srcR, cursorR, epermR, invpermR, srcpermR, dstpermR, E, EB);

  // ---- 7: prep egat2 weights ----
  prep_w4<<<4, 256, 0, stream>>>(w2.Wni, w2.Wnj, w2.Wf, w2.Wnode, Wt_ni, Wt_nj, Wt_f, Wt_nd);

  // ---- 8: per-graph counts (node + edge) ----
  const int GB1 = (G + 255) / 256;
  seg_cnt2<<<2 * GB1, 256, 0, stream>>>(nid, N, cnt_n, eid, E, cnt_e, G, GB1);

  const int GB  = (N + 3) / 4;       // gather grids
  const int NBn = (N + 127) / 128;   // segsum node blocks
  const int NBe = (E + 63) / 64;     // segsum edge blocks

  auto layer1 = [&](const float* h, const float* e, const int* eperm,
                    const int* src_perm, const int* rowptr) {
    lin3_packed<<<(N + 15) / 16, 128, 0, stream>>>(h, w1.Wni, w1.bni, w1.Wnj, w1.bnj,
                                                   w1.Wnode, w1.bnode, f_nin, f_nj, N);
    lin1_packed<<<(E + 15) / 16, 128, 0, stream>>>(e, w1.Wf, w1.bf, eperm, ebp, E);
    egat_gather<<<GB, 256, 0, stream>>>(f_nin, f_nj, ebp, src_perm, rowptr, w1.attn, nb, N);
  };
  auto layer2 = [&](const int* src_perm, const int* dst_perm, const int* rowptr) {
    gemm3_k128<<<(N + 127) / 128, 256, 0, stream>>>(nb,
        Wt_ni, w2.bni,   f_nin,       256,
        Wt_nd, w2.bnode, f_nin + 128, 256,
        Wt_nj, w2.bnj,   f_nj,        128, N);
    gemm_edge_fused<<<(E + 63) / 64, 256, 0, stream>>>(ebp, Wt_f, w2.bf, f_nin, f_nj,
                                                       src_perm, dst_perm, w2.attn, ex, E);
    egat_gather2<<<GB, 256, 0, stream>>>(f_nin, ex, src_perm, rowptr, nb, N);
  };

  // ---- P branch ----
  layer1(hP, eP, epermP, srcpermP, rowptrP);
  segsum_both<<<NBn + NBe, 256, 0, stream>>>(nb, nid, N, SnP, ebp, invpermP, eid, E, SeP, NBn);

  // ---- R branch: egat1 + egat2 x2 ----
  layer1(hR, eR, epermR, srcpermR, rowptrR);
  layer2(srcpermR, dstpermR, rowptrR);
  layer2(srcpermR, dstpermR, rowptrR);
  segsum_both<<<NBn + NBe, 256, 0, stream>>>(nb, nid, N, SnR, ebp, invpermR, eid, E, SeR, NBn);

  // ---- Diff aggregate (node + edge in one launch) ----
  diff_linear2<<<2 * G, 128, 0, stream>>>(SnP, SnR, cnt_n, Wa_n, ba_n,
                                          SeP, SeR, cnt_e, Wa_e, ba_e, Gf, G);

  // ---- MLP head ----
  mlp_linear<256, 512, true><<<G, 512, 0, stream>>>(Gf, Wm1, bm1, x1);
  mlp_linear<512, 256, true><<<G, 256, 0, stream>>>(x1, Wm2, bm2, x2);
  mlp_final<<<(G + 255) / 256, 256, 0, stream>>>(x2, Wm3, bm3, (float*)d_out, G);
}

// Round 19
// 679.527 us; speedup vs baseline: 1.0008x; 1.0008x over previous
//
#include <hip/hip_runtime.h>
#include <cstddef>
#include <cstdint>

typedef unsigned int uint;
typedef unsigned short ushort;
typedef __attribute__((ext_vector_type(4))) float f32x4;
typedef __attribute__((ext_vector_type(8))) short short8;

// ---------- bf16 helpers (storage = ushort) ----------
__device__ __forceinline__ ushort f2b(float v) {
  uint x = __float_as_uint(v);
  return (ushort)((x + 0x7fffu + ((x >> 16) & 1u)) >> 16);  // RNE
}
__device__ __forceinline__ float b2f(ushort u) { return __uint_as_float(((uint)u) << 16); }
__device__ __forceinline__ float b2f_lo(uint u) { return __uint_as_float(u << 16); }
__device__ __forceinline__ float b2f_hi(uint u) { return __uint_as_float(u & 0xffff0000u); }
__device__ __forceinline__ uint pk2(float lo, float hi) {
  return (uint)f2b(lo) | ((uint)f2b(hi) << 16);
}
__device__ __forceinline__ uint pkadd(uint a, uint b) {
  return pk2(b2f_lo(a) + b2f_lo(b), b2f_hi(a) + b2f_hi(b));
}

__device__ __forceinline__ int lowerb(const int* __restrict__ ids, int M, int v) {
  int lo = 0, hi = M;
  while (lo < hi) { int mid = (lo + hi) >> 1; if (ids[mid] < v) lo = mid + 1; else hi = mid; }
  return lo;
}

// zero a contiguous 16B-aligned region
__global__ void fillz16(uint4* p, int n16) {
  int i = blockIdx.x * 256 + threadIdx.x;
  if (i < n16) p[i] = make_uint4(0, 0, 0, 0);
}

// ---------- CSR build, P and R merged per phase ----------
__global__ void hist_dst2(const int* __restrict__ dstP, int* __restrict__ cntP,
                          const int* __restrict__ dstR, int* __restrict__ cntR,
                          int E, int EB) {
  int b = blockIdx.x;
  const int* dst; int* cnt;
  if (b < EB) { dst = dstP; cnt = cntP; } else { dst = dstR; cnt = cntR; b -= EB; }
  int e = b * 256 + threadIdx.x;
  if (e < E) atomicAdd(&cnt[dst[e]], 1);
}

__global__ void scan_local2(const int* __restrict__ cntP, int* __restrict__ rowP, int* __restrict__ bsP,
                            const int* __restrict__ cntR, int* __restrict__ rowR, int* __restrict__ bsR,
                            int N, int NB) {
  __shared__ int tmp[256];
  int b = blockIdx.x;
  const int* cnt; int* rowptr; int* bs;
  if (b < NB) { cnt = cntP; rowptr = rowP; bs = bsP; }
  else        { cnt = cntR; rowptr = rowR; bs = bsR; b -= NB; }
  int t = threadIdx.x;
  int i = b * 256 + t;
  int v = (i < N) ? cnt[i] : 0;
  tmp[t] = v;
  __syncthreads();
  for (int ofs = 1; ofs < 256; ofs <<= 1) {
    int u = (t >= ofs) ? tmp[t - ofs] : 0;
    __syncthreads();
    tmp[t] += u;
    __syncthreads();
  }
  if (i < N) rowptr[i] = tmp[t] - v;          // exclusive
  if (t == 255) bs[b] = tmp[255];
}

__global__ void scan_block2(int* __restrict__ bsP, int* __restrict__ bsR, int n) {
  __shared__ int tmp[256];
  int* bs = (blockIdx.x == 0) ? bsP : bsR;
  int t = threadIdx.x;
  int v = (t < n) ? bs[t] : 0;
  tmp[t] = v;
  __syncthreads();
  for (int ofs = 1; ofs < 256; ofs <<= 1) {
    int u = (t >= ofs) ? tmp[t - ofs] : 0;
    __syncthreads();
    tmp[t] += u;
    __syncthreads();
  }
  if (t < n) bs[t] = tmp[t] - v;              // exclusive
}

__global__ void scan_add2(int* __restrict__ rowP, int* __restrict__ curP, const int* __restrict__ bsP,
                          int* __restrict__ rowR, int* __restrict__ curR, const int* __restrict__ bsR,
                          int N, int E, int NB) {
  int b = blockIdx.x;
  int* rowptr; int* cursor; const int* bs;
  if (b < NB) { rowptr = rowP; cursor = curP; bs = bsP; }
  else        { rowptr = rowR; cursor = curR; bs = bsR; b -= NB; }
  int i = b * 256 + threadIdx.x;
  if (i < N) {
    int v = rowptr[i] + bs[b];
    rowptr[i] = v;
    cursor[i] = v;
  }
  if (i == 0) rowptr[N] = E;
}

__global__ void scatter_idx2(
    const int* __restrict__ dstP, const int* __restrict__ srcP, int* __restrict__ curP,
    int* __restrict__ epP, int* __restrict__ ivP, int* __restrict__ spP, int* __restrict__ dpP,
    const int* __restrict__ dstR, const int* __restrict__ srcR, int* __restrict__ curR,
    int* __restrict__ epR, int* __restrict__ ivR, int* __restrict__ spR, int* __restrict__ dpR,
    int E, int EB) {
  int b = blockIdx.x;
  const int *dst, *src; int *cur, *ep, *iv, *sp, *dp;
  if (b < EB) { dst = dstP; src = srcP; cur = curP; ep = epP; iv = ivP; sp = spP; dp = dpP; }
  else { dst = dstR; src = srcR; cur = curR; ep = epR; iv = ivR; sp = spR; dp = dpR; b -= EB; }
  int e = b * 256 + threadIdx.x;
  if (e < E) {
    int d = dst[e];
    int p = atomicAdd(&cur[d], 1);
    ep[p] = e;
    iv[e] = p;
    sp[p] = src[e];
    dp[p] = d;
  }
}

// ---------- prep: 4x W[128][128] fp32 -> transposed, bf16, XOR-swizzled ----------
__global__ void prep_w4(const float* __restrict__ W0, const float* __restrict__ W1,
                        const float* __restrict__ W2, const float* __restrict__ W3,
                        ushort* __restrict__ T0, ushort* __restrict__ T1,
                        ushort* __restrict__ T2, ushort* __restrict__ T3) {
  const float* W = (blockIdx.x == 0) ? W0 : (blockIdx.x == 1) ? W1 : (blockIdx.x == 2) ? W2 : W3;
  ushort* T      = (blockIdx.x == 0) ? T0 : (blockIdx.x == 1) ? T1 : (blockIdx.x == 2) ? T2 : T3;
  int t = threadIdx.x;        // 256 threads
  int n = t >> 1;
  int k0 = (t & 1) * 64;
  uint sw = (uint)(n & 7) << 3;
  for (int kk = 0; kk < 64; ++kk) {
    int k = k0 + kk;
    T[n * 128 + (k ^ sw)] = f2b(W[k * 128 + n]);
  }
}

// ---------- per-graph counts, node+edge merged ----------
__global__ void seg_cnt2(const int* __restrict__ nid, int N, int* __restrict__ cn,
                         const int* __restrict__ eid, int E, int* __restrict__ ce,
                         int G, int GB1) {
  int b = blockIdx.x;
  if (b < GB1) {
    int g = b * 256 + threadIdx.x;
    if (g < G) cn[g] = lowerb(nid, N, g + 1) - lowerb(nid, N, g);
  } else {
    int g = (b - GB1) * 256 + threadIdx.x;
    if (g < G) ce[g] = lowerb(eid, E, g + 1) - lowerb(eid, E, g);
  }
}

// ---------- fused triple GEMM (node linears): stage A once, 3 weights ----------
__global__ __launch_bounds__(256) void gemm3_k128(
    const ushort* __restrict__ X,
    const ushort* __restrict__ Wt0, const float* __restrict__ b0, ushort* __restrict__ Y0, int ldy0,
    const ushort* __restrict__ Wt1, const float* __restrict__ b1, ushort* __restrict__ Y1, int ldy1,
    const ushort* __restrict__ Wt2, const float* __restrict__ b2, ushort* __restrict__ Y2, int ldy2,
    int M) {
  __shared__ ushort As[128 * 128];
  int t = threadIdx.x;
  int row0 = blockIdx.x * 128;

  { // stage A: linear bf16 copy, swizzled store
    int r = t >> 1;
    int k0h = (t & 1) * 64;
    int grow = row0 + r;
    uint sw = (uint)(r & 7) << 3;
    if (grow < M) {
      const ushort* xr = X + (size_t)grow * 128;
#pragma unroll
      for (int c = 0; c < 8; ++c) {
        int k0 = k0h + c * 8;
        *(uint4*)(As + r * 128 + (k0 ^ sw)) = *(const uint4*)(xr + k0);
      }
    } else {
      uint4 z = make_uint4(0, 0, 0, 0);
#pragma unroll
      for (int c = 0; c < 8; ++c) {
        int k0 = k0h + c * 8;
        *(uint4*)(As + r * 128 + (k0 ^ sw)) = z;
      }
    }
  }
  __syncthreads();

  int lane = t & 63;
  int wid = t >> 6;
  int wr = wid >> 1, wc = wid & 1;
  uint swl = (uint)(lane & 7) << 3;

#pragma unroll
  for (int w = 0; w < 3; ++w) {
    const ushort* Wt = (w == 0) ? Wt0 : (w == 1) ? Wt1 : Wt2;
    const float* bb  = (w == 0) ? b0  : (w == 1) ? b1  : b2;
    ushort* Y        = (w == 0) ? Y0  : (w == 1) ? Y1  : Y2;
    int ldy          = (w == 0) ? ldy0 : (w == 1) ? ldy1 : ldy2;

    f32x4 acc[4][4];
#pragma unroll
    for (int n4 = 0; n4 < 4; ++n4) {
      float bv = bb[wc * 64 + n4 * 16 + (lane & 15)];
#pragma unroll
      for (int m4 = 0; m4 < 4; ++m4) acc[m4][n4] = (f32x4){bv, bv, bv, bv};
    }
#pragma unroll
    for (int kk = 0; kk < 4; ++kk) {
      int kidx = kk * 32 + 8 * (lane >> 4);
      short8 af[4], bfr[4];
#pragma unroll
      for (int m4 = 0; m4 < 4; ++m4) {
        int rm = wr * 64 + m4 * 16 + (lane & 15);
        af[m4] = *(const short8*)(As + rm * 128 + (kidx ^ swl));
      }
#pragma unroll
      for (int n4 = 0; n4 < 4; ++n4) {
        int cn = wc * 64 + n4 * 16 + (lane & 15);
        bfr[n4] = *(const short8*)(Wt + cn * 128 + (kidx ^ swl));   // direct from L2
      }
#pragma unroll
      for (int m4 = 0; m4 < 4; ++m4)
#pragma unroll
        for (int n4 = 0; n4 < 4; ++n4)
          acc[m4][n4] = __builtin_amdgcn_mfma_f32_16x16x32_bf16(af[m4], bfr[n4], acc[m4][n4], 0, 0, 0);
    }
    int coln = wc * 64 + (lane & 15);
#pragma unroll
    for (int m4 = 0; m4 < 4; ++m4) {
      int rb = row0 + wr * 64 + m4 * 16 + ((lane >> 4) << 2);
#pragma unroll
      for (int n4 = 0; n4 < 4; ++n4) {
        int cc = coln + n4 * 16;
#pragma unroll
        for (int i = 0; i < 4; ++i)
          if (rb + i < M) Y[(size_t)(rb + i) * ldy + cc] = f2b(acc[m4][n4][i]);
      }
    }
  }
}

// ---------- fused edge GEMM + edge-stage (egat2), LDS time-shared ----------
static constexpr int NST = 132;
__global__ __launch_bounds__(256) void gemm_edge_fused(
    ushort* ebp, const ushort* __restrict__ Wt, const float* __restrict__ b,
    const ushort* __restrict__ f_nin, const ushort* __restrict__ f_nj,
    const int* __restrict__ src_perm, const int* __restrict__ dst_perm,
    const float* __restrict__ attn, float* __restrict__ ex, int E) {
  __shared__ ushort Buf[64 * NST];   // 16.9 KB, As then NN
  int t = threadIdx.x;
  int row0 = blockIdx.x * 64;
  int r = t >> 2, q = t & 3;
  int grow_st = row0 + r;
  uint sw = (uint)(r & 7) << 3;

  { // phase A: stage As (swizzled, stride 128)
    if (grow_st < E) {
      const ushort* xr = ebp + (size_t)grow_st * 128;
#pragma unroll
      for (int c = 0; c < 4; ++c) {
        int k0 = q * 32 + c * 8;
        *(uint4*)(Buf + r * 128 + (k0 ^ sw)) = *(const uint4*)(xr + k0);
      }
    } else {
      uint4 z = make_uint4(0, 0, 0, 0);
#pragma unroll
      for (int c = 0; c < 4; ++c) {
        int k0 = q * 32 + c * 8;
        *(uint4*)(Buf + r * 128 + (k0 ^ sw)) = z;
      }
    }
  }
  __syncthreads();

  int lane = t & 63;
  int wid = t >> 6;
  int wr = wid >> 1, wc = wid & 1;     // 2x2 waves of 32 rows x 64 cols
  uint swl = (uint)(lane & 7) << 3;

  f32x4 acc[2][4];
#pragma unroll
  for (int n4 = 0; n4 < 4; ++n4) {
    float bv = b[wc * 64 + n4 * 16 + (lane & 15)];
#pragma unroll
    for (int m4 = 0; m4 < 2; ++m4) acc[m4][n4] = (f32x4){bv, bv, bv, bv};
  }
#pragma unroll
  for (int kk = 0; kk < 4; ++kk) {
    int kidx = kk * 32 + 8 * (lane >> 4);
    short8 af[2], bfr[4];
#pragma unroll
    for (int m4 = 0; m4 < 2; ++m4) {
      int rm = wr * 32 + m4 * 16 + (lane & 15);
      af[m4] = *(const short8*)(Buf + rm * 128 + (kidx ^ swl));
    }
#pragma unroll
    for (int n4 = 0; n4 < 4; ++n4) {
      int cn = wc * 64 + n4 * 16 + (lane & 15);
      bfr[n4] = *(const short8*)(Wt + cn * 128 + (kidx ^ swl));   // direct from L2
    }
#pragma unroll
    for (int m4 = 0; m4 < 2; ++m4)
#pragma unroll
      for (int n4 = 0; n4 < 4; ++n4)
        acc[m4][n4] = __builtin_amdgcn_mfma_f32_16x16x32_bf16(af[m4], bfr[n4], acc[m4][n4], 0, 0, 0);
  }
  __syncthreads();                      // As reads done

  { // phase B: restage Buf as NN = bf16(ni+nj), stride NST
    if (grow_st < E) {
      int s = src_perm[grow_st], d = dst_perm[grow_st];
      const ushort* nir = f_nin + (size_t)s * 256;
      const ushort* njr = f_nj + (size_t)d * 128;
#pragma unroll
      for (int c = 0; c < 4; ++c) {
        int k0 = q * 32 + c * 8;
        uint4 ua = *(const uint4*)(nir + k0);
        uint4 ub = *(const uint4*)(njr + k0);
        uint4 o;
        o.x = pkadd(ua.x, ub.x); o.y = pkadd(ua.y, ub.y);
        o.z = pkadd(ua.z, ub.z); o.w = pkadd(ua.w, ub.w);
        *(uint4*)(Buf + r * NST + k0) = o;
      }
    }
  }
  __syncthreads();

  float at4[4];
#pragma unroll
  for (int n4 = 0; n4 < 4; ++n4) at4[n4] = attn[wc * 64 + n4 * 16 + (lane & 15)];

#pragma unroll
  for (int m4 = 0; m4 < 2; ++m4) {
#pragma unroll
    for (int i = 0; i < 4; ++i) {
      int row = wr * 32 + m4 * 16 + ((lane >> 4) << 2) + i;
      int grow = row0 + row;
      float ph0 = 0.f, ph1 = 0.f;
      if (grow < E) {
#pragma unroll
        for (int n4 = 0; n4 < 4; ++n4) {
          int col = wc * 64 + n4 * 16 + (lane & 15);
          float v = acc[m4][n4][i] + b2f(Buf[row * NST + col]);
          v = v >= 0.f ? v : 0.01f * v;
          ebp[(size_t)grow * 128 + col] = f2b(v);
          float p = v * at4[n4];
          if (n4 < 2) ph0 += p; else ph1 += p;
        }
      }
      ph0 += __shfl_xor(ph0, 1); ph0 += __shfl_xor(ph0, 2);
      ph0 += __shfl_xor(ph0, 4); ph0 += __shfl_xor(ph0, 8);
      ph1 += __shfl_xor(ph1, 1); ph1 += __shfl_xor(ph1, 2);
      ph1 += __shfl_xor(ph1, 4); ph1 += __shfl_xor(ph1, 8);
      if ((lane & 15) == 0 && grow < E) {
        ex[(size_t)grow * 4 + wc * 2 + 0] = __expf(ph0);
        ex[(size_t)grow * 4 + wc * 2 + 1] = __expf(ph1);
      }
    }
  }
}

// ---------- layer-1 node linears v2: 256 thr, 32 rows, contiguous reads ----------
// thread t -> col pair cp=t&63, row group rg=t>>6 (8 rows each). Packed stores.
__global__ __launch_bounds__(256) void lin3_v2(const float* __restrict__ X,
    const float* __restrict__ W1, const float* __restrict__ b1,
    const float* __restrict__ W2, const float* __restrict__ b2,
    const float* __restrict__ W3, const float* __restrict__ b3,
    ushort* __restrict__ Ynin, ushort* __restrict__ Ynj, int M) {
  constexpr int K = 17;
  __shared__ float xs[32 * K];
  int t = threadIdx.x;
  int cp = t & 63;
  int rg = t >> 6;             // wave index = row group (wave-uniform)
  int row0 = blockIdx.x * 32;
  int nr = M - row0; if (nr > 32) nr = 32;
  for (int i = t; i < nr * K; i += 256) xs[i] = X[(size_t)row0 * K + i];  // contiguous
  __syncthreads();
  float2 B1 = *(const float2*)(b1 + 2 * cp);
  float2 B2 = *(const float2*)(b2 + 2 * cp);
  float2 B3 = *(const float2*)(b3 + 2 * cp);
  float a1x[8], a1y[8], a2x[8], a2y[8], a3x[8], a3y[8];
#pragma unroll
  for (int r = 0; r < 8; ++r) {
    a1x[r] = B1.x; a1y[r] = B1.y;
    a2x[r] = B2.x; a2y[r] = B2.y;
    a3x[r] = B3.x; a3y[r] = B3.y;
  }
#pragma unroll
  for (int k = 0; k < K; ++k) {
    float2 w1 = *(const float2*)(W1 + k * 128 + 2 * cp);
    float2 w2 = *(const float2*)(W2 + k * 128 + 2 * cp);
    float2 w3 = *(const float2*)(W3 + k * 128 + 2 * cp);
#pragma unroll
    for (int r = 0; r < 8; ++r) {
      float x = xs[(rg * 8 + r) * K + k];   // wave-uniform LDS broadcast
      a1x[r] = fmaf(x, w1.x, a1x[r]); a1y[r] = fmaf(x, w1.y, a1y[r]);
      a2x[r] = fmaf(x, w2.x, a2x[r]); a2y[r] = fmaf(x, w2.y, a2y[r]);
      a3x[r] = fmaf(x, w3.x, a3x[r]); a3y[r] = fmaf(x, w3.y, a3y[r]);
    }
  }
#pragma unroll
  for (int r = 0; r < 8; ++r) {
    int row = rg * 8 + r;
    if (row < nr) {
      size_t n = (size_t)(row0 + row);
      ((uint*)(Ynin + n * 256))[cp]       = pk2(a1x[r], a1y[r]);  // f_ni
      ((uint*)(Ynin + n * 256 + 128))[cp] = pk2(a3x[r], a3y[r]);  // f_node
      ((uint*)(Ynj + n * 128))[cp]        = pk2(a2x[r], a2y[r]);
    }
  }
}

// ---------- layer-1 edge linear v2 (K=15): ORIGINAL-order contiguous reads,
// SCATTER writes to ebp[invperm[e]] (writes are fire-and-forget; no gather stall).
__global__ __launch_bounds__(256) void lin1_scatter(const float* __restrict__ X,
    const float* __restrict__ W, const float* __restrict__ b,
    const int* __restrict__ invperm, ushort* __restrict__ Y, int M) {
  constexpr int K = 15;
  __shared__ float xs[32 * K];
  __shared__ int ip[32];
  int t = threadIdx.x;
  int cp = t & 63;
  int rg = t >> 6;
  int row0 = blockIdx.x * 32;
  int nr = M - row0; if (nr > 32) nr = 32;
  if (t < nr) ip[t] = invperm[row0 + t];
  for (int i = t; i < nr * K; i += 256) xs[i] = X[(size_t)row0 * K + i];  // contiguous
  __syncthreads();
  float2 BB = *(const float2*)(b + 2 * cp);
  float ax[8], ay[8];
#pragma unroll
  for (int r = 0; r < 8; ++r) { ax[r] = BB.x; ay[r] = BB.y; }
#pragma unroll
  for (int k = 0; k < K; ++k) {
    float2 w = *(const float2*)(W + k * 128 + 2 * cp);
#pragma unroll
    for (int r = 0; r < 8; ++r) {
      float x = xs[(rg * 8 + r) * K + k];
      ax[r] = fmaf(x, w.x, ax[r]);
      ay[r] = fmaf(x, w.y, ay[r]);
    }
  }
#pragma unroll
  for (int r = 0; r < 8; ++r) {
    int row = rg * 8 + r;
    if (row < nr)
      ((uint*)(Y + (size_t)ip[row] * 128))[cp] = pk2(ax[r], ay[r]);  // 256B scatter
  }
}

// ---------- layer-1 fused edge+aggregate (CSR over dst) ----------
__global__ void egat_gather(const ushort* __restrict__ f_nin,   // [N][256] = ni | node
                            const ushort* __restrict__ f_nj,    // [N][128]
                            ushort* ebp,                         // [E][128] perm order, in/out
                            const int* __restrict__ src_perm,
                            const int* __restrict__ rowptr,
                            const float* __restrict__ attn,
                            ushort* __restrict__ nb, int N) {
  int d = blockIdx.x * 4 + (threadIdx.x >> 6);
  if (d >= N) return;
  int lane = threadIdx.x & 63;
  int lo = rowptr[d], hi = rowptr[d + 1];
  int h = lane >> 4;
  float2 at = *(const float2*)(attn + h * 32 + (lane & 15) * 2);
  uint unj = *((const uint*)(f_nj + (size_t)d * 128) + lane);
  float nj0 = b2f_lo(unj), nj1 = b2f_hi(unj);
  float acc0 = 0.f, acc1 = 0.f, exsum = 0.f;
  for (int i = lo; i < hi; ++i) {
    int s = src_perm[i];
    const uint* pn = (const uint*)(f_nin + (size_t)s * 256);
    uint uni = pn[lane];        // f_ni[s]
    uint und = pn[64 + lane];   // f_node[s]
    uint* ep = (uint*)(ebp + (size_t)i * 128) + lane;
    uint ue = *ep;
    float v0 = b2f_lo(ue) + b2f_lo(uni) + nj0;
    float v1 = b2f_hi(ue) + b2f_hi(uni) + nj1;
    v0 = v0 >= 0.f ? v0 : 0.01f * v0;
    v1 = v1 >= 0.f ? v1 : 0.01f * v1;
    *ep = pk2(v0, v1);
    float p = v0 * at.x + v1 * at.y;
    p += __shfl_xor(p, 1);
    p += __shfl_xor(p, 2);
    p += __shfl_xor(p, 4);
    p += __shfl_xor(p, 8);            // all 16 lanes of head h hold the logit
    float ev = __expf(p);             // softmax shift-invariant; logits O(1)
    exsum += ev;
    acc0 = fmaf(b2f_lo(und), ev, acc0);
    acc1 = fmaf(b2f_hi(und), ev, acc1);
  }
  float inv = exsum > 0.f ? 1.f / exsum : 0.f;
  ((uint*)(nb + (size_t)d * 128))[lane] = pk2(acc0 * inv, acc1 * inv);
}

// ---------- light per-node combine (egat2): nb[d] = sum(f_node*ex)/sum(ex) ----------
__global__ void egat_gather2(const ushort* __restrict__ f_nin,
                             const float* __restrict__ ex,
                             const int* __restrict__ src_perm,
                             const int* __restrict__ rowptr,
                             ushort* __restrict__ nb, int N) {
  int d = blockIdx.x * 4 + (threadIdx.x >> 6);
  if (d >= N) return;
  int lane = threadIdx.x & 63;
  int lo = rowptr[d], hi = rowptr[d + 1];
  int h = lane >> 4;
  float acc0 = 0.f, acc1 = 0.f, exsum = 0.f;
  for (int i = lo; i < hi; ++i) {
    float ev = ex[(size_t)i * 4 + h];
    int s = src_perm[i];
    uint und = *((const uint*)(f_nin + (size_t)s * 256 + 128) + lane);  // f_node
    exsum += ev;
    acc0 = fmaf(b2f_lo(und), ev, acc0);
    acc1 = fmaf(b2f_hi(und), ev, acc1);
  }
  float inv = exsum > 0.f ? 1.f / exsum : 0.f;
  ((uint*)(nb + (size_t)d * 128))[lane] = pk2(acc0 * inv, acc1 * inv);
}

// ---------- node segsum (seq) + edge segsum (invperm gather), MERGED ----------
__global__ __launch_bounds__(256) void segsum_both(
    const ushort* __restrict__ nbX, const int* __restrict__ nid, int N, float* __restrict__ Sn,
    const ushort* __restrict__ ebX, const int* __restrict__ invperm,
    const int* __restrict__ eid, int E, float* __restrict__ Se, int NBn) {
  int t = threadIdx.x & 63;
  int wv = threadIdx.x >> 6;
  if ((int)blockIdx.x < NBn) {
    int r0 = (blockIdx.x * 4 + wv) * 32;
    if (r0 >= N) return;
    int r1 = r0 + 32; if (r1 > N) r1 = N;
    float a0 = 0.f, a1 = 0.f;
    int cur = nid[r0];
    for (int r = r0; r < r1; ++r) {
      int id = nid[r];
      if (id != cur) {
        atomicAdd(&Sn[(size_t)cur * 128 + 2 * t], a0);
        atomicAdd(&Sn[(size_t)cur * 128 + 2 * t + 1], a1);
        a0 = a1 = 0.f; cur = id;
      }
      uint u = *((const uint*)(nbX + (size_t)r * 128) + t);
      a0 += b2f_lo(u); a1 += b2f_hi(u);
    }
    atomicAdd(&Sn[(size_t)cur * 128 + 2 * t], a0);
    atomicAdd(&Sn[(size_t)cur * 128 + 2 * t + 1], a1);
  } else {
    int b = blockIdx.x - NBn;
    int r0 = (b * 4 + wv) * 16;
    if (r0 >= E) return;
    int r1 = r0 + 16; if (r1 > E) r1 = E;
    float a0 = 0.f, a1 = 0.f;
    int cur = eid[r0];
    for (int r = r0; r < r1; ++r) {
      int id = eid[r];
      if (id != cur) {
        atomicAdd(&Se[(size_t)cur * 128 + 2 * t], a0);
        atomicAdd(&Se[(size_t)cur * 128 + 2 * t + 1], a1);
        a0 = a1 = 0.f; cur = id;
      }
      uint u = *((const uint*)(ebX + (size_t)invperm[r] * 128) + t);
      a0 += b2f_lo(u); a1 += b2f_hi(u);
    }
    atomicAdd(&Se[(size_t)cur * 128 + 2 * t], a0);
    atomicAdd(&Se[(size_t)cur * 128 + 2 * t + 1], a1);
  }
}

// ---------- diff linears, node+edge MERGED: out[g] = (SP-SR)@W + cnt*b ----------
__global__ void diff_linear2(const float* __restrict__ SnP, const float* __restrict__ SnR,
                             const int* __restrict__ cn,
                             const float* __restrict__ Wn, const float* __restrict__ bn,
                             const float* __restrict__ SeP, const float* __restrict__ SeR,
                             const int* __restrict__ ce,
                             const float* __restrict__ We, const float* __restrict__ be,
                             float* __restrict__ out, int G) {
  int g = blockIdx.x;
  int t = threadIdx.x;
  bool is_e = g >= G; if (is_e) g -= G;
  const float* SP = is_e ? SeP : SnP;
  const float* SR = is_e ? SeR : SnR;
  const int* cnt  = is_e ? ce  : cn;
  const float* W  = is_e ? We  : Wn;
  const float* b  = is_e ? be  : bn;
  int coloff = is_e ? 128 : 0;
  __shared__ float xs[128];
  xs[t] = SP[(size_t)g * 128 + t] - SR[(size_t)g * 128 + t];
  __syncthreads();
  float acc = (float)cnt[g] * b[t];
  for (int k = 0; k < 128; ++k) acc = fmaf(xs[k], W[k * 128 + t], acc);
  out[(size_t)g * 256 + coloff + t] = acc;
}

template<int K, int NC, bool RELU>
__global__ void mlp_linear(const float* __restrict__ X, const float* __restrict__ W,
                           const float* __restrict__ b, float* __restrict__ Y) {
  int g = blockIdx.x;
  int t = threadIdx.x;
  __shared__ float xs[K];
  for (int i = t; i < K; i += NC) xs[i] = X[(size_t)g * K + i];
  __syncthreads();
  float acc = b[t];
  for (int k = 0; k < K; ++k) acc = fmaf(xs[k], W[k * NC + t], acc);
  if (RELU) acc = fmaxf(acc, 0.f);
  Y[(size_t)g * NC + t] = acc;
}

__global__ void mlp_final(const float* __restrict__ X, const float* __restrict__ W,
                          const float* __restrict__ b, float* __restrict__ out, int G) {
  int g = blockIdx.x * blockDim.x + threadIdx.x;
  if (g >= G) return;
  float acc = b[0];
  for (int k = 0; k < 256; ++k) acc = fmaf(X[(size_t)g * 256 + k], W[k], acc);
  out[g] = acc;
}

struct LayerW {
  const float *Wni, *bni, *Wnj, *bnj, *Wf, *bf, *Wnode, *bnode, *attn;
};

extern "C" void kernel_launch(void* const* d_in, const int* in_sizes, int n_in,
                              void* d_out, int out_size, void* d_ws, size_t ws_size,
                              hipStream_t stream) {
  const float* hR = (const float*)d_in[0];
  const float* eR = (const float*)d_in[1];
  const float* hP = (const float*)d_in[2];
  const float* eP = (const float*)d_in[3];
  const int* srcR = (const int*)d_in[4];
  const int* dstR = (const int*)d_in[5];
  const int* srcP = (const int*)d_in[6];
  const int* dstP = (const int*)d_in[7];
  const int* nid  = (const int*)d_in[8];
  const int* eid  = (const int*)d_in[9];
  LayerW w1 { (const float*)d_in[10], (const float*)d_in[11], (const float*)d_in[12],
              (const float*)d_in[13], (const float*)d_in[14], (const float*)d_in[15],
              (const float*)d_in[16], (const float*)d_in[17], (const float*)d_in[18] };
  LayerW w2 { (const float*)d_in[19], (const float*)d_in[20], (const float*)d_in[21],
              (const float*)d_in[22], (const float*)d_in[23], (const float*)d_in[24],
              (const float*)d_in[25], (const float*)d_in[26], (const float*)d_in[27] };
  const float* Wa_n = (const float*)d_in[28];
  const float* ba_n = (const float*)d_in[29];
  const float* Wa_e = (const float*)d_in[30];
  const float* ba_e = (const float*)d_in[31];
  const float* Wm1  = (const float*)d_in[32];
  const float* bm1  = (const float*)d_in[33];
  const float* Wm2  = (const float*)d_in[34];
  const float* bm2  = (const float*)d_in[35];
  const float* Wm3  = (const float*)d_in[36];
  const float* bm3  = (const float*)d_in[37];

  const int N = in_sizes[0] / 17;   // 60000
  const int E = in_sizes[4];        // 240000
  const int G = out_size;           // 1024

  // ---- workspace carve-up ----
  char* base = (char*)d_ws;
  size_t off = 0;
  auto alloc = [&](size_t bytes) { char* p = base + off; off += (bytes + 255) & ~(size_t)255; return p; };
  ushort* nb     = (ushort*)alloc((size_t)N * 128 * 2);   // node state bf16
  ushort* f_nin  = (ushort*)alloc((size_t)N * 256 * 2);   // [ni | node] fused rows
  ushort* f_nj   = (ushort*)alloc((size_t)N * 128 * 2);
  ushort* ebp    = (ushort*)alloc((size_t)E * 128 * 2);   // edge state bf16, dst-CSR order
  float*  ex     = (float*)alloc((size_t)E * 4 * 4);      // per-edge exp(logit), egat2 path
  int*    rowptrP = (int*)alloc((size_t)(N + 1) * 4);
  int*    rowptrR = (int*)alloc((size_t)(N + 1) * 4);
  int*    epermP  = (int*)alloc((size_t)E * 4);
  int*    epermR  = (int*)alloc((size_t)E * 4);
  int*    invpermP = (int*)alloc((size_t)E * 4);
  int*    invpermR = (int*)alloc((size_t)E * 4);
  int*    srcpermP = (int*)alloc((size_t)E * 4);
  int*    srcpermR = (int*)alloc((size_t)E * 4);
  int*    dstpermP = (int*)alloc((size_t)E * 4);
  int*    dstpermR = (int*)alloc((size_t)E * 4);
  int*    cursorP = (int*)alloc((size_t)N * 4);
  int*    cursorR = (int*)alloc((size_t)N * 4);
  int*    blocksumP = (int*)alloc(1024 * 4);
  int*    blocksumR = (int*)alloc(1024 * 4);
  ushort* Wt_ni  = (ushort*)alloc(128 * 128 * 2);
  ushort* Wt_nj  = (ushort*)alloc(128 * 128 * 2);
  ushort* Wt_f   = (ushort*)alloc(128 * 128 * 2);
  ushort* Wt_nd  = (ushort*)alloc(128 * 128 * 2);
  // ---- contiguous zero region: cntP, cntR, SnP, SnR, SeP, SeR ----
  size_t zoff0 = off;
  int*    cntP   = (int*)alloc((size_t)N * 4);
  int*    cntR   = (int*)alloc((size_t)N * 4);
  float*  SnP    = (float*)alloc((size_t)G * 128 * 4);
  float*  SnR    = (float*)alloc((size_t)G * 128 * 4);
  float*  SeP    = (float*)alloc((size_t)G * 128 * 4);
  float*  SeR    = (float*)alloc((size_t)G * 128 * 4);
  size_t zoff1 = off;
  float*  Gf     = (float*)alloc((size_t)G * 256 * 4);
  float*  x1     = (float*)alloc((size_t)G * 512 * 4);
  float*  x2     = (float*)alloc((size_t)G * 256 * 4);
  int*    cnt_n  = (int*)alloc((size_t)G * 4);
  int*    cnt_e  = (int*)alloc((size_t)G * 4);
  if (off > ws_size) return;  // graceful fail

  const int EB = (E + 255) / 256;   // 938
  const int NB = (N + 255) / 256;   // 235 <= 256, fits scan_block

  // ---- 1: zero cntP/cntR + all S accumulators in one launch ----
  int n16 = (int)((zoff1 - zoff0) / 16);
  fillz16<<<(n16 + 255) / 256, 256, 0, stream>>>((uint4*)(base + zoff0), n16);

  // ---- 2-6: CSR builds, P and R in parallel grids ----
  hist_dst2<<<2 * EB, 256, 0, stream>>>(dstP, cntP, dstR, cntR, E, EB);
  scan_local2<<<2 * NB, 256, 0, stream>>>(cntP, rowptrP, blocksumP, cntR, rowptrR, blocksumR, N, NB);
  scan_block2<<<2, 256, 0, stream>>>(blocksumP, blocksumR, NB);
  scan_add2<<<2 * NB, 256, 0, stream>>>(rowptrP, cursorP, blocksumP, rowptrR, cursorR, blocksumR, N, E, NB);
  scatter_idx2<<<2 * EB, 256, 0, stream>>>(dstP, srcP, cursorP, epermP, invpermP, srcpermP, dstpermP,
                                           dstR, srcR, cursorR, epermR, invpermR, srcpermR, dstpermR, E, EB);

  // ---- 7: prep egat2 weights ----
  prep_w4<<<4, 256, 0, stream>>>(w2.Wni, w2.Wnj, w2.Wf, w2.Wnode, Wt_ni, Wt_nj, Wt_f, Wt_nd);

  // ---- 8: per-graph counts (node + edge) ----
  const int GB1 = (G + 255) / 256;
  seg_cnt2<<<2 * GB1, 256, 0, stream>>>(nid, N, cnt_n, eid, E, cnt_e, G, GB1);

  const int GB  = (N + 3) / 4;       // gather grids
  const int NBn = (N + 127) / 128;   // segsum node blocks
  const int NBe = (E + 63) / 64;     // segsum edge blocks

  auto layer1 = [&](const float* h, const float* e, const int* invperm,
                    const int* src_perm, const int* rowptr) {
    lin3_v2<<<(N + 31) / 32, 256, 0, stream>>>(h, w1.Wni, w1.bni, w1.Wnj, w1.bnj,
                                               w1.Wnode, w1.bnode, f_nin, f_nj, N);
    lin1_scatter<<<(E + 31) / 32, 256, 0, stream>>>(e, w1.Wf, w1.bf, invperm, ebp, E);
    egat_gather<<<GB, 256, 0, stream>>>(f_nin, f_nj, ebp, src_perm, rowptr, w1.attn, nb, N);
  };
  auto layer2 = [&](const int* src_perm, const int* dst_perm, const int* rowptr) {
    gemm3_k128<<<(N + 127) / 128, 256, 0, stream>>>(nb,
        Wt_ni, w2.bni,   f_nin,       256,
        Wt_nd, w2.bnode, f_nin + 128, 256,
        Wt_nj, w2.bnj,   f_nj,        128, N);
    gemm_edge_fused<<<(E + 63) / 64, 256, 0, stream>>>(ebp, Wt_f, w2.bf, f_nin, f_nj,
                                                       src_perm, dst_perm, w2.attn, ex, E);
    egat_gather2<<<GB, 256, 0, stream>>>(f_nin, ex, src_perm, rowptr, nb, N);
  };

  // ---- P branch ----
  layer1(hP, eP, invpermP, srcpermP, rowptrP);
  segsum_both<<<NBn + NBe, 256, 0, stream>>>(nb, nid, N, SnP, ebp, invpermP, eid, E, SeP, NBn);

  // ---- R branch: egat1 + egat2 x2 ----
  layer1(hR, eR, invpermR, srcpermR, rowptrR);
  layer2(srcpermR, dstpermR, rowptrR);
  layer2(srcpermR, dstpermR, rowptrR);
  segsum_both<<<NBn + NBe, 256, 0, stream>>>(nb, nid, N, SnR, ebp, invpermR, eid, E, SeR, NBn);

  // ---- Diff aggregate (node + edge in one launch) ----
  diff_linear2<<<2 * G, 128, 0, stream>>>(SnP, SnR, cnt_n, Wa_n, ba_n,
                                          SeP, SeR, cnt_e, Wa_e, ba_e, Gf, G);

  // ---- MLP head ----
  mlp_linear<256, 512, true><<<G, 512, 0, stream>>>(Gf, Wm1, bm1, x1);
  mlp_linear<512, 256, true><<<G, 256, 0, stream>>>(x1, Wm2, bm2, x2);
  mlp_final<<<(G + 255) / 256, 256, 0, stream>>>(x2, Wm3, bm3, (float*)d_out, G);
}

// Round 20
// 621.022 us; speedup vs baseline: 1.0950x; 1.0942x over previous
//
#include <hip/hip_runtime.h>
#include <cstddef>
#include <cstdint>

typedef unsigned int uint;
typedef unsigned short ushort;
typedef __attribute__((ext_vector_type(4))) float f32x4;
typedef __attribute__((ext_vector_type(8))) short short8;

// ---------- bf16 helpers (storage = ushort) ----------
__device__ __forceinline__ ushort f2b(float v) {
  uint x = __float_as_uint(v);
  return (ushort)((x + 0x7fffu + ((x >> 16) & 1u)) >> 16);  // RNE
}
__device__ __forceinline__ float b2f(ushort u) { return __uint_as_float(((uint)u) << 16); }
__device__ __forceinline__ float b2f_lo(uint u) { return __uint_as_float(u << 16); }
__device__ __forceinline__ float b2f_hi(uint u) { return __uint_as_float(u & 0xffff0000u); }
__device__ __forceinline__ uint pk2(float lo, float hi) {
  return (uint)f2b(lo) | ((uint)f2b(hi) << 16);
}
__device__ __forceinline__ uint pkadd(uint a, uint b) {
  return pk2(b2f_lo(a) + b2f_lo(b), b2f_hi(a) + b2f_hi(b));
}

__device__ __forceinline__ int lowerb(const int* __restrict__ ids, int M, int v) {
  int lo = 0, hi = M;
  while (lo < hi) { int mid = (lo + hi) >> 1; if (ids[mid] < v) lo = mid + 1; else hi = mid; }
  return lo;
}

// zero a contiguous 16B-aligned region
__global__ void fillz16(uint4* p, int n16) {
  int i = blockIdx.x * 256 + threadIdx.x;
  if (i < n16) p[i] = make_uint4(0, 0, 0, 0);
}

// ---------- CSR build, P and R merged per phase ----------
__global__ void hist_dst2(const int* __restrict__ dstP, int* __restrict__ cntP,
                          const int* __restrict__ dstR, int* __restrict__ cntR,
                          int E, int EB) {
  int b = blockIdx.x;
  const int* dst; int* cnt;
  if (b < EB) { dst = dstP; cnt = cntP; } else { dst = dstR; cnt = cntR; b -= EB; }
  int e = b * 256 + threadIdx.x;
  if (e < E) atomicAdd(&cnt[dst[e]], 1);
}

__global__ void scan_local2(const int* __restrict__ cntP, int* __restrict__ rowP, int* __restrict__ bsP,
                            const int* __restrict__ cntR, int* __restrict__ rowR, int* __restrict__ bsR,
                            int N, int NB) {
  __shared__ int tmp[256];
  int b = blockIdx.x;
  const int* cnt; int* rowptr; int* bs;
  if (b < NB) { cnt = cntP; rowptr = rowP; bs = bsP; }
  else        { cnt = cntR; rowptr = rowR; bs = bsR; b -= NB; }
  int t = threadIdx.x;
  int i = b * 256 + t;
  int v = (i < N) ? cnt[i] : 0;
  tmp[t] = v;
  __syncthreads();
  for (int ofs = 1; ofs < 256; ofs <<= 1) {
    int u = (t >= ofs) ? tmp[t - ofs] : 0;
    __syncthreads();
    tmp[t] += u;
    __syncthreads();
  }
  if (i < N) rowptr[i] = tmp[t] - v;          // exclusive
  if (t == 255) bs[b] = tmp[255];
}

__global__ void scan_block2(int* __restrict__ bsP, int* __restrict__ bsR, int n) {
  __shared__ int tmp[256];
  int* bs = (blockIdx.x == 0) ? bsP : bsR;
  int t = threadIdx.x;
  int v = (t < n) ? bs[t] : 0;
  tmp[t] = v;
  __syncthreads();
  for (int ofs = 1; ofs < 256; ofs <<= 1) {
    int u = (t >= ofs) ? tmp[t - ofs] : 0;
    __syncthreads();
    tmp[t] += u;
    __syncthreads();
  }
  if (t < n) bs[t] = tmp[t] - v;              // exclusive
}

__global__ void scan_add2(int* __restrict__ rowP, int* __restrict__ curP, const int* __restrict__ bsP,
                          int* __restrict__ rowR, int* __restrict__ curR, const int* __restrict__ bsR,
                          int N, int E, int NB) {
  int b = blockIdx.x;
  int* rowptr; int* cursor; const int* bs;
  if (b < NB) { rowptr = rowP; cursor = curP; bs = bsP; }
  else        { rowptr = rowR; cursor = curR; bs = bsR; b -= NB; }
  int i = b * 256 + threadIdx.x;
  if (i < N) {
    int v = rowptr[i] + bs[b];
    rowptr[i] = v;
    cursor[i] = v;
  }
  if (i == 0) rowptr[N] = E;
}

__global__ void scatter_idx2(
    const int* __restrict__ dstP, const int* __restrict__ srcP, int* __restrict__ curP,
    int* __restrict__ epP, int* __restrict__ ivP, int* __restrict__ spP, int* __restrict__ dpP,
    const int* __restrict__ dstR, const int* __restrict__ srcR, int* __restrict__ curR,
    int* __restrict__ epR, int* __restrict__ ivR, int* __restrict__ spR, int* __restrict__ dpR,
    int E, int EB) {
  int b = blockIdx.x;
  const int *dst, *src; int *cur, *ep, *iv, *sp, *dp;
  if (b < EB) { dst = dstP; src = srcP; cur = curP; ep = epP; iv = ivP; sp = spP; dp = dpP; }
  else { dst = dstR; src = srcR; cur = curR; ep = epR; iv = ivR; sp = spR; dp = dpR; b -= EB; }
  int e = b * 256 + threadIdx.x;
  if (e < E) {
    int d = dst[e];
    int p = atomicAdd(&cur[d], 1);
    ep[p] = e;
    iv[e] = p;
    sp[p] = src[e];
    dp[p] = d;
  }
}

// ---------- prep: 4x W[128][128] fp32 -> transposed, bf16, XOR-swizzled ----------
__global__ void prep_w4(const float* __restrict__ W0, const float* __restrict__ W1,
                        const float* __restrict__ W2, const float* __restrict__ W3,
                        ushort* __restrict__ T0, ushort* __restrict__ T1,
                        ushort* __restrict__ T2, ushort* __restrict__ T3) {
  const float* W = (blockIdx.x == 0) ? W0 : (blockIdx.x == 1) ? W1 : (blockIdx.x == 2) ? W2 : W3;
  ushort* T      = (blockIdx.x == 0) ? T0 : (blockIdx.x == 1) ? T1 : (blockIdx.x == 2) ? T2 : T3;
  int t = threadIdx.x;        // 256 threads
  int n = t >> 1;
  int k0 = (t & 1) * 64;
  uint sw = (uint)(n & 7) << 3;
  for (int kk = 0; kk < 64; ++kk) {
    int k = k0 + kk;
    T[n * 128 + (k ^ sw)] = f2b(W[k * 128 + n]);
  }
}

// ---------- per-graph counts, node+edge merged ----------
__global__ void seg_cnt2(const int* __restrict__ nid, int N, int* __restrict__ cn,
                         const int* __restrict__ eid, int E, int* __restrict__ ce,
                         int G, int GB1) {
  int b = blockIdx.x;
  if (b < GB1) {
    int g = b * 256 + threadIdx.x;
    if (g < G) cn[g] = lowerb(nid, N, g + 1) - lowerb(nid, N, g);
  } else {
    int g = (b - GB1) * 256 + threadIdx.x;
    if (g < G) ce[g] = lowerb(eid, E, g + 1) - lowerb(eid, E, g);
  }
}

// ---------- fused triple GEMM (node linears): stage A once, 3 weights ----------
__global__ __launch_bounds__(256) void gemm3_k128(
    const ushort* __restrict__ X,
    const ushort* __restrict__ Wt0, const float* __restrict__ b0, ushort* __restrict__ Y0, int ldy0,
    const ushort* __restrict__ Wt1, const float* __restrict__ b1, ushort* __restrict__ Y1, int ldy1,
    const ushort* __restrict__ Wt2, const float* __restrict__ b2, ushort* __restrict__ Y2, int ldy2,
    int M) {
  __shared__ ushort As[128 * 128];
  int t = threadIdx.x;
  int row0 = blockIdx.x * 128;

  { // stage A: linear bf16 copy, swizzled store
    int r = t >> 1;
    int k0h = (t & 1) * 64;
    int grow = row0 + r;
    uint sw = (uint)(r & 7) << 3;
    if (grow < M) {
      const ushort* xr = X + (size_t)grow * 128;
#pragma unroll
      for (int c = 0; c < 8; ++c) {
        int k0 = k0h + c * 8;
        *(uint4*)(As + r * 128 + (k0 ^ sw)) = *(const uint4*)(xr + k0);
      }
    } else {
      uint4 z = make_uint4(0, 0, 0, 0);
#pragma unroll
      for (int c = 0; c < 8; ++c) {
        int k0 = k0h + c * 8;
        *(uint4*)(As + r * 128 + (k0 ^ sw)) = z;
      }
    }
  }
  __syncthreads();

  int lane = t & 63;
  int wid = t >> 6;
  int wr = wid >> 1, wc = wid & 1;
  uint swl = (uint)(lane & 7) << 3;

#pragma unroll
  for (int w = 0; w < 3; ++w) {
    const ushort* Wt = (w == 0) ? Wt0 : (w == 1) ? Wt1 : Wt2;
    const float* bb  = (w == 0) ? b0  : (w == 1) ? b1  : b2;
    ushort* Y        = (w == 0) ? Y0  : (w == 1) ? Y1  : Y2;
    int ldy          = (w == 0) ? ldy0 : (w == 1) ? ldy1 : ldy2;

    f32x4 acc[4][4];
#pragma unroll
    for (int n4 = 0; n4 < 4; ++n4) {
      float bv = bb[wc * 64 + n4 * 16 + (lane & 15)];
#pragma unroll
      for (int m4 = 0; m4 < 4; ++m4) acc[m4][n4] = (f32x4){bv, bv, bv, bv};
    }
#pragma unroll
    for (int kk = 0; kk < 4; ++kk) {
      int kidx = kk * 32 + 8 * (lane >> 4);
      short8 af[4], bfr[4];
#pragma unroll
      for (int m4 = 0; m4 < 4; ++m4) {
        int rm = wr * 64 + m4 * 16 + (lane & 15);
        af[m4] = *(const short8*)(As + rm * 128 + (kidx ^ swl));
      }
#pragma unroll
      for (int n4 = 0; n4 < 4; ++n4) {
        int cn = wc * 64 + n4 * 16 + (lane & 15);
        bfr[n4] = *(const short8*)(Wt + cn * 128 + (kidx ^ swl));   // direct from L2
      }
#pragma unroll
      for (int m4 = 0; m4 < 4; ++m4)
#pragma unroll
        for (int n4 = 0; n4 < 4; ++n4)
          acc[m4][n4] = __builtin_amdgcn_mfma_f32_16x16x32_bf16(af[m4], bfr[n4], acc[m4][n4], 0, 0, 0);
    }
    int coln = wc * 64 + (lane & 15);
#pragma unroll
    for (int m4 = 0; m4 < 4; ++m4) {
      int rb = row0 + wr * 64 + m4 * 16 + ((lane >> 4) << 2);
#pragma unroll
      for (int n4 = 0; n4 < 4; ++n4) {
        int cc = coln + n4 * 16;
#pragma unroll
        for (int i = 0; i < 4; ++i)
          if (rb + i < M) Y[(size_t)(rb + i) * ldy + cc] = f2b(acc[m4][n4][i]);
      }
    }
  }
}

// ---------- fused edge GEMM + edge-stage (egat2), LDS time-shared ----------
static constexpr int NST = 132;
__global__ __launch_bounds__(256) void gemm_edge_fused(
    ushort* ebp, const ushort* __restrict__ Wt, const float* __restrict__ b,
    const ushort* __restrict__ f_nin, const ushort* __restrict__ f_nj,
    const int* __restrict__ src_perm, const int* __restrict__ dst_perm,
    const float* __restrict__ attn, float* __restrict__ ex, int E) {
  __shared__ ushort Buf[64 * NST];   // 16.9 KB, As then NN
  int t = threadIdx.x;
  int row0 = blockIdx.x * 64;
  int r = t >> 2, q = t & 3;
  int grow_st = row0 + r;
  uint sw = (uint)(r & 7) << 3;

  { // phase A: stage As (swizzled, stride 128)
    if (grow_st < E) {
      const ushort* xr = ebp + (size_t)grow_st * 128;
#pragma unroll
      for (int c = 0; c < 4; ++c) {
        int k0 = q * 32 + c * 8;
        *(uint4*)(Buf + r * 128 + (k0 ^ sw)) = *(const uint4*)(xr + k0);
      }
    } else {
      uint4 z = make_uint4(0, 0, 0, 0);
#pragma unroll
      for (int c = 0; c < 4; ++c) {
        int k0 = q * 32 + c * 8;
        *(uint4*)(Buf + r * 128 + (k0 ^ sw)) = z;
      }
    }
  }
  __syncthreads();

  int lane = t & 63;
  int wid = t >> 6;
  int wr = wid >> 1, wc = wid & 1;     // 2x2 waves of 32 rows x 64 cols
  uint swl = (uint)(lane & 7) << 3;

  f32x4 acc[2][4];
#pragma unroll
  for (int n4 = 0; n4 < 4; ++n4) {
    float bv = b[wc * 64 + n4 * 16 + (lane & 15)];
#pragma unroll
    for (int m4 = 0; m4 < 2; ++m4) acc[m4][n4] = (f32x4){bv, bv, bv, bv};
  }
#pragma unroll
  for (int kk = 0; kk < 4; ++kk) {
    int kidx = kk * 32 + 8 * (lane >> 4);
    short8 af[2], bfr[4];
#pragma unroll
    for (int m4 = 0; m4 < 2; ++m4) {
      int rm = wr * 32 + m4 * 16 + (lane & 15);
      af[m4] = *(const short8*)(Buf + rm * 128 + (kidx ^ swl));
    }
#pragma unroll
    for (int n4 = 0; n4 < 4; ++n4) {
      int cn = wc * 64 + n4 * 16 + (lane & 15);
      bfr[n4] = *(const short8*)(Wt + cn * 128 + (kidx ^ swl));   // direct from L2
    }
#pragma unroll
    for (int m4 = 0; m4 < 2; ++m4)
#pragma unroll
      for (int n4 = 0; n4 < 4; ++n4)
        acc[m4][n4] = __builtin_amdgcn_mfma_f32_16x16x32_bf16(af[m4], bfr[n4], acc[m4][n4], 0, 0, 0);
  }
  __syncthreads();                      // As reads done

  { // phase B: restage Buf as NN = bf16(ni+nj), stride NST
    if (grow_st < E) {
      int s = src_perm[grow_st], d = dst_perm[grow_st];
      const ushort* nir = f_nin + (size_t)s * 256;
      const ushort* njr = f_nj + (size_t)d * 128;
#pragma unroll
      for (int c = 0; c < 4; ++c) {
        int k0 = q * 32 + c * 8;
        uint4 ua = *(const uint4*)(nir + k0);
        uint4 ub = *(const uint4*)(njr + k0);
        uint4 o;
        o.x = pkadd(ua.x, ub.x); o.y = pkadd(ua.y, ub.y);
        o.z = pkadd(ua.z, ub.z); o.w = pkadd(ua.w, ub.w);
        *(uint4*)(Buf + r * NST + k0) = o;
      }
    }
  }
  __syncthreads();

  float at4[4];
#pragma unroll
  for (int n4 = 0; n4 < 4; ++n4) at4[n4] = attn[wc * 64 + n4 * 16 + (lane & 15)];

#pragma unroll
  for (int m4 = 0; m4 < 2; ++m4) {
#pragma unroll
    for (int i = 0; i < 4; ++i) {
      int row = wr * 32 + m4 * 16 + ((lane >> 4) << 2) + i;
      int grow = row0 + row;
      float ph0 = 0.f, ph1 = 0.f;
      if (grow < E) {
#pragma unroll
        for (int n4 = 0; n4 < 4; ++n4) {
          int col = wc * 64 + n4 * 16 + (lane & 15);
          float v = acc[m4][n4][i] + b2f(Buf[row * NST + col]);
          v = v >= 0.f ? v : 0.01f * v;
          ebp[(size_t)grow * 128 + col] = f2b(v);
          float p = v * at4[n4];
          if (n4 < 2) ph0 += p; else ph1 += p;
        }
      }
      ph0 += __shfl_xor(ph0, 1); ph0 += __shfl_xor(ph0, 2);
      ph0 += __shfl_xor(ph0, 4); ph0 += __shfl_xor(ph0, 8);
      ph1 += __shfl_xor(ph1, 1); ph1 += __shfl_xor(ph1, 2);
      ph1 += __shfl_xor(ph1, 4); ph1 += __shfl_xor(ph1, 8);
      if ((lane & 15) == 0 && grow < E) {
        ex[(size_t)grow * 4 + wc * 2 + 0] = __expf(ph0);
        ex[(size_t)grow * 4 + wc * 2 + 1] = __expf(ph1);
      }
    }
  }
}

// ---------- layer-1 fused node linears (R15-proven) ----------
template<int K>
__global__ __launch_bounds__(128) void lin3_small(const float* __restrict__ X,
    const float* __restrict__ W1, const float* __restrict__ b1,
    const float* __restrict__ W2, const float* __restrict__ b2,
    const float* __restrict__ W3, const float* __restrict__ b3,
    ushort* __restrict__ Ynin, ushort* __restrict__ Ynj, int M) {
  constexpr int ROWS = 16;
  __shared__ float xs[ROWS * K];
  int t = threadIdx.x;
  int row0 = blockIdx.x * ROWS;
  int nr = M - row0; if (nr > ROWS) nr = ROWS;
  for (int i = t; i < nr * K; i += 128) xs[i] = X[(size_t)row0 * K + i];
  __syncthreads();
  float a1[ROWS], a2[ROWS], a3[ROWS];
  float v1 = b1[t], v2 = b2[t], v3 = b3[t];
#pragma unroll
  for (int r = 0; r < ROWS; ++r) { a1[r] = v1; a2[r] = v2; a3[r] = v3; }
#pragma unroll
  for (int k = 0; k < K; ++k) {
    float w1 = W1[k * 128 + t], w2 = W2[k * 128 + t], w3 = W3[k * 128 + t];
#pragma unroll
    for (int r = 0; r < ROWS; ++r) {
      float x = xs[r * K + k];
      a1[r] = fmaf(x, w1, a1[r]);
      a2[r] = fmaf(x, w2, a2[r]);
      a3[r] = fmaf(x, w3, a3[r]);
    }
  }
  for (int r = 0; r < nr; ++r) {
    size_t n = (size_t)(row0 + r);
    Ynin[n * 256 + t] = f2b(a1[r]);        // f_ni
    Ynin[n * 256 + 128 + t] = f2b(a3[r]);  // f_node
    Ynj[n * 128 + t] = f2b(a2[r]);
  }
}

// ---------- layer-1 edge linear (K=15), perm order (R15-proven) ----------
template<int K>
__global__ __launch_bounds__(128) void lin1_perm(const float* __restrict__ X,
    const float* __restrict__ W, const float* __restrict__ b,
    const int* __restrict__ eperm, ushort* __restrict__ Y, int M) {
  constexpr int ROWS = 16;
  __shared__ float xs[ROWS * K];
  __shared__ int es[ROWS];
  int t = threadIdx.x;
  int row0 = blockIdx.x * ROWS;
  int nr = M - row0; if (nr > ROWS) nr = ROWS;
  if (t < nr) es[t] = eperm[row0 + t];
  __syncthreads();
  for (int i = t; i < nr * K; i += 128) {
    int r = i / K, c = i - r * K;
    xs[i] = X[(size_t)es[r] * K + c];
  }
  __syncthreads();
  float acc[ROWS];
  float bias = b[t];
#pragma unroll
  for (int r = 0; r < ROWS; ++r) acc[r] = bias;
#pragma unroll
  for (int k = 0; k < K; ++k) {
    float w = W[k * 128 + t];
#pragma unroll
    for (int r = 0; r < ROWS; ++r) acc[r] = fmaf(xs[r * K + k], w, acc[r]);
  }
  for (int r = 0; r < nr; ++r) Y[(size_t)(row0 + r) * 128 + t] = f2b(acc[r]);
}

// ---------- layer-1 fused edge+aggregate (CSR over dst) ----------
__global__ void egat_gather(const ushort* __restrict__ f_nin,   // [N][256] = ni | node
                            const ushort* __restrict__ f_nj,    // [N][128]
                            ushort* ebp,                         // [E][128] perm order, in/out
                            const int* __restrict__ src_perm,
                            const int* __restrict__ rowptr,
                            const float* __restrict__ attn,
                            ushort* __restrict__ nb, int N) {
  int d = blockIdx.x * 4 + (threadIdx.x >> 6);
  if (d >= N) return;
  int lane = threadIdx.x & 63;
  int lo = rowptr[d], hi = rowptr[d + 1];
  int h = lane >> 4;
  float2 at = *(const float2*)(attn + h * 32 + (lane & 15) * 2);
  uint unj = *((const uint*)(f_nj + (size_t)d * 128) + lane);
  float nj0 = b2f_lo(unj), nj1 = b2f_hi(unj);
  float acc0 = 0.f, acc1 = 0.f, exsum = 0.f;
  for (int i = lo; i < hi; ++i) {
    int s = src_perm[i];
    const uint* pn = (const uint*)(f_nin + (size_t)s * 256);
    uint uni = pn[lane];        // f_ni[s]
    uint und = pn[64 + lane];   // f_node[s]
    uint* ep = (uint*)(ebp + (size_t)i * 128) + lane;
    uint ue = *ep;
    float v0 = b2f_lo(ue) + b2f_lo(uni) + nj0;
    float v1 = b2f_hi(ue) + b2f_hi(uni) + nj1;
    v0 = v0 >= 0.f ? v0 : 0.01f * v0;
    v1 = v1 >= 0.f ? v1 : 0.01f * v1;
    *ep = pk2(v0, v1);
    float p = v0 * at.x + v1 * at.y;
    p += __shfl_xor(p, 1);
    p += __shfl_xor(p, 2);
    p += __shfl_xor(p, 4);
    p += __shfl_xor(p, 8);            // all 16 lanes of head h hold the logit
    float ev = __expf(p);             // softmax shift-invariant; logits O(1)
    exsum += ev;
    acc0 = fmaf(b2f_lo(und), ev, acc0);
    acc1 = fmaf(b2f_hi(und), ev, acc1);
  }
  float inv = exsum > 0.f ? 1.f / exsum : 0.f;
  ((uint*)(nb + (size_t)d * 128))[lane] = pk2(acc0 * inv, acc1 * inv);
}

// ---------- light per-node combine (egat2): nb[d] = sum(f_node*ex)/sum(ex) ----------
__global__ void egat_gather2(const ushort* __restrict__ f_nin,
                             const float* __restrict__ ex,
                             const int* __restrict__ src_perm,
                             const int* __restrict__ rowptr,
                             ushort* __restrict__ nb, int N) {
  int d = blockIdx.x * 4 + (threadIdx.x >> 6);
  if (d >= N) return;
  int lane = threadIdx.x & 63;
  int lo = rowptr[d], hi = rowptr[d + 1];
  int h = lane >> 4;
  float acc0 = 0.f, acc1 = 0.f, exsum = 0.f;
  for (int i = lo; i < hi; ++i) {
    float ev = ex[(size_t)i * 4 + h];
    int s = src_perm[i];
    uint und = *((const uint*)(f_nin + (size_t)s * 256 + 128) + lane);  // f_node
    exsum += ev;
    acc0 = fmaf(b2f_lo(und), ev, acc0);
    acc1 = fmaf(b2f_hi(und), ev, acc1);
  }
  float inv = exsum > 0.f ? 1.f / exsum : 0.f;
  ((uint*)(nb + (size_t)d * 128))[lane] = pk2(acc0 * inv, acc1 * inv);
}

// ---------- node segsum (seq) + edge segsum (invperm gather), MERGED ----------
__global__ __launch_bounds__(256) void segsum_both(
    const ushort* __restrict__ nbX, const int* __restrict__ nid, int N, float* __restrict__ Sn,
    const ushort* __restrict__ ebX, const int* __restrict__ invperm,
    const int* __restrict__ eid, int E, float* __restrict__ Se, int NBn) {
  int t = threadIdx.x & 63;
  int wv = threadIdx.x >> 6;
  if ((int)blockIdx.x < NBn) {
    int r0 = (blockIdx.x * 4 + wv) * 32;
    if (r0 >= N) return;
    int r1 = r0 + 32; if (r1 > N) r1 = N;
    float a0 = 0.f, a1 = 0.f;
    int cur = nid[r0];
    for (int r = r0; r < r1; ++r) {
      int id = nid[r];
      if (id != cur) {
        atomicAdd(&Sn[(size_t)cur * 128 + 2 * t], a0);
        atomicAdd(&Sn[(size_t)cur * 128 + 2 * t + 1], a1);
        a0 = a1 = 0.f; cur = id;
      }
      uint u = *((const uint*)(nbX + (size_t)r * 128) + t);
      a0 += b2f_lo(u); a1 += b2f_hi(u);
    }
    atomicAdd(&Sn[(size_t)cur * 128 + 2 * t], a0);
    atomicAdd(&Sn[(size_t)cur * 128 + 2 * t + 1], a1);
  } else {
    int b = blockIdx.x - NBn;
    int r0 = (b * 4 + wv) * 16;
    if (r0 >= E) return;
    int r1 = r0 + 16; if (r1 > E) r1 = E;
    float a0 = 0.f, a1 = 0.f;
    int cur = eid[r0];
    for (int r = r0; r < r1; ++r) {
      int id = eid[r];
      if (id != cur) {
        atomicAdd(&Se[(size_t)cur * 128 + 2 * t], a0);
        atomicAdd(&Se[(size_t)cur * 128 + 2 * t + 1], a1);
        a0 = a1 = 0.f; cur = id;
      }
      uint u = *((const uint*)(ebX + (size_t)invperm[r] * 128) + t);
      a0 += b2f_lo(u); a1 += b2f_hi(u);
    }
    atomicAdd(&Se[(size_t)cur * 128 + 2 * t], a0);
    atomicAdd(&Se[(size_t)cur * 128 + 2 * t + 1], a1);
  }
}

// ---------- diff linears, node+edge MERGED: out[g] = (SP-SR)@W + cnt*b ----------
__global__ void diff_linear2(const float* __restrict__ SnP, const float* __restrict__ SnR,
                             const int* __restrict__ cn,
                             const float* __restrict__ Wn, const float* __restrict__ bn,
                             const float* __restrict__ SeP, const float* __restrict__ SeR,
                             const int* __restrict__ ce,
                             const float* __restrict__ We, const float* __restrict__ be,
                             float* __restrict__ out, int G) {
  int g = blockIdx.x;
  int t = threadIdx.x;
  bool is_e = g >= G; if (is_e) g -= G;
  const float* SP = is_e ? SeP : SnP;
  const float* SR = is_e ? SeR : SnR;
  const int* cnt  = is_e ? ce  : cn;
  const float* W  = is_e ? We  : Wn;
  const float* b  = is_e ? be  : bn;
  int coloff = is_e ? 128 : 0;
  __shared__ float xs[128];
  xs[t] = SP[(size_t)g * 128 + t] - SR[(size_t)g * 128 + t];
  __syncthreads();
  float acc = (float)cnt[g] * b[t];
  for (int k = 0; k < 128; ++k) acc = fmaf(xs[k], W[k * 128 + t], acc);
  out[(size_t)g * 256 + coloff + t] = acc;
}

template<int K, int NC, bool RELU>
__global__ void mlp_linear(const float* __restrict__ X, const float* __restrict__ W,
                           const float* __restrict__ b, float* __restrict__ Y) {
  int g = blockIdx.x;
  int t = threadIdx.x;
  __shared__ float xs[K];
  for (int i = t; i < K; i += NC) xs[i] = X[(size_t)g * K + i];
  __syncthreads();
  float acc = b[t];
  for (int k = 0; k < K; ++k) acc = fmaf(xs[k], W[k * NC + t], acc);
  if (RELU) acc = fmaxf(acc, 0.f);
  Y[(size_t)g * NC + t] = acc;
}

__global__ void mlp_final(const float* __restrict__ X, const float* __restrict__ W,
                          const float* __restrict__ b, float* __restrict__ out, int G) {
  int g = blockIdx.x * blockDim.x + threadIdx.x;
  if (g >= G) return;
  float acc = b[0];
  for (int k = 0; k < 256; ++k) acc = fmaf(X[(size_t)g * 256 + k], W[k], acc);
  out[g] = acc;
}

struct LayerW {
  const float *Wni, *bni, *Wnj, *bnj, *Wf, *bf, *Wnode, *bnode, *attn;
};

extern "C" void kernel_launch(void* const* d_in, const int* in_sizes, int n_in,
                              void* d_out, int out_size, void* d_ws, size_t ws_size,
                              hipStream_t stream) {
  const float* hR = (const float*)d_in[0];
  const float* eR = (const float*)d_in[1];
  const float* hP = (const float*)d_in[2];
  const float* eP = (const float*)d_in[3];
  const int* srcR = (const int*)d_in[4];
  const int* dstR = (const int*)d_in[5];
  const int* srcP = (const int*)d_in[6];
  const int* dstP = (const int*)d_in[7];
  const int* nid  = (const int*)d_in[8];
  const int* eid  = (const int*)d_in[9];
  LayerW w1 { (const float*)d_in[10], (const float*)d_in[11], (const float*)d_in[12],
              (const float*)d_in[13], (const float*)d_in[14], (const float*)d_in[15],
              (const float*)d_in[16], (const float*)d_in[17], (const float*)d_in[18] };
  LayerW w2 { (const float*)d_in[19], (const float*)d_in[20], (const float*)d_in[21],
              (const float*)d_in[22], (const float*)d_in[23], (const float*)d_in[24],
              (const float*)d_in[25], (const float*)d_in[26], (const float*)d_in[27] };
  const float* Wa_n = (const float*)d_in[28];
  const float* ba_n = (const float*)d_in[29];
  const float* Wa_e = (const float*)d_in[30];
  const float* ba_e = (const float*)d_in[31];
  const float* Wm1  = (const float*)d_in[32];
  const float* bm1  = (const float*)d_in[33];
  const float* Wm2  = (const float*)d_in[34];
  const float* bm2  = (const float*)d_in[35];
  const float* Wm3  = (const float*)d_in[36];
  const float* bm3  = (const float*)d_in[37];

  const int N = in_sizes[0] / 17;   // 60000
  const int E = in_sizes[4];        // 240000
  const int G = out_size;           // 1024

  // ---- workspace carve-up ----
  char* base = (char*)d_ws;
  size_t off = 0;
  auto alloc = [&](size_t bytes) { char* p = base + off; off += (bytes + 255) & ~(size_t)255; return p; };
  ushort* nb     = (ushort*)alloc((size_t)N * 128 * 2);   // node state bf16
  ushort* f_nin  = (ushort*)alloc((size_t)N * 256 * 2);   // [ni | node] fused rows
  ushort* f_nj   = (ushort*)alloc((size_t)N * 128 * 2);
  ushort* ebp    = (ushort*)alloc((size_t)E * 128 * 2);   // edge state bf16, dst-CSR order
  float*  ex     = (float*)alloc((size_t)E * 4 * 4);      // per-edge exp(logit), egat2 path
  int*    rowptrP = (int*)alloc((size_t)(N + 1) * 4);
  int*    rowptrR = (int*)alloc((size_t)(N + 1) * 4);
  int*    epermP  = (int*)alloc((size_t)E * 4);
  int*    epermR  = (int*)alloc((size_t)E * 4);
  int*    invpermP = (int*)alloc((size_t)E * 4);
  int*    invpermR = (int*)alloc((size_t)E * 4);
  int*    srcpermP = (int*)alloc((size_t)E * 4);
  int*    srcpermR = (int*)alloc((size_t)E * 4);
  int*    dstpermP = (int*)alloc((size_t)E * 4);
  int*    dstpermR = (int*)alloc((size_t)E * 4);
  int*    cursorP = (int*)alloc((size_t)N * 4);
  int*    cursorR = (int*)alloc((size_t)N * 4);
  int*    blocksumP = (int*)alloc(1024 * 4);
  int*    blocksumR = (int*)alloc(1024 * 4);
  ushort* Wt_ni  = (ushort*)alloc(128 * 128 * 2);
  ushort* Wt_nj  = (ushort*)alloc(128 * 128 * 2);
  ushort* Wt_f   = (ushort*)alloc(128 * 128 * 2);
  ushort* Wt_nd  = (ushort*)alloc(128 * 128 * 2);
  // ---- contiguous zero region: cntP, cntR, SnP, SnR, SeP, SeR ----
  size_t zoff0 = off;
  int*    cntP   = (int*)alloc((size_t)N * 4);
  int*    cntR   = (int*)alloc((size_t)N * 4);
  float*  SnP    = (float*)alloc((size_t)G * 128 * 4);
  float*  SnR    = (float*)alloc((size_t)G * 128 * 4);
  float*  SeP    = (float*)alloc((size_t)G * 128 * 4);
  float*  SeR    = (float*)alloc((size_t)G * 128 * 4);
  size_t zoff1 = off;
  float*  Gf     = (float*)alloc((size_t)G * 256 * 4);
  float*  x1     = (float*)alloc((size_t)G * 512 * 4);
  float*  x2     = (float*)alloc((size_t)G * 256 * 4);
  int*    cnt_n  = (int*)alloc((size_t)G * 4);
  int*    cnt_e  = (int*)alloc((size_t)G * 4);
  if (off > ws_size) return;  // graceful fail

  const int EB = (E + 255) / 256;   // 938
  const int NB = (N + 255) / 256;   // 235 <= 256, fits scan_block

  // ---- 1: zero cntP/cntR + all S accumulators in one launch ----
  int n16 = (int)((zoff1 - zoff0) / 16);
  fillz16<<<(n16 + 255) / 256, 256, 0, stream>>>((uint4*)(base + zoff0), n16);

  // ---- 2-6: CSR builds, P and R in parallel grids ----
  hist_dst2<<<2 * EB, 256, 0, stream>>>(dstP, cntP, dstR, cntR, E, EB);
  scan_local2<<<2 * NB, 256, 0, stream>>>(cntP, rowptrP, blocksumP, cntR, rowptrR, blocksumR, N, NB);
  scan_block2<<<2, 256, 0, stream>>>(blocksumP, blocksumR, NB);
  scan_add2<<<2 * NB, 256, 0, stream>>>(rowptrP, cursorP, blocksumP, rowptrR, cursorR, blocksumR, N, E, NB);
  scatter_idx2<<<2 * EB, 256, 0, stream>>>(dstP, srcP, cursorP, epermP, invpermP, srcpermP, dstpermP,
                                           dstR, srcR, cursorR, epermR, invpermR, srcpermR, dstpermR, E, EB);

  // ---- 7: prep egat2 weights ----
  prep_w4<<<4, 256, 0, stream>>>(w2.Wni, w2.Wnj, w2.Wf, w2.Wnode, Wt_ni, Wt_nj, Wt_f, Wt_nd);

  // ---- 8: per-graph counts (node + edge) ----
  const int GB1 = (G + 255) / 256;
  seg_cnt2<<<2 * GB1, 256, 0, stream>>>(nid, N, cnt_n, eid, E, cnt_e, G, GB1);

  const int GB  = (N + 3) / 4;       // gather grids
  const int NBn = (N + 127) / 128;   // segsum node blocks
  const int NBe = (E + 63) / 64;     // segsum edge blocks

  auto layer1 = [&](const float* h, const float* e, const int* eperm,
                    const int* src_perm, const int* rowptr) {
    lin3_small<17><<<(N + 15) / 16, 128, 0, stream>>>(h, w1.Wni, w1.bni, w1.Wnj, w1.bnj,
                                                      w1.Wnode, w1.bnode, f_nin, f_nj, N);
    lin1_perm<15><<<(E + 15) / 16, 128, 0, stream>>>(e, w1.Wf, w1.bf, eperm, ebp, E);
    egat_gather<<<GB, 256, 0, stream>>>(f_nin, f_nj, ebp, src_perm, rowptr, w1.attn, nb, N);
  };
  auto layer2 = [&](const int* src_perm, const int* dst_perm, const int* rowptr) {
    gemm3_k128<<<(N + 127) / 128, 256, 0, stream>>>(nb,
        Wt_ni, w2.bni,   f_nin,       256,
        Wt_nd, w2.bnode, f_nin + 128, 256,
        Wt_nj, w2.bnj,   f_nj,        128, N);
    gemm_edge_fused<<<(E + 63) / 64, 256, 0, stream>>>(ebp, Wt_f, w2.bf, f_nin, f_nj,
                                                       src_perm, dst_perm, w2.attn, ex, E);
    egat_gather2<<<GB, 256, 0, stream>>>(f_nin, ex, src_perm, rowptr, nb, N);
  };

  // ---- P branch ----
  layer1(hP, eP, epermP, srcpermP, rowptrP);
  segsum_both<<<NBn + NBe, 256, 0, stream>>>(nb, nid, N, SnP, ebp, invpermP, eid, E, SeP, NBn);

  // ---- R branch: egat1 + egat2 x2 ----
  layer1(hR, eR, epermR, srcpermR, rowptrR);
  layer2(srcpermR, dstpermR, rowptrR);
  layer2(srcpermR, dstpermR, rowptrR);
  segsum_both<<<NBn + NBe, 256, 0, stream>>>(nb, nid, N, SnR, ebp, invpermR, eid, E, SeR, NBn);

  // ---- Diff aggregate (node + edge in one launch) ----
  diff_linear2<<<2 * G, 128, 0, stream>>>(SnP, SnR, cnt_n, Wa_n, ba_n,
                                          SeP, SeR, cnt_e, Wa_e, ba_e, Gf, G);

  // ---- MLP head ----
  mlp_linear<256, 512, true><<<G, 512, 0, stream>>>(Gf, Wm1, bm1, x1);
  mlp_linear<512, 256, true><<<G, 256, 0, stream>>>(x1, Wm2, bm2, x2);
  mlp_final<<<(G + 255) / 256, 256, 0, stream>>>(x2, Wm3, bm3, (float*)d_out, G);
}

// Round 21
// 590.375 us; speedup vs baseline: 1.1519x; 1.0519x over previous
//
#include <hip/hip_runtime.h>
#include <cstddef>
#include <cstdint>

typedef unsigned int uint;
typedef unsigned short ushort;
typedef __attribute__((ext_vector_type(4))) float f32x4;
typedef __attribute__((ext_vector_type(8))) short short8;

// ---------- bf16 helpers (storage = ushort) ----------
__device__ __forceinline__ ushort f2b(float v) {
  uint x = __float_as_uint(v);
  return (ushort)((x + 0x7fffu + ((x >> 16) & 1u)) >> 16);  // RNE
}
__device__ __forceinline__ float b2f(ushort u) { return __uint_as_float(((uint)u) << 16); }
__device__ __forceinline__ float b2f_lo(uint u) { return __uint_as_float(u << 16); }
__device__ __forceinline__ float b2f_hi(uint u) { return __uint_as_float(u & 0xffff0000u); }
__device__ __forceinline__ uint pk2(float lo, float hi) {
  return (uint)f2b(lo) | ((uint)f2b(hi) << 16);
}
__device__ __forceinline__ uint pkadd(uint a, uint b) {
  return pk2(b2f_lo(a) + b2f_lo(b), b2f_hi(a) + b2f_hi(b));
}

__device__ __forceinline__ int lowerb(const int* __restrict__ ids, int M, int v) {
  int lo = 0, hi = M;
  while (lo < hi) { int mid = (lo + hi) >> 1; if (ids[mid] < v) lo = mid + 1; else hi = mid; }
  return lo;
}

// zero a contiguous 16B-aligned region
__global__ void fillz16(uint4* p, int n16) {
  int i = blockIdx.x * 256 + threadIdx.x;
  if (i < n16) p[i] = make_uint4(0, 0, 0, 0);
}

// ---------- CSR build, P and R merged per phase ----------
__global__ void hist_dst2(const int* __restrict__ dstP, int* __restrict__ cntP,
                          const int* __restrict__ dstR, int* __restrict__ cntR,
                          int E, int EB) {
  int b = blockIdx.x;
  const int* dst; int* cnt;
  if (b < EB) { dst = dstP; cnt = cntP; } else { dst = dstR; cnt = cntR; b -= EB; }
  int e = b * 256 + threadIdx.x;
  if (e < E) atomicAdd(&cnt[dst[e]], 1);
}

__global__ void scan_local2(const int* __restrict__ cntP, int* __restrict__ rowP, int* __restrict__ bsP,
                            const int* __restrict__ cntR, int* __restrict__ rowR, int* __restrict__ bsR,
                            int N, int NB) {
  __shared__ int tmp[256];
  int b = blockIdx.x;
  const int* cnt; int* rowptr; int* bs;
  if (b < NB) { cnt = cntP; rowptr = rowP; bs = bsP; }
  else        { cnt = cntR; rowptr = rowR; bs = bsR; b -= NB; }
  int t = threadIdx.x;
  int i = b * 256 + t;
  int v = (i < N) ? cnt[i] : 0;
  tmp[t] = v;
  __syncthreads();
  for (int ofs = 1; ofs < 256; ofs <<= 1) {
    int u = (t >= ofs) ? tmp[t - ofs] : 0;
    __syncthreads();
    tmp[t] += u;
    __syncthreads();
  }
  if (i < N) rowptr[i] = tmp[t] - v;          // exclusive
  if (t == 255) bs[b] = tmp[255];
}

__global__ void scan_block2(int* __restrict__ bsP, int* __restrict__ bsR, int n) {
  __shared__ int tmp[256];
  int* bs = (blockIdx.x == 0) ? bsP : bsR;
  int t = threadIdx.x;
  int v = (t < n) ? bs[t] : 0;
  tmp[t] = v;
  __syncthreads();
  for (int ofs = 1; ofs < 256; ofs <<= 1) {
    int u = (t >= ofs) ? tmp[t - ofs] : 0;
    __syncthreads();
    tmp[t] += u;
    __syncthreads();
  }
  if (t < n) bs[t] = tmp[t] - v;              // exclusive
}

__global__ void scan_add2(int* __restrict__ rowP, int* __restrict__ curP, const int* __restrict__ bsP,
                          int* __restrict__ rowR, int* __restrict__ curR, const int* __restrict__ bsR,
                          int N, int E, int NB) {
  int b = blockIdx.x;
  int* rowptr; int* cursor; const int* bs;
  if (b < NB) { rowptr = rowP; cursor = curP; bs = bsP; }
  else        { rowptr = rowR; cursor = curR; bs = bsR; b -= NB; }
  int i = b * 256 + threadIdx.x;
  if (i < N) {
    int v = rowptr[i] + bs[b];
    rowptr[i] = v;
    cursor[i] = v;
  }
  if (i == 0) rowptr[N] = E;
}

__global__ void scatter_idx2(
    const int* __restrict__ dstP, const int* __restrict__ srcP, int* __restrict__ curP,
    int* __restrict__ epP, int* __restrict__ ivP, int* __restrict__ spP, int* __restrict__ dpP,
    const int* __restrict__ dstR, const int* __restrict__ srcR, int* __restrict__ curR,
    int* __restrict__ epR, int* __restrict__ ivR, int* __restrict__ spR, int* __restrict__ dpR,
    int E, int EB) {
  int b = blockIdx.x;
  const int *dst, *src; int *cur, *ep, *iv, *sp, *dp;
  if (b < EB) { dst = dstP; src = srcP; cur = curP; ep = epP; iv = ivP; sp = spP; dp = dpP; }
  else { dst = dstR; src = srcR; cur = curR; ep = epR; iv = ivR; sp = spR; dp = dpR; b -= EB; }
  int e = b * 256 + threadIdx.x;
  if (e < E) {
    int d = dst[e];
    int p = atomicAdd(&cur[d], 1);
    ep[p] = e;
    iv[e] = p;
    sp[p] = src[e];
    dp[p] = d;
  }
}

// ---------- prep: 4x W[128][128] fp32 -> transposed, bf16, XOR-swizzled ----------
__global__ void prep_w4(const float* __restrict__ W0, const float* __restrict__ W1,
                        const float* __restrict__ W2, const float* __restrict__ W3,
                        ushort* __restrict__ T0, ushort* __restrict__ T1,
                        ushort* __restrict__ T2, ushort* __restrict__ T3) {
  const float* W = (blockIdx.x == 0) ? W0 : (blockIdx.x == 1) ? W1 : (blockIdx.x == 2) ? W2 : W3;
  ushort* T      = (blockIdx.x == 0) ? T0 : (blockIdx.x == 1) ? T1 : (blockIdx.x == 2) ? T2 : T3;
  int t = threadIdx.x;        // 256 threads
  int n = t >> 1;
  int k0 = (t & 1) * 64;
  uint sw = (uint)(n & 7) << 3;
  for (int kk = 0; kk < 64; ++kk) {
    int k = k0 + kk;
    T[n * 128 + (k ^ sw)] = f2b(W[k * 128 + n]);
  }
}

// ---------- per-graph counts, node+edge merged ----------
__global__ void seg_cnt2(const int* __restrict__ nid, int N, int* __restrict__ cn,
                         const int* __restrict__ eid, int E, int* __restrict__ ce,
                         int G, int GB1) {
  int b = blockIdx.x;
  if (b < GB1) {
    int g = b * 256 + threadIdx.x;
    if (g < G) cn[g] = lowerb(nid, N, g + 1) - lowerb(nid, N, g);
  } else {
    int g = (b - GB1) * 256 + threadIdx.x;
    if (g < G) ce[g] = lowerb(eid, E, g + 1) - lowerb(eid, E, g);
  }
}

// ---------- fused triple GEMM (node linears): stage A once, 3 weights ----------
__global__ __launch_bounds__(256) void gemm3_k128(
    const ushort* __restrict__ X,
    const ushort* __restrict__ Wt0, const float* __restrict__ b0, ushort* __restrict__ Y0, int ldy0,
    const ushort* __restrict__ Wt1, const float* __restrict__ b1, ushort* __restrict__ Y1, int ldy1,
    const ushort* __restrict__ Wt2, const float* __restrict__ b2, ushort* __restrict__ Y2, int ldy2,
    int M) {
  __shared__ ushort As[128 * 128];
  int t = threadIdx.x;
  int row0 = blockIdx.x * 128;

  { // stage A: linear bf16 copy, swizzled store
    int r = t >> 1;
    int k0h = (t & 1) * 64;
    int grow = row0 + r;
    uint sw = (uint)(r & 7) << 3;
    if (grow < M) {
      const ushort* xr = X + (size_t)grow * 128;
#pragma unroll
      for (int c = 0; c < 8; ++c) {
        int k0 = k0h + c * 8;
        *(uint4*)(As + r * 128 + (k0 ^ sw)) = *(const uint4*)(xr + k0);
      }
    } else {
      uint4 z = make_uint4(0, 0, 0, 0);
#pragma unroll
      for (int c = 0; c < 8; ++c) {
        int k0 = k0h + c * 8;
        *(uint4*)(As + r * 128 + (k0 ^ sw)) = z;
      }
    }
  }
  __syncthreads();

  int lane = t & 63;
  int wid = t >> 6;
  int wr = wid >> 1, wc = wid & 1;
  uint swl = (uint)(lane & 7) << 3;

#pragma unroll
  for (int w = 0; w < 3; ++w) {
    const ushort* Wt = (w == 0) ? Wt0 : (w == 1) ? Wt1 : Wt2;
    const float* bb  = (w == 0) ? b0  : (w == 1) ? b1  : b2;
    ushort* Y        = (w == 0) ? Y0  : (w == 1) ? Y1  : Y2;
    int ldy          = (w == 0) ? ldy0 : (w == 1) ? ldy1 : ldy2;

    f32x4 acc[4][4];
#pragma unroll
    for (int n4 = 0; n4 < 4; ++n4) {
      float bv = bb[wc * 64 + n4 * 16 + (lane & 15)];
#pragma unroll
      for (int m4 = 0; m4 < 4; ++m4) acc[m4][n4] = (f32x4){bv, bv, bv, bv};
    }
#pragma unroll
    for (int kk = 0; kk < 4; ++kk) {
      int kidx = kk * 32 + 8 * (lane >> 4);
      short8 af[4], bfr[4];
#pragma unroll
      for (int m4 = 0; m4 < 4; ++m4) {
        int rm = wr * 64 + m4 * 16 + (lane & 15);
        af[m4] = *(const short8*)(As + rm * 128 + (kidx ^ swl));
      }
#pragma unroll
      for (int n4 = 0; n4 < 4; ++n4) {
        int cn = wc * 64 + n4 * 16 + (lane & 15);
        bfr[n4] = *(const short8*)(Wt + cn * 128 + (kidx ^ swl));   // direct from L2
      }
#pragma unroll
      for (int m4 = 0; m4 < 4; ++m4)
#pragma unroll
        for (int n4 = 0; n4 < 4; ++n4)
          acc[m4][n4] = __builtin_amdgcn_mfma_f32_16x16x32_bf16(af[m4], bfr[n4], acc[m4][n4], 0, 0, 0);
    }
    int coln = wc * 64 + (lane & 15);
#pragma unroll
    for (int m4 = 0; m4 < 4; ++m4) {
      int rb = row0 + wr * 64 + m4 * 16 + ((lane >> 4) << 2);
#pragma unroll
      for (int n4 = 0; n4 < 4; ++n4) {
        int cc = coln + n4 * 16;
#pragma unroll
        for (int i = 0; i < 4; ++i)
          if (rb + i < M) Y[(size_t)(rb + i) * ldy + cc] = f2b(acc[m4][n4][i]);
      }
    }
  }
}

// ---------- fused edge GEMM + edge-stage (egat2), LDS time-shared ----------
static constexpr int NST = 132;
__global__ __launch_bounds__(256) void gemm_edge_fused(
    ushort* ebp, const ushort* __restrict__ Wt, const float* __restrict__ b,
    const ushort* __restrict__ f_nin, const ushort* __restrict__ f_nj,
    const int* __restrict__ src_perm, const int* __restrict__ dst_perm,
    const float* __restrict__ attn, float* __restrict__ ex, int E) {
  __shared__ ushort Buf[64 * NST];   // 16.9 KB, As then NN
  int t = threadIdx.x;
  int row0 = blockIdx.x * 64;
  int r = t >> 2, q = t & 3;
  int grow_st = row0 + r;
  uint sw = (uint)(r & 7) << 3;

  { // phase A: stage As (swizzled, stride 128)
    if (grow_st < E) {
      const ushort* xr = ebp + (size_t)grow_st * 128;
#pragma unroll
      for (int c = 0; c < 4; ++c) {
        int k0 = q * 32 + c * 8;
        *(uint4*)(Buf + r * 128 + (k0 ^ sw)) = *(const uint4*)(xr + k0);
      }
    } else {
      uint4 z = make_uint4(0, 0, 0, 0);
#pragma unroll
      for (int c = 0; c < 4; ++c) {
        int k0 = q * 32 + c * 8;
        *(uint4*)(Buf + r * 128 + (k0 ^ sw)) = z;
      }
    }
  }
  __syncthreads();

  int lane = t & 63;
  int wid = t >> 6;
  int wr = wid >> 1, wc = wid & 1;     // 2x2 waves of 32 rows x 64 cols
  uint swl = (uint)(lane & 7) << 3;

  f32x4 acc[2][4];
#pragma unroll
  for (int n4 = 0; n4 < 4; ++n4) {
    float bv = b[wc * 64 + n4 * 16 + (lane & 15)];
#pragma unroll
    for (int m4 = 0; m4 < 2; ++m4) acc[m4][n4] = (f32x4){bv, bv, bv, bv};
  }
#pragma unroll
  for (int kk = 0; kk < 4; ++kk) {
    int kidx = kk * 32 + 8 * (lane >> 4);
    short8 af[2], bfr[4];
#pragma unroll
    for (int m4 = 0; m4 < 2; ++m4) {
      int rm = wr * 32 + m4 * 16 + (lane & 15);
      af[m4] = *(const short8*)(Buf + rm * 128 + (kidx ^ swl));
    }
#pragma unroll
    for (int n4 = 0; n4 < 4; ++n4) {
      int cn = wc * 64 + n4 * 16 + (lane & 15);
      bfr[n4] = *(const short8*)(Wt + cn * 128 + (kidx ^ swl));   // direct from L2
    }
#pragma unroll
    for (int m4 = 0; m4 < 2; ++m4)
#pragma unroll
      for (int n4 = 0; n4 < 4; ++n4)
        acc[m4][n4] = __builtin_amdgcn_mfma_f32_16x16x32_bf16(af[m4], bfr[n4], acc[m4][n4], 0, 0, 0);
  }
  __syncthreads();                      // As reads done

  { // phase B: restage Buf as NN = bf16(ni+nj), stride NST
    if (grow_st < E) {
      int s = src_perm[grow_st], d = dst_perm[grow_st];
      const ushort* nir = f_nin + (size_t)s * 256;
      const ushort* njr = f_nj + (size_t)d * 128;
#pragma unroll
      for (int c = 0; c < 4; ++c) {
        int k0 = q * 32 + c * 8;
        uint4 ua = *(const uint4*)(nir + k0);
        uint4 ub = *(const uint4*)(njr + k0);
        uint4 o;
        o.x = pkadd(ua.x, ub.x); o.y = pkadd(ua.y, ub.y);
        o.z = pkadd(ua.z, ub.z); o.w = pkadd(ua.w, ub.w);
        *(uint4*)(Buf + r * NST + k0) = o;
      }
    }
  }
  __syncthreads();

  float at4[4];
#pragma unroll
  for (int n4 = 0; n4 < 4; ++n4) at4[n4] = attn[wc * 64 + n4 * 16 + (lane & 15)];

#pragma unroll
  for (int m4 = 0; m4 < 2; ++m4) {
#pragma unroll
    for (int i = 0; i < 4; ++i) {
      int row = wr * 32 + m4 * 16 + ((lane >> 4) << 2) + i;
      int grow = row0 + row;
      float ph0 = 0.f, ph1 = 0.f;
      if (grow < E) {
#pragma unroll
        for (int n4 = 0; n4 < 4; ++n4) {
          int col = wc * 64 + n4 * 16 + (lane & 15);
          float v = acc[m4][n4][i] + b2f(Buf[row * NST + col]);
          v = v >= 0.f ? v : 0.01f * v;
          ebp[(size_t)grow * 128 + col] = f2b(v);
          float p = v * at4[n4];
          if (n4 < 2) ph0 += p; else ph1 += p;
        }
      }
      ph0 += __shfl_xor(ph0, 1); ph0 += __shfl_xor(ph0, 2);
      ph0 += __shfl_xor(ph0, 4); ph0 += __shfl_xor(ph0, 8);
      ph1 += __shfl_xor(ph1, 1); ph1 += __shfl_xor(ph1, 2);
      ph1 += __shfl_xor(ph1, 4); ph1 += __shfl_xor(ph1, 8);
      if ((lane & 15) == 0 && grow < E) {
        ex[(size_t)grow * 4 + wc * 2 + 0] = __expf(ph0);
        ex[(size_t)grow * 4 + wc * 2 + 1] = __expf(ph1);
      }
    }
  }
}

// ---------- layer-1 fused node linears (R15-proven) ----------
template<int K>
__global__ __launch_bounds__(128) void lin3_small(const float* __restrict__ X,
    const float* __restrict__ W1, const float* __restrict__ b1,
    const float* __restrict__ W2, const float* __restrict__ b2,
    const float* __restrict__ W3, const float* __restrict__ b3,
    ushort* __restrict__ Ynin, ushort* __restrict__ Ynj, int M) {
  constexpr int ROWS = 16;
  __shared__ float xs[ROWS * K];
  int t = threadIdx.x;
  int row0 = blockIdx.x * ROWS;
  int nr = M - row0; if (nr > ROWS) nr = ROWS;
  for (int i = t; i < nr * K; i += 128) xs[i] = X[(size_t)row0 * K + i];
  __syncthreads();
  float a1[ROWS], a2[ROWS], a3[ROWS];
  float v1 = b1[t], v2 = b2[t], v3 = b3[t];
#pragma unroll
  for (int r = 0; r < ROWS; ++r) { a1[r] = v1; a2[r] = v2; a3[r] = v3; }
#pragma unroll
  for (int k = 0; k < K; ++k) {
    float w1 = W1[k * 128 + t], w2 = W2[k * 128 + t], w3 = W3[k * 128 + t];
#pragma unroll
    for (int r = 0; r < ROWS; ++r) {
      float x = xs[r * K + k];
      a1[r] = fmaf(x, w1, a1[r]);
      a2[r] = fmaf(x, w2, a2[r]);
      a3[r] = fmaf(x, w3, a3[r]);
    }
  }
  for (int r = 0; r < nr; ++r) {
    size_t n = (size_t)(row0 + r);
    Ynin[n * 256 + t] = f2b(a1[r]);        // f_ni
    Ynin[n * 256 + 128 + t] = f2b(a3[r]);  // f_node
    Ynj[n * 128 + t] = f2b(a2[r]);
  }
}

// ---------- layer-1 edge linear (K=15), perm order (R15-proven) ----------
template<int K>
__global__ __launch_bounds__(128) void lin1_perm(const float* __restrict__ X,
    const float* __restrict__ W, const float* __restrict__ b,
    const int* __restrict__ eperm, ushort* __restrict__ Y, int M) {
  constexpr int ROWS = 16;
  __shared__ float xs[ROWS * K];
  __shared__ int es[ROWS];
  int t = threadIdx.x;
  int row0 = blockIdx.x * ROWS;
  int nr = M - row0; if (nr > ROWS) nr = ROWS;
  if (t < nr) es[t] = eperm[row0 + t];
  __syncthreads();
  for (int i = t; i < nr * K; i += 128) {
    int r = i / K, c = i - r * K;
    xs[i] = X[(size_t)es[r] * K + c];
  }
  __syncthreads();
  float acc[ROWS];
  float bias = b[t];
#pragma unroll
  for (int r = 0; r < ROWS; ++r) acc[r] = bias;
#pragma unroll
  for (int k = 0; k < K; ++k) {
    float w = W[k * 128 + t];
#pragma unroll
    for (int r = 0; r < ROWS; ++r) acc[r] = fmaf(xs[r * K + k], w, acc[r]);
  }
  for (int r = 0; r < nr; ++r) Y[(size_t)(row0 + r) * 128 + t] = f2b(acc[r]);
}

// ---------- layer-1 fused edge+aggregate (CSR over dst), 2-edge pipelined ----------
__global__ void egat_gather(const ushort* __restrict__ f_nin,   // [N][256] = ni | node
                            const ushort* __restrict__ f_nj,    // [N][128]
                            ushort* ebp,                         // [E][128] perm order, in/out
                            const int* __restrict__ src_perm,
                            const int* __restrict__ rowptr,
                            const float* __restrict__ attn,
                            ushort* __restrict__ nb, int N) {
  int d = blockIdx.x * 4 + (threadIdx.x >> 6);
  if (d >= N) return;
  int lane = threadIdx.x & 63;
  int lo = rowptr[d], hi = rowptr[d + 1];
  int h = lane >> 4;
  float2 at = *(const float2*)(attn + h * 32 + (lane & 15) * 2);
  uint unj = *((const uint*)(f_nj + (size_t)d * 128) + lane);
  float nj0 = b2f_lo(unj), nj1 = b2f_hi(unj);
  float acc0 = 0.f, acc1 = 0.f, exsum = 0.f;

  int i = lo;
  for (; i + 1 < hi; i += 2) {
    // issue both edges' loads up front (2x memory-level parallelism)
    int s0 = src_perm[i], s1 = src_perm[i + 1];
    const uint* pn0 = (const uint*)(f_nin + (size_t)s0 * 256);
    const uint* pn1 = (const uint*)(f_nin + (size_t)s1 * 256);
    uint uniA = pn0[lane];
    uint undA = pn0[64 + lane];
    uint uniB = pn1[lane];
    uint undB = pn1[64 + lane];
    uint* epA = (uint*)(ebp + (size_t)i * 128) + lane;
    uint* epB = (uint*)(ebp + (size_t)(i + 1) * 128) + lane;
    uint ueA = *epA;
    uint ueB = *epB;

    // edge i
    float v0 = b2f_lo(ueA) + b2f_lo(uniA) + nj0;
    float v1 = b2f_hi(ueA) + b2f_hi(uniA) + nj1;
    v0 = v0 >= 0.f ? v0 : 0.01f * v0;
    v1 = v1 >= 0.f ? v1 : 0.01f * v1;
    *epA = pk2(v0, v1);
    float p = v0 * at.x + v1 * at.y;
    p += __shfl_xor(p, 1); p += __shfl_xor(p, 2);
    p += __shfl_xor(p, 4); p += __shfl_xor(p, 8);
    float ev = __expf(p);
    exsum += ev;
    acc0 = fmaf(b2f_lo(undA), ev, acc0);
    acc1 = fmaf(b2f_hi(undA), ev, acc1);

    // edge i+1
    v0 = b2f_lo(ueB) + b2f_lo(uniB) + nj0;
    v1 = b2f_hi(ueB) + b2f_hi(uniB) + nj1;
    v0 = v0 >= 0.f ? v0 : 0.01f * v0;
    v1 = v1 >= 0.f ? v1 : 0.01f * v1;
    *epB = pk2(v0, v1);
    p = v0 * at.x + v1 * at.y;
    p += __shfl_xor(p, 1); p += __shfl_xor(p, 2);
    p += __shfl_xor(p, 4); p += __shfl_xor(p, 8);
    ev = __expf(p);
    exsum += ev;
    acc0 = fmaf(b2f_lo(undB), ev, acc0);
    acc1 = fmaf(b2f_hi(undB), ev, acc1);
  }
  if (i < hi) {   // remainder edge
    int s = src_perm[i];
    const uint* pn = (const uint*)(f_nin + (size_t)s * 256);
    uint uni = pn[lane];
    uint und = pn[64 + lane];
    uint* ep = (uint*)(ebp + (size_t)i * 128) + lane;
    uint ue = *ep;
    float v0 = b2f_lo(ue) + b2f_lo(uni) + nj0;
    float v1 = b2f_hi(ue) + b2f_hi(uni) + nj1;
    v0 = v0 >= 0.f ? v0 : 0.01f * v0;
    v1 = v1 >= 0.f ? v1 : 0.01f * v1;
    *ep = pk2(v0, v1);
    float p = v0 * at.x + v1 * at.y;
    p += __shfl_xor(p, 1); p += __shfl_xor(p, 2);
    p += __shfl_xor(p, 4); p += __shfl_xor(p, 8);
    float ev = __expf(p);
    exsum += ev;
    acc0 = fmaf(b2f_lo(und), ev, acc0);
    acc1 = fmaf(b2f_hi(und), ev, acc1);
  }
  float inv = exsum > 0.f ? 1.f / exsum : 0.f;
  ((uint*)(nb + (size_t)d * 128))[lane] = pk2(acc0 * inv, acc1 * inv);
}

// ---------- light per-node combine (egat2), 2-edge pipelined ----------
__global__ void egat_gather2(const ushort* __restrict__ f_nin,
                             const float* __restrict__ ex,
                             const int* __restrict__ src_perm,
                             const int* __restrict__ rowptr,
                             ushort* __restrict__ nb, int N) {
  int d = blockIdx.x * 4 + (threadIdx.x >> 6);
  if (d >= N) return;
  int lane = threadIdx.x & 63;
  int lo = rowptr[d], hi = rowptr[d + 1];
  int h = lane >> 4;
  float acc0 = 0.f, acc1 = 0.f, exsum = 0.f;

  int i = lo;
  for (; i + 1 < hi; i += 2) {
    float evA = ex[(size_t)i * 4 + h];
    float evB = ex[(size_t)(i + 1) * 4 + h];
    int s0 = src_perm[i], s1 = src_perm[i + 1];
    uint undA = *((const uint*)(f_nin + (size_t)s0 * 256 + 128) + lane);
    uint undB = *((const uint*)(f_nin + (size_t)s1 * 256 + 128) + lane);
    exsum += evA;
    acc0 = fmaf(b2f_lo(undA), evA, acc0);
    acc1 = fmaf(b2f_hi(undA), evA, acc1);
    exsum += evB;
    acc0 = fmaf(b2f_lo(undB), evB, acc0);
    acc1 = fmaf(b2f_hi(undB), evB, acc1);
  }
  if (i < hi) {
    float ev = ex[(size_t)i * 4 + h];
    int s = src_perm[i];
    uint und = *((const uint*)(f_nin + (size_t)s * 256 + 128) + lane);
    exsum += ev;
    acc0 = fmaf(b2f_lo(und), ev, acc0);
    acc1 = fmaf(b2f_hi(und), ev, acc1);
  }
  float inv = exsum > 0.f ? 1.f / exsum : 0.f;
  ((uint*)(nb + (size_t)d * 128))[lane] = pk2(acc0 * inv, acc1 * inv);
}

// ---------- node segsum (seq) + edge segsum (invperm gather), MERGED ----------
__global__ __launch_bounds__(256) void segsum_both(
    const ushort* __restrict__ nbX, const int* __restrict__ nid, int N, float* __restrict__ Sn,
    const ushort* __restrict__ ebX, const int* __restrict__ invperm,
    const int* __restrict__ eid, int E, float* __restrict__ Se, int NBn) {
  int t = threadIdx.x & 63;
  int wv = threadIdx.x >> 6;
  if ((int)blockIdx.x < NBn) {
    int r0 = (blockIdx.x * 4 + wv) * 32;
    if (r0 >= N) return;
    int r1 = r0 + 32; if (r1 > N) r1 = N;
    float a0 = 0.f, a1 = 0.f;
    int cur = nid[r0];
    for (int r = r0; r < r1; ++r) {
      int id = nid[r];
      if (id != cur) {
        atomicAdd(&Sn[(size_t)cur * 128 + 2 * t], a0);
        atomicAdd(&Sn[(size_t)cur * 128 + 2 * t + 1], a1);
        a0 = a1 = 0.f; cur = id;
      }
      uint u = *((const uint*)(nbX + (size_t)r * 128) + t);
      a0 += b2f_lo(u); a1 += b2f_hi(u);
    }
    atomicAdd(&Sn[(size_t)cur * 128 + 2 * t], a0);
    atomicAdd(&Sn[(size_t)cur * 128 + 2 * t + 1], a1);
  } else {
    int b = blockIdx.x - NBn;
    int r0 = (b * 4 + wv) * 16;
    if (r0 >= E) return;
    int r1 = r0 + 16; if (r1 > E) r1 = E;
    float a0 = 0.f, a1 = 0.f;
    int cur = eid[r0];
    for (int r = r0; r < r1; ++r) {
      int id = eid[r];
      if (id != cur) {
        atomicAdd(&Se[(size_t)cur * 128 + 2 * t], a0);
        atomicAdd(&Se[(size_t)cur * 128 + 2 * t + 1], a1);
        a0 = a1 = 0.f; cur = id;
      }
      uint u = *((const uint*)(ebX + (size_t)invperm[r] * 128) + t);
      a0 += b2f_lo(u); a1 += b2f_hi(u);
    }
    atomicAdd(&Se[(size_t)cur * 128 + 2 * t], a0);
    atomicAdd(&Se[(size_t)cur * 128 + 2 * t + 1], a1);
  }
}

// ---------- diff linears, node+edge MERGED: out[g] = (SP-SR)@W + cnt*b ----------
__global__ void diff_linear2(const float* __restrict__ SnP, const float* __restrict__ SnR,
                             const int* __restrict__ cn,
                             const float* __restrict__ Wn, const float* __restrict__ bn,
                             const float* __restrict__ SeP, const float* __restrict__ SeR,
                             const int* __restrict__ ce,
                             const float* __restrict__ We, const float* __restrict__ be,
                             float* __restrict__ out, int G) {
  int g = blockIdx.x;
  int t = threadIdx.x;
  bool is_e = g >= G; if (is_e) g -= G;
  const float* SP = is_e ? SeP : SnP;
  const float* SR = is_e ? SeR : SnR;
  const int* cnt  = is_e ? ce  : cn;
  const float* W  = is_e ? We  : Wn;
  const float* b  = is_e ? be  : bn;
  int coloff = is_e ? 128 : 0;
  __shared__ float xs[128];
  xs[t] = SP[(size_t)g * 128 + t] - SR[(size_t)g * 128 + t];
  __syncthreads();
  float acc = (float)cnt[g] * b[t];
  for (int k = 0; k < 128; ++k) acc = fmaf(xs[k], W[k * 128 + t], acc);
  out[(size_t)g * 256 + coloff + t] = acc;
}

template<int K, int NC, bool RELU>
__global__ void mlp_linear(const float* __restrict__ X, const float* __restrict__ W,
                           const float* __restrict__ b, float* __restrict__ Y) {
  int g = blockIdx.x;
  int t = threadIdx.x;
  __shared__ float xs[K];
  for (int i = t; i < K; i += NC) xs[i] = X[(size_t)g * K + i];
  __syncthreads();
  float acc = b[t];
  for (int k = 0; k < K; ++k) acc = fmaf(xs[k], W[k * NC + t], acc);
  if (RELU) acc = fmaxf(acc, 0.f);
  Y[(size_t)g * NC + t] = acc;
}

__global__ void mlp_final(const float* __restrict__ X, const float* __restrict__ W,
                          const float* __restrict__ b, float* __restrict__ out, int G) {
  int g = blockIdx.x * blockDim.x + threadIdx.x;
  if (g >= G) return;
  float acc = b[0];
  for (int k = 0; k < 256; ++k) acc = fmaf(X[(size_t)g * 256 + k], W[k], acc);
  out[g] = acc;
}

struct LayerW {
  const float *Wni, *bni, *Wnj, *bnj, *Wf, *bf, *Wnode, *bnode, *attn;
};

extern "C" void kernel_launch(void* const* d_in, const int* in_sizes, int n_in,
                              void* d_out, int out_size, void* d_ws, size_t ws_size,
                              hipStream_t stream) {
  const float* hR = (const float*)d_in[0];
  const float* eR = (const float*)d_in[1];
  const float* hP = (const float*)d_in[2];
  const float* eP = (const float*)d_in[3];
  const int* srcR = (const int*)d_in[4];
  const int* dstR = (const int*)d_in[5];
  const int* srcP = (const int*)d_in[6];
  const int* dstP = (const int*)d_in[7];
  const int* nid  = (const int*)d_in[8];
  const int* eid  = (const int*)d_in[9];
  LayerW w1 { (const float*)d_in[10], (const float*)d_in[11], (const float*)d_in[12],
              (const float*)d_in[13], (const float*)d_in[14], (const float*)d_in[15],
              (const float*)d_in[16], (const float*)d_in[17], (const float*)d_in[18] };
  LayerW w2 { (const float*)d_in[19], (const float*)d_in[20], (const float*)d_in[21],
              (const float*)d_in[22], (const float*)d_in[23], (const float*)d_in[24],
              (const float*)d_in[25], (const float*)d_in[26], (const float*)d_in[27] };
  const float* Wa_n = (const float*)d_in[28];
  const float* ba_n = (const float*)d_in[29];
  const float* Wa_e = (const float*)d_in[30];
  const float* ba_e = (const float*)d_in[31];
  const float* Wm1  = (const float*)d_in[32];
  const float* bm1  = (const float*)d_in[33];
  const float* Wm2  = (const float*)d_in[34];
  const float* bm2  = (const float*)d_in[35];
  const float* Wm3  = (const float*)d_in[36];
  const float* bm3  = (const float*)d_in[37];

  const int N = in_sizes[0] / 17;   // 60000
  const int E = in_sizes[4];        // 240000
  const int G = out_size;           // 1024

  // ---- workspace carve-up ----
  char* base = (char*)d_ws;
  size_t off = 0;
  auto alloc = [&](size_t bytes) { char* p = base + off; off += (bytes + 255) & ~(size_t)255; return p; };
  ushort* nb     = (ushort*)alloc((size_t)N * 128 * 2);   // node state bf16
  ushort* f_nin  = (ushort*)alloc((size_t)N * 256 * 2);   // [ni | node] fused rows
  ushort* f_nj   = (ushort*)alloc((size_t)N * 128 * 2);
  ushort* ebp    = (ushort*)alloc((size_t)E * 128 * 2);   // edge state bf16, dst-CSR order
  float*  ex     = (float*)alloc((size_t)E * 4 * 4);      // per-edge exp(logit), egat2 path
  int*    rowptrP = (int*)alloc((size_t)(N + 1) * 4);
  int*    rowptrR = (int*)alloc((size_t)(N + 1) * 4);
  int*    epermP  = (int*)alloc((size_t)E * 4);
  int*    epermR  = (int*)alloc((size_t)E * 4);
  int*    invpermP = (int*)alloc((size_t)E * 4);
  int*    invpermR = (int*)alloc((size_t)E * 4);
  int*    srcpermP = (int*)alloc((size_t)E * 4);
  int*    srcpermR = (int*)alloc((size_t)E * 4);
  int*    dstpermP = (int*)alloc((size_t)E * 4);
  int*    dstpermR = (int*)alloc((size_t)E * 4);
  int*    cursorP = (int*)alloc((size_t)N * 4);
  int*    cursorR = (int*)alloc((size_t)N * 4);
  int*    blocksumP = (int*)alloc(1024 * 4);
  int*    blocksumR = (int*)alloc(1024 * 4);
  ushort* Wt_ni  = (ushort*)alloc(128 * 128 * 2);
  ushort* Wt_nj  = (ushort*)alloc(128 * 128 * 2);
  ushort* Wt_f   = (ushort*)alloc(128 * 128 * 2);
  ushort* Wt_nd  = (ushort*)alloc(128 * 128 * 2);
  // ---- contiguous zero region: cntP, cntR, SnP, SnR, SeP, SeR ----
  size_t zoff0 = off;
  int*    cntP   = (int*)alloc((size_t)N * 4);
  int*    cntR   = (int*)alloc((size_t)N * 4);
  float*  SnP    = (float*)alloc((size_t)G * 128 * 4);
  float*  SnR    = (float*)alloc((size_t)G * 128 * 4);
  float*  SeP    = (float*)alloc((size_t)G * 128 * 4);
  float*  SeR    = (float*)alloc((size_t)G * 128 * 4);
  size_t zoff1 = off;
  float*  Gf     = (float*)alloc((size_t)G * 256 * 4);
  float*  x1     = (float*)alloc((size_t)G * 512 * 4);
  float*  x2     = (float*)alloc((size_t)G * 256 * 4);
  int*    cnt_n  = (int*)alloc((size_t)G * 4);
  int*    cnt_e  = (int*)alloc((size_t)G * 4);
  if (off > ws_size) return;  // graceful fail

  const int EB = (E + 255) / 256;   // 938
  const int NB = (N + 255) / 256;   // 235 <= 256, fits scan_block

  // ---- 1: zero cntP/cntR + all S accumulators in one launch ----
  int n16 = (int)((zoff1 - zoff0) / 16);
  fillz16<<<(n16 + 255) / 256, 256, 0, stream>>>((uint4*)(base + zoff0), n16);

  // ---- 2-6: CSR builds, P and R in parallel grids ----
  hist_dst2<<<2 * EB, 256, 0, stream>>>(dstP, cntP, dstR, cntR, E, EB);
  scan_local2<<<2 * NB, 256, 0, stream>>>(cntP, rowptrP, blocksumP, cntR, rowptrR, blocksumR, N, NB);
  scan_block2<<<2, 256, 0, stream>>>(blocksumP, blocksumR, NB);
  scan_add2<<<2 * NB, 256, 0, stream>>>(rowptrP, cursorP, blocksumP, rowptrR, cursorR, blocksumR, N, E, NB);
  scatter_idx2<<<2 * EB, 256, 0, stream>>>(dstP, srcP, cursorP, epermP, invpermP, srcpermP, dstpermP,
                                           dstR, srcR, cursorR, epermR, invpermR, srcpermR, dstpermR, E, EB);

  // ---- 7: prep egat2 weights ----
  prep_w4<<<4, 256, 0, stream>>>(w2.Wni, w2.Wnj, w2.Wf, w2.Wnode, Wt_ni, Wt_nj, Wt_f, Wt_nd);

  // ---- 8: per-graph counts (node + edge) ----
  const int GB1 = (G + 255) / 256;
  seg_cnt2<<<2 * GB1, 256, 0, stream>>>(nid, N, cnt_n, eid, E, cnt_e, G, GB1);

  const int GB  = (N + 3) / 4;       // gather grids
  const int NBn = (N + 127) / 128;   // segsum node blocks
  const int NBe = (E + 63) / 64;     // segsum edge blocks

  auto layer1 = [&](const float* h, const float* e, const int* eperm,
                    const int* src_perm, const int* rowptr) {
    lin3_small<17><<<(N + 15) / 16, 128, 0, stream>>>(h, w1.Wni, w1.bni, w1.Wnj, w1.bnj,
                                                      w1.Wnode, w1.bnode, f_nin, f_nj, N);
    lin1_perm<15><<<(E + 15) / 16, 128, 0, stream>>>(e, w1.Wf, w1.bf, eperm, ebp, E);
    egat_gather<<<GB, 256, 0, stream>>>(f_nin, f_nj, ebp, src_perm, rowptr, w1.attn, nb, N);
  };
  auto layer2 = [&](const int* src_perm, const int* dst_perm, const int* rowptr) {
    gemm3_k128<<<(N + 127) / 128, 256, 0, stream>>>(nb,
        Wt_ni, w2.bni,   f_nin,       256,
        Wt_nd, w2.bnode, f_nin + 128, 256,
        Wt_nj, w2.bnj,   f_nj,        128, N);
    gemm_edge_fused<<<(E + 63) / 64, 256, 0, stream>>>(ebp, Wt_f, w2.bf, f_nin, f_nj,
                                                       src_perm, dst_perm, w2.attn, ex, E);
    egat_gather2<<<GB, 256, 0, stream>>>(f_nin, ex, src_perm, rowptr, nb, N);
  };

  // ---- P branch ----
  layer1(hP, eP, epermP, srcpermP, rowptrP);
  segsum_both<<<NBn + NBe, 256, 0, stream>>>(nb, nid, N, SnP, ebp, invpermP, eid, E, SeP, NBn);

  // ---- R branch: egat1 + egat2 x2 ----
  layer1(hR, eR, epermR, srcpermR, rowptrR);
  layer2(srcpermR, dstpermR, rowptrR);
  layer2(srcpermR, dstpermR, rowptrR);
  segsum_both<<<NBn + NBe, 256, 0, stream>>>(nb, nid, N, SnR, ebp, invpermR, eid, E, SeR, NBn);

  // ---- Diff aggregate (node + edge in one launch) ----
  diff_linear2<<<2 * G, 128, 0, stream>>>(SnP, SnR, cnt_n, Wa_n, ba_n,
                                          SeP, SeR, cnt_e, Wa_e, ba_e, Gf, G);

  // ---- MLP head ----
  mlp_linear<256, 512, true><<<G, 512, 0, stream>>>(Gf, Wm1, bm1, x1);
  mlp_linear<512, 256, true><<<G, 256, 0, stream>>>(x1, Wm2, bm2, x2);
  mlp_final<<<(G + 255) / 256, 256, 0, stream>>>(x2, Wm3, bm3, (float*)d_out, G);
}

// Round 22
// 589.553 us; speedup vs baseline: 1.1535x; 1.0014x over previous
//
#include <hip/hip_runtime.h>
#include <cstddef>
#include <cstdint>

typedef unsigned int uint;
typedef unsigned short ushort;
typedef __attribute__((ext_vector_type(4))) float f32x4;
typedef __attribute__((ext_vector_type(8))) short short8;

// ---------- bf16 helpers (storage = ushort) ----------
__device__ __forceinline__ ushort f2b(float v) {
  uint x = __float_as_uint(v);
  return (ushort)((x + 0x7fffu + ((x >> 16) & 1u)) >> 16);  // RNE
}
__device__ __forceinline__ float b2f(ushort u) { return __uint_as_float(((uint)u) << 16); }
__device__ __forceinline__ float b2f_lo(uint u) { return __uint_as_float(u << 16); }
__device__ __forceinline__ float b2f_hi(uint u) { return __uint_as_float(u & 0xffff0000u); }
__device__ __forceinline__ uint pk2(float lo, float hi) {
  return (uint)f2b(lo) | ((uint)f2b(hi) << 16);
}
__device__ __forceinline__ uint pkadd(uint a, uint b) {
  return pk2(b2f_lo(a) + b2f_lo(b), b2f_hi(a) + b2f_hi(b));
}

__device__ __forceinline__ int lowerb(const int* __restrict__ ids, int M, int v) {
  int lo = 0, hi = M;
  while (lo < hi) { int mid = (lo + hi) >> 1; if (ids[mid] < v) lo = mid + 1; else hi = mid; }
  return lo;
}

// zero a contiguous 16B-aligned region
__global__ void fillz16(uint4* p, int n16) {
  int i = blockIdx.x * 256 + threadIdx.x;
  if (i < n16) p[i] = make_uint4(0, 0, 0, 0);
}

// ---------- CSR build, P and R merged per phase ----------
__global__ void hist_dst2(const int* __restrict__ dstP, int* __restrict__ cntP,
                          const int* __restrict__ dstR, int* __restrict__ cntR,
                          int E, int EB) {
  int b = blockIdx.x;
  const int* dst; int* cnt;
  if (b < EB) { dst = dstP; cnt = cntP; } else { dst = dstR; cnt = cntR; b -= EB; }
  int e = b * 256 + threadIdx.x;
  if (e < E) atomicAdd(&cnt[dst[e]], 1);
}

__global__ void scan_local2(const int* __restrict__ cntP, int* __restrict__ rowP, int* __restrict__ bsP,
                            const int* __restrict__ cntR, int* __restrict__ rowR, int* __restrict__ bsR,
                            int N, int NB) {
  __shared__ int tmp[256];
  int b = blockIdx.x;
  const int* cnt; int* rowptr; int* bs;
  if (b < NB) { cnt = cntP; rowptr = rowP; bs = bsP; }
  else        { cnt = cntR; rowptr = rowR; bs = bsR; b -= NB; }
  int t = threadIdx.x;
  int i = b * 256 + t;
  int v = (i < N) ? cnt[i] : 0;
  tmp[t] = v;
  __syncthreads();
  for (int ofs = 1; ofs < 256; ofs <<= 1) {
    int u = (t >= ofs) ? tmp[t - ofs] : 0;
    __syncthreads();
    tmp[t] += u;
    __syncthreads();
  }
  if (i < N) rowptr[i] = tmp[t] - v;          // exclusive
  if (t == 255) bs[b] = tmp[255];
}

__global__ void scan_block2(int* __restrict__ bsP, int* __restrict__ bsR, int n) {
  __shared__ int tmp[256];
  int* bs = (blockIdx.x == 0) ? bsP : bsR;
  int t = threadIdx.x;
  int v = (t < n) ? bs[t] : 0;
  tmp[t] = v;
  __syncthreads();
  for (int ofs = 1; ofs < 256; ofs <<= 1) {
    int u = (t >= ofs) ? tmp[t - ofs] : 0;
    __syncthreads();
    tmp[t] += u;
    __syncthreads();
  }
  if (t < n) bs[t] = tmp[t] - v;              // exclusive
}

__global__ void scan_add2(int* __restrict__ rowP, int* __restrict__ curP, const int* __restrict__ bsP,
                          int* __restrict__ rowR, int* __restrict__ curR, const int* __restrict__ bsR,
                          int N, int E, int NB) {
  int b = blockIdx.x;
  int* rowptr; int* cursor; const int* bs;
  if (b < NB) { rowptr = rowP; cursor = curP; bs = bsP; }
  else        { rowptr = rowR; cursor = curR; bs = bsR; b -= NB; }
  int i = b * 256 + threadIdx.x;
  if (i < N) {
    int v = rowptr[i] + bs[b];
    rowptr[i] = v;
    cursor[i] = v;
  }
  if (i == 0) rowptr[N] = E;
}

__global__ void scatter_idx2(
    const int* __restrict__ dstP, const int* __restrict__ srcP, int* __restrict__ curP,
    int* __restrict__ epP, int* __restrict__ ivP, int* __restrict__ spP, int* __restrict__ dpP,
    const int* __restrict__ dstR, const int* __restrict__ srcR, int* __restrict__ curR,
    int* __restrict__ epR, int* __restrict__ ivR, int* __restrict__ spR, int* __restrict__ dpR,
    int E, int EB) {
  int b = blockIdx.x;
  const int *dst, *src; int *cur, *ep, *iv, *sp, *dp;
  if (b < EB) { dst = dstP; src = srcP; cur = curP; ep = epP; iv = ivP; sp = spP; dp = dpP; }
  else { dst = dstR; src = srcR; cur = curR; ep = epR; iv = ivR; sp = spR; dp = dpR; b -= EB; }
  int e = b * 256 + threadIdx.x;
  if (e < E) {
    int d = dst[e];
    int p = atomicAdd(&cur[d], 1);
    ep[p] = e;
    iv[e] = p;
    sp[p] = src[e];
    dp[p] = d;
  }
}

// ---------- prep: 4x W[128][128] fp32 -> transposed, bf16, XOR-swizzled ----------
__global__ void prep_w4(const float* __restrict__ W0, const float* __restrict__ W1,
                        const float* __restrict__ W2, const float* __restrict__ W3,
                        ushort* __restrict__ T0, ushort* __restrict__ T1,
                        ushort* __restrict__ T2, ushort* __restrict__ T3) {
  const float* W = (blockIdx.x == 0) ? W0 : (blockIdx.x == 1) ? W1 : (blockIdx.x == 2) ? W2 : W3;
  ushort* T      = (blockIdx.x == 0) ? T0 : (blockIdx.x == 1) ? T1 : (blockIdx.x == 2) ? T2 : T3;
  int t = threadIdx.x;        // 256 threads
  int n = t >> 1;
  int k0 = (t & 1) * 64;
  uint sw = (uint)(n & 7) << 3;
  for (int kk = 0; kk < 64; ++kk) {
    int k = k0 + kk;
    T[n * 128 + (k ^ sw)] = f2b(W[k * 128 + n]);
  }
}

// ---------- per-graph counts, node+edge merged ----------
__global__ void seg_cnt2(const int* __restrict__ nid, int N, int* __restrict__ cn,
                         const int* __restrict__ eid, int E, int* __restrict__ ce,
                         int G, int GB1) {
  int b = blockIdx.x;
  if (b < GB1) {
    int g = b * 256 + threadIdx.x;
    if (g < G) cn[g] = lowerb(nid, N, g + 1) - lowerb(nid, N, g);
  } else {
    int g = (b - GB1) * 256 + threadIdx.x;
    if (g < G) ce[g] = lowerb(eid, E, g + 1) - lowerb(eid, E, g);
  }
}

// ---------- fused triple GEMM (node linears): stage A once, 3 weights ----------
__global__ __launch_bounds__(256) void gemm3_k128(
    const ushort* __restrict__ X,
    const ushort* __restrict__ Wt0, const float* __restrict__ b0, ushort* __restrict__ Y0, int ldy0,
    const ushort* __restrict__ Wt1, const float* __restrict__ b1, ushort* __restrict__ Y1, int ldy1,
    const ushort* __restrict__ Wt2, const float* __restrict__ b2, ushort* __restrict__ Y2, int ldy2,
    int M) {
  __shared__ ushort As[128 * 128];
  int t = threadIdx.x;
  int row0 = blockIdx.x * 128;

  { // stage A: linear bf16 copy, swizzled store
    int r = t >> 1;
    int k0h = (t & 1) * 64;
    int grow = row0 + r;
    uint sw = (uint)(r & 7) << 3;
    if (grow < M) {
      const ushort* xr = X + (size_t)grow * 128;
#pragma unroll
      for (int c = 0; c < 8; ++c) {
        int k0 = k0h + c * 8;
        *(uint4*)(As + r * 128 + (k0 ^ sw)) = *(const uint4*)(xr + k0);
      }
    } else {
      uint4 z = make_uint4(0, 0, 0, 0);
#pragma unroll
      for (int c = 0; c < 8; ++c) {
        int k0 = k0h + c * 8;
        *(uint4*)(As + r * 128 + (k0 ^ sw)) = z;
      }
    }
  }
  __syncthreads();

  int lane = t & 63;
  int wid = t >> 6;
  int wr = wid >> 1, wc = wid & 1;
  uint swl = (uint)(lane & 7) << 3;

#pragma unroll
  for (int w = 0; w < 3; ++w) {
    const ushort* Wt = (w == 0) ? Wt0 : (w == 1) ? Wt1 : Wt2;
    const float* bb  = (w == 0) ? b0  : (w == 1) ? b1  : b2;
    ushort* Y        = (w == 0) ? Y0  : (w == 1) ? Y1  : Y2;
    int ldy          = (w == 0) ? ldy0 : (w == 1) ? ldy1 : ldy2;

    f32x4 acc[4][4];
#pragma unroll
    for (int n4 = 0; n4 < 4; ++n4) {
      float bv = bb[wc * 64 + n4 * 16 + (lane & 15)];
#pragma unroll
      for (int m4 = 0; m4 < 4; ++m4) acc[m4][n4] = (f32x4){bv, bv, bv, bv};
    }
#pragma unroll
    for (int kk = 0; kk < 4; ++kk) {
      int kidx = kk * 32 + 8 * (lane >> 4);
      short8 af[4], bfr[4];
#pragma unroll
      for (int m4 = 0; m4 < 4; ++m4) {
        int rm = wr * 64 + m4 * 16 + (lane & 15);
        af[m4] = *(const short8*)(As + rm * 128 + (kidx ^ swl));
      }
#pragma unroll
      for (int n4 = 0; n4 < 4; ++n4) {
        int cn = wc * 64 + n4 * 16 + (lane & 15);
        bfr[n4] = *(const short8*)(Wt + cn * 128 + (kidx ^ swl));   // direct from L2
      }
#pragma unroll
      for (int m4 = 0; m4 < 4; ++m4)
#pragma unroll
        for (int n4 = 0; n4 < 4; ++n4)
          acc[m4][n4] = __builtin_amdgcn_mfma_f32_16x16x32_bf16(af[m4], bfr[n4], acc[m4][n4], 0, 0, 0);
    }
    int coln = wc * 64 + (lane & 15);
#pragma unroll
    for (int m4 = 0; m4 < 4; ++m4) {
      int rb = row0 + wr * 64 + m4 * 16 + ((lane >> 4) << 2);
#pragma unroll
      for (int n4 = 0; n4 < 4; ++n4) {
        int cc = coln + n4 * 16;
#pragma unroll
        for (int i = 0; i < 4; ++i)
          if (rb + i < M) Y[(size_t)(rb + i) * ldy + cc] = f2b(acc[m4][n4][i]);
      }
    }
  }
}

// ---------- fused edge GEMM + edge-stage (egat2), LDS time-shared ----------
// T14 async-STAGE split: ni/nj gather loads issued BEFORE the MFMA phase
// (in flight under As-stage + MFMA); only pkadd + LDS write after barrier.
static constexpr int NST = 132;
__global__ __launch_bounds__(256) void gemm_edge_fused(
    ushort* ebp, const ushort* __restrict__ Wt, const float* __restrict__ b,
    const ushort* __restrict__ f_nin, const ushort* __restrict__ f_nj,
    const int* __restrict__ src_perm, const int* __restrict__ dst_perm,
    const float* __restrict__ attn, float* __restrict__ ex, int E) {
  __shared__ ushort Buf[64 * NST];   // 16.9 KB, As then NN
  int t = threadIdx.x;
  int row0 = blockIdx.x * 64;
  int r = t >> 2, q = t & 3;
  int grow_st = row0 + r;
  uint sw = (uint)(r & 7) << 3;

  // issue phase-B gather loads EARLY (hide latency under As stage + MFMA)
  uint4 ua[4], ub[4];
  if (grow_st < E) {
    int s = src_perm[grow_st], d = dst_perm[grow_st];
    const ushort* nir = f_nin + (size_t)s * 256;
    const ushort* njr = f_nj + (size_t)d * 128;
#pragma unroll
    for (int c = 0; c < 4; ++c) {
      int k0 = q * 32 + c * 8;
      ua[c] = *(const uint4*)(nir + k0);
      ub[c] = *(const uint4*)(njr + k0);
    }
  }

  { // phase A: stage As (swizzled, stride 128)
    if (grow_st < E) {
      const ushort* xr = ebp + (size_t)grow_st * 128;
#pragma unroll
      for (int c = 0; c < 4; ++c) {
        int k0 = q * 32 + c * 8;
        *(uint4*)(Buf + r * 128 + (k0 ^ sw)) = *(const uint4*)(xr + k0);
      }
    } else {
      uint4 z = make_uint4(0, 0, 0, 0);
#pragma unroll
      for (int c = 0; c < 4; ++c) {
        int k0 = q * 32 + c * 8;
        *(uint4*)(Buf + r * 128 + (k0 ^ sw)) = z;
      }
    }
  }
  __syncthreads();

  int lane = t & 63;
  int wid = t >> 6;
  int wr = wid >> 1, wc = wid & 1;     // 2x2 waves of 32 rows x 64 cols
  uint swl = (uint)(lane & 7) << 3;

  f32x4 acc[2][4];
#pragma unroll
  for (int n4 = 0; n4 < 4; ++n4) {
    float bv = b[wc * 64 + n4 * 16 + (lane & 15)];
#pragma unroll
    for (int m4 = 0; m4 < 2; ++m4) acc[m4][n4] = (f32x4){bv, bv, bv, bv};
  }
#pragma unroll
  for (int kk = 0; kk < 4; ++kk) {
    int kidx = kk * 32 + 8 * (lane >> 4);
    short8 af[2], bfr[4];
#pragma unroll
    for (int m4 = 0; m4 < 2; ++m4) {
      int rm = wr * 32 + m4 * 16 + (lane & 15);
      af[m4] = *(const short8*)(Buf + rm * 128 + (kidx ^ swl));
    }
#pragma unroll
    for (int n4 = 0; n4 < 4; ++n4) {
      int cn = wc * 64 + n4 * 16 + (lane & 15);
      bfr[n4] = *(const short8*)(Wt + cn * 128 + (kidx ^ swl));   // direct from L2
    }
#pragma unroll
    for (int m4 = 0; m4 < 2; ++m4)
#pragma unroll
      for (int n4 = 0; n4 < 4; ++n4)
        acc[m4][n4] = __builtin_amdgcn_mfma_f32_16x16x32_bf16(af[m4], bfr[n4], acc[m4][n4], 0, 0, 0);
  }
  __syncthreads();                      // As reads done

  { // phase B (write-late): NN = bf16(ni+nj) from prefetched regs, stride NST
    if (grow_st < E) {
#pragma unroll
      for (int c = 0; c < 4; ++c) {
        int k0 = q * 32 + c * 8;
        uint4 o;
        o.x = pkadd(ua[c].x, ub[c].x); o.y = pkadd(ua[c].y, ub[c].y);
        o.z = pkadd(ua[c].z, ub[c].z); o.w = pkadd(ua[c].w, ub[c].w);
        *(uint4*)(Buf + r * NST + k0) = o;
      }
    }
  }
  __syncthreads();

  float at4[4];
#pragma unroll
  for (int n4 = 0; n4 < 4; ++n4) at4[n4] = attn[wc * 64 + n4 * 16 + (lane & 15)];

#pragma unroll
  for (int m4 = 0; m4 < 2; ++m4) {
#pragma unroll
    for (int i = 0; i < 4; ++i) {
      int row = wr * 32 + m4 * 16 + ((lane >> 4) << 2) + i;
      int grow = row0 + row;
      float ph0 = 0.f, ph1 = 0.f;
      if (grow < E) {
#pragma unroll
        for (int n4 = 0; n4 < 4; ++n4) {
          int col = wc * 64 + n4 * 16 + (lane & 15);
          float v = acc[m4][n4][i] + b2f(Buf[row * NST + col]);
          v = v >= 0.f ? v : 0.01f * v;
          ebp[(size_t)grow * 128 + col] = f2b(v);
          float p = v * at4[n4];
          if (n4 < 2) ph0 += p; else ph1 += p;
        }
      }
      ph0 += __shfl_xor(ph0, 1); ph0 += __shfl_xor(ph0, 2);
      ph0 += __shfl_xor(ph0, 4); ph0 += __shfl_xor(ph0, 8);
      ph1 += __shfl_xor(ph1, 1); ph1 += __shfl_xor(ph1, 2);
      ph1 += __shfl_xor(ph1, 4); ph1 += __shfl_xor(ph1, 8);
      if ((lane & 15) == 0 && grow < E) {
        ex[(size_t)grow * 4 + wc * 2 + 0] = __expf(ph0);
        ex[(size_t)grow * 4 + wc * 2 + 1] = __expf(ph1);
      }
    }
  }
}

// ---------- layer-1 fused node linears (R15-proven) ----------
template<int K>
__global__ __launch_bounds__(128) void lin3_small(const float* __restrict__ X,
    const float* __restrict__ W1, const float* __restrict__ b1,
    const float* __restrict__ W2, const float* __restrict__ b2,
    const float* __restrict__ W3, const float* __restrict__ b3,
    ushort* __restrict__ Ynin, ushort* __restrict__ Ynj, int M) {
  constexpr int ROWS = 16;
  __shared__ float xs[ROWS * K];
  int t = threadIdx.x;
  int row0 = blockIdx.x * ROWS;
  int nr = M - row0; if (nr > ROWS) nr = ROWS;
  for (int i = t; i < nr * K; i += 128) xs[i] = X[(size_t)row0 * K + i];
  __syncthreads();
  float a1[ROWS], a2[ROWS], a3[ROWS];
  float v1 = b1[t], v2 = b2[t], v3 = b3[t];
#pragma unroll
  for (int r = 0; r < ROWS; ++r) { a1[r] = v1; a2[r] = v2; a3[r] = v3; }
#pragma unroll
  for (int k = 0; k < K; ++k) {
    float w1 = W1[k * 128 + t], w2 = W2[k * 128 + t], w3 = W3[k * 128 + t];
#pragma unroll
    for (int r = 0; r < ROWS; ++r) {
      float x = xs[r * K + k];
      a1[r] = fmaf(x, w1, a1[r]);
      a2[r] = fmaf(x, w2, a2[r]);
      a3[r] = fmaf(x, w3, a3[r]);
    }
  }
  for (int r = 0; r < nr; ++r) {
    size_t n = (size_t)(row0 + r);
    Ynin[n * 256 + t] = f2b(a1[r]);        // f_ni
    Ynin[n * 256 + 128 + t] = f2b(a3[r]);  // f_node
    Ynj[n * 128 + t] = f2b(a2[r]);
  }
}

// ---------- layer-1 edge linear (K=15), perm order (R15-proven) ----------
template<int K>
__global__ __launch_bounds__(128) void lin1_perm(const float* __restrict__ X,
    const float* __restrict__ W, const float* __restrict__ b,
    const int* __restrict__ eperm, ushort* __restrict__ Y, int M) {
  constexpr int ROWS = 16;
  __shared__ float xs[ROWS * K];
  __shared__ int es[ROWS];
  int t = threadIdx.x;
  int row0 = blockIdx.x * ROWS;
  int nr = M - row0; if (nr > ROWS) nr = ROWS;
  if (t < nr) es[t] = eperm[row0 + t];
  __syncthreads();
  for (int i = t; i < nr * K; i += 128) {
    int r = i / K, c = i - r * K;
    xs[i] = X[(size_t)es[r] * K + c];
  }
  __syncthreads();
  float acc[ROWS];
  float bias = b[t];
#pragma unroll
  for (int r = 0; r < ROWS; ++r) acc[r] = bias;
#pragma unroll
  for (int k = 0; k < K; ++k) {
    float w = W[k * 128 + t];
#pragma unroll
    for (int r = 0; r < ROWS; ++r) acc[r] = fmaf(xs[r * K + k], w, acc[r]);
  }
  for (int r = 0; r < nr; ++r) Y[(size_t)(row0 + r) * 128 + t] = f2b(acc[r]);
}

// ---------- layer-1 fused edge+aggregate (CSR over dst), 2-edge pipelined ----------
__global__ void egat_gather(const ushort* __restrict__ f_nin,   // [N][256] = ni | node
                            const ushort* __restrict__ f_nj,    // [N][128]
                            ushort* ebp,                         // [E][128] perm order, in/out
                            const int* __restrict__ src_perm,
                            const int* __restrict__ rowptr,
                            const float* __restrict__ attn,
                            ushort* __restrict__ nb, int N) {
  int d = blockIdx.x * 4 + (threadIdx.x >> 6);
  if (d >= N) return;
  int lane = threadIdx.x & 63;
  int lo = rowptr[d], hi = rowptr[d + 1];
  int h = lane >> 4;
  float2 at = *(const float2*)(attn + h * 32 + (lane & 15) * 2);
  uint unj = *((const uint*)(f_nj + (size_t)d * 128) + lane);
  float nj0 = b2f_lo(unj), nj1 = b2f_hi(unj);
  float acc0 = 0.f, acc1 = 0.f, exsum = 0.f;

  int i = lo;
  for (; i + 1 < hi; i += 2) {
    int s0 = src_perm[i], s1 = src_perm[i + 1];
    const uint* pn0 = (const uint*)(f_nin + (size_t)s0 * 256);
    const uint* pn1 = (const uint*)(f_nin + (size_t)s1 * 256);
    uint uniA = pn0[lane];
    uint undA = pn0[64 + lane];
    uint uniB = pn1[lane];
    uint undB = pn1[64 + lane];
    uint* epA = (uint*)(ebp + (size_t)i * 128) + lane;
    uint* epB = (uint*)(ebp + (size_t)(i + 1) * 128) + lane;
    uint ueA = *epA;
    uint ueB = *epB;

    float v0 = b2f_lo(ueA) + b2f_lo(uniA) + nj0;
    float v1 = b2f_hi(ueA) + b2f_hi(uniA) + nj1;
    v0 = v0 >= 0.f ? v0 : 0.01f * v0;
    v1 = v1 >= 0.f ? v1 : 0.01f * v1;
    *epA = pk2(v0, v1);
    float p = v0 * at.x + v1 * at.y;
    p += __shfl_xor(p, 1); p += __shfl_xor(p, 2);
    p += __shfl_xor(p, 4); p += __shfl_xor(p, 8);
    float ev = __expf(p);
    exsum += ev;
    acc0 = fmaf(b2f_lo(undA), ev, acc0);
    acc1 = fmaf(b2f_hi(undA), ev, acc1);

    v0 = b2f_lo(ueB) + b2f_lo(uniB) + nj0;
    v1 = b2f_hi(ueB) + b2f_hi(uniB) + nj1;
    v0 = v0 >= 0.f ? v0 : 0.01f * v0;
    v1 = v1 >= 0.f ? v1 : 0.01f * v1;
    *epB = pk2(v0, v1);
    p = v0 * at.x + v1 * at.y;
    p += __shfl_xor(p, 1); p += __shfl_xor(p, 2);
    p += __shfl_xor(p, 4); p += __shfl_xor(p, 8);
    ev = __expf(p);
    exsum += ev;
    acc0 = fmaf(b2f_lo(undB), ev, acc0);
    acc1 = fmaf(b2f_hi(undB), ev, acc1);
  }
  if (i < hi) {
    int s = src_perm[i];
    const uint* pn = (const uint*)(f_nin + (size_t)s * 256);
    uint uni = pn[lane];
    uint und = pn[64 + lane];
    uint* ep = (uint*)(ebp + (size_t)i * 128) + lane;
    uint ue = *ep;
    float v0 = b2f_lo(ue) + b2f_lo(uni) + nj0;
    float v1 = b2f_hi(ue) + b2f_hi(uni) + nj1;
    v0 = v0 >= 0.f ? v0 : 0.01f * v0;
    v1 = v1 >= 0.f ? v1 : 0.01f * v1;
    *ep = pk2(v0, v1);
    float p = v0 * at.x + v1 * at.y;
    p += __shfl_xor(p, 1); p += __shfl_xor(p, 2);
    p += __shfl_xor(p, 4); p += __shfl_xor(p, 8);
    float ev = __expf(p);
    exsum += ev;
    acc0 = fmaf(b2f_lo(und), ev, acc0);
    acc1 = fmaf(b2f_hi(und), ev, acc1);
  }
  float inv = exsum > 0.f ? 1.f / exsum : 0.f;
  ((uint*)(nb + (size_t)d * 128))[lane] = pk2(acc0 * inv, acc1 * inv);
}

// ---------- light per-node combine (egat2), 2-edge pipelined ----------
__global__ void egat_gather2(const ushort* __restrict__ f_nin,
                             const float* __restrict__ ex,
                             const int* __restrict__ src_perm,
                             const int* __restrict__ rowptr,
                             ushort* __restrict__ nb, int N) {
  int d = blockIdx.x * 4 + (threadIdx.x >> 6);
  if (d >= N) return;
  int lane = threadIdx.x & 63;
  int lo = rowptr[d], hi = rowptr[d + 1];
  int h = lane >> 4;
  float acc0 = 0.f, acc1 = 0.f, exsum = 0.f;

  int i = lo;
  for (; i + 1 < hi; i += 2) {
    float evA = ex[(size_t)i * 4 + h];
    float evB = ex[(size_t)(i + 1) * 4 + h];
    int s0 = src_perm[i], s1 = src_perm[i + 1];
    uint undA = *((const uint*)(f_nin + (size_t)s0 * 256 + 128) + lane);
    uint undB = *((const uint*)(f_nin + (size_t)s1 * 256 + 128) + lane);
    exsum += evA;
    acc0 = fmaf(b2f_lo(undA), evA, acc0);
    acc1 = fmaf(b2f_hi(undA), evA, acc1);
    exsum += evB;
    acc0 = fmaf(b2f_lo(undB), evB, acc0);
    acc1 = fmaf(b2f_hi(undB), evB, acc1);
  }
  if (i < hi) {
    float ev = ex[(size_t)i * 4 + h];
    int s = src_perm[i];
    uint und = *((const uint*)(f_nin + (size_t)s * 256 + 128) + lane);
    exsum += ev;
    acc0 = fmaf(b2f_lo(und), ev, acc0);
    acc1 = fmaf(b2f_hi(und), ev, acc1);
  }
  float inv = exsum > 0.f ? 1.f / exsum : 0.f;
  ((uint*)(nb + (size_t)d * 128))[lane] = pk2(acc0 * inv, acc1 * inv);
}

// ---------- node segsum (seq) + edge segsum (invperm gather), MERGED ----------
__global__ __launch_bounds__(256) void segsum_both(
    const ushort* __restrict__ nbX, const int* __restrict__ nid, int N, float* __restrict__ Sn,
    const ushort* __restrict__ ebX, const int* __restrict__ invperm,
    const int* __restrict__ eid, int E, float* __restrict__ Se, int NBn) {
  int t = threadIdx.x & 63;
  int wv = threadIdx.x >> 6;
  if ((int)blockIdx.x < NBn) {
    int r0 = (blockIdx.x * 4 + wv) * 32;
    if (r0 >= N) return;
    int r1 = r0 + 32; if (r1 > N) r1 = N;
    float a0 = 0.f, a1 = 0.f;
    int cur = nid[r0];
    for (int r = r0; r < r1; ++r) {
      int id = nid[r];
      if (id != cur) {
        atomicAdd(&Sn[(size_t)cur * 128 + 2 * t], a0);
        atomicAdd(&Sn[(size_t)cur * 128 + 2 * t + 1], a1);
        a0 = a1 = 0.f; cur = id;
      }
      uint u = *((const uint*)(nbX + (size_t)r * 128) + t);
      a0 += b2f_lo(u); a1 += b2f_hi(u);
    }
    atomicAdd(&Sn[(size_t)cur * 128 + 2 * t], a0);
    atomicAdd(&Sn[(size_t)cur * 128 + 2 * t + 1], a1);
  } else {
    int b = blockIdx.x - NBn;
    int r0 = (b * 4 + wv) * 16;
    if (r0 >= E) return;
    int r1 = r0 + 16; if (r1 > E) r1 = E;
    float a0 = 0.f, a1 = 0.f;
    int cur = eid[r0];
    for (int r = r0; r < r1; ++r) {
      int id = eid[r];
      if (id != cur) {
        atomicAdd(&Se[(size_t)cur * 128 + 2 * t], a0);
        atomicAdd(&Se[(size_t)cur * 128 + 2 * t + 1], a1);
        a0 = a1 = 0.f; cur = id;
      }
      uint u = *((const uint*)(ebX + (size_t)invperm[r] * 128) + t);
      a0 += b2f_lo(u); a1 += b2f_hi(u);
    }
    atomicAdd(&Se[(size_t)cur * 128 + 2 * t], a0);
    atomicAdd(&Se[(size_t)cur * 128 + 2 * t + 1], a1);
  }
}

// ---------- diff linears, node+edge MERGED: out[g] = (SP-SR)@W + cnt*b ----------
__global__ void diff_linear2(const float* __restrict__ SnP, const float* __restrict__ SnR,
                             const int* __restrict__ cn,
                             const float* __restrict__ Wn, const float* __restrict__ bn,
                             const float* __restrict__ SeP, const float* __restrict__ SeR,
                             const int* __restrict__ ce,
                             const float* __restrict__ We, const float* __restrict__ be,
                             float* __restrict__ out, int G) {
  int g = blockIdx.x;
  int t = threadIdx.x;
  bool is_e = g >= G; if (is_e) g -= G;
  const float* SP = is_e ? SeP : SnP;
  const float* SR = is_e ? SeR : SnR;
  const int* cnt  = is_e ? ce  : cn;
  const float* W  = is_e ? We  : Wn;
  const float* b  = is_e ? be  : bn;
  int coloff = is_e ? 128 : 0;
  __shared__ float xs[128];
  xs[t] = SP[(size_t)g * 128 + t] - SR[(size_t)g * 128 + t];
  __syncthreads();
  float acc = (float)cnt[g] * b[t];
  for (int k = 0; k < 128; ++k) acc = fmaf(xs[k], W[k * 128 + t], acc);
  out[(size_t)g * 256 + coloff + t] = acc;
}

template<int K, int NC, bool RELU>
__global__ void mlp_linear(const float* __restrict__ X, const float* __restrict__ W,
                           const float* __restrict__ b, float* __restrict__ Y) {
  int g = blockIdx.x;
  int t = threadIdx.x;
  __shared__ float xs[K];
  for (int i = t; i < K; i += NC) xs[i] = X[(size_t)g * K + i];
  __syncthreads();
  float acc = b[t];
  for (int k = 0; k < K; ++k) acc = fmaf(xs[k], W[k * NC + t], acc);
  if (RELU) acc = fmaxf(acc, 0.f);
  Y[(size_t)g * NC + t] = acc;
}

__global__ void mlp_final(const float* __restrict__ X, const float* __restrict__ W,
                          const float* __restrict__ b, float* __restrict__ out, int G) {
  int g = blockIdx.x * blockDim.x + threadIdx.x;
  if (g >= G) return;
  float acc = b[0];
  for (int k = 0; k < 256; ++k) acc = fmaf(X[(size_t)g * 256 + k], W[k], acc);
  out[g] = acc;
}

struct LayerW {
  const float *Wni, *bni, *Wnj, *bnj, *Wf, *bf, *Wnode, *bnode, *attn;
};

extern "C" void kernel_launch(void* const* d_in, const int* in_sizes, int n_in,
                              void* d_out, int out_size, void* d_ws, size_t ws_size,
                              hipStream_t stream) {
  const float* hR = (const float*)d_in[0];
  const float* eR = (const float*)d_in[1];
  const float* hP = (const float*)d_in[2];
  const float* eP = (const float*)d_in[3];
  const int* srcR = (const int*)d_in[4];
  const int* dstR = (const int*)d_in[5];
  const int* srcP = (const int*)d_in[6];
  const int* dstP = (const int*)d_in[7];
  const int* nid  = (const int*)d_in[8];
  const int* eid  = (const int*)d_in[9];
  LayerW w1 { (const float*)d_in[10], (const float*)d_in[11], (const float*)d_in[12],
              (const float*)d_in[13], (const float*)d_in[14], (const float*)d_in[15],
              (const float*)d_in[16], (const float*)d_in[17], (const float*)d_in[18] };
  LayerW w2 { (const float*)d_in[19], (const float*)d_in[20], (const float*)d_in[21],
              (const float*)d_in[22], (const float*)d_in[23], (const float*)d_in[24],
              (const float*)d_in[25], (const float*)d_in[26], (const float*)d_in[27] };
  const float* Wa_n = (const float*)d_in[28];
  const float* ba_n = (const float*)d_in[29];
  const float* Wa_e = (const float*)d_in[30];
  const float* ba_e = (const float*)d_in[31];
  const float* Wm1  = (const float*)d_in[32];
  const float* bm1  = (const float*)d_in[33];
  const float* Wm2  = (const float*)d_in[34];
  const float* bm2  = (const float*)d_in[35];
  const float* Wm3  = (const float*)d_in[36];
  const float* bm3  = (const float*)d_in[37];

  const int N = in_sizes[0] / 17;   // 60000
  const int E = in_sizes[4];        // 240000
  const int G = out_size;           // 1024

  // ---- workspace carve-up ----
  char* base = (char*)d_ws;
  size_t off = 0;
  auto alloc = [&](size_t bytes) { char* p = base + off; off += (bytes + 255) & ~(size_t)255; return p; };
  ushort* nb     = (ushort*)alloc((size_t)N * 128 * 2);   // node state bf16
  ushort* f_nin  = (ushort*)alloc((size_t)N * 256 * 2);   // [ni | node] fused rows
  ushort* f_nj   = (ushort*)alloc((size_t)N * 128 * 2);
  ushort* ebp    = (ushort*)alloc((size_t)E * 128 * 2);   // edge state bf16, dst-CSR order
  float*  ex     = (float*)alloc((size_t)E * 4 * 4);      // per-edge exp(logit), egat2 path
  int*    rowptrP = (int*)alloc((size_t)(N + 1) * 4);
  int*    rowptrR = (int*)alloc((size_t)(N + 1) * 4);
  int*    epermP  = (int*)alloc((size_t)E * 4);
  int*    epermR  = (int*)alloc((size_t)E * 4);
  int*    invpermP = (int*)alloc((size_t)E * 4);
  int*    invpermR = (int*)alloc((size_t)E * 4);
  int*    srcpermP = (int*)alloc((size_t)E * 4);
  int*    srcpermR = (int*)alloc((size_t)E * 4);
  int*    dstpermP = (int*)alloc((size_t)E * 4);
  int*    dstpermR = (int*)alloc((size_t)E * 4);
  int*    cursorP = (int*)alloc((size_t)N * 4);
  int*    cursorR = (int*)alloc((size_t)N * 4);
  int*    blocksumP = (int*)alloc(1024 * 4);
  int*    blocksumR = (int*)alloc(1024 * 4);
  ushort* Wt_ni  = (ushort*)alloc(128 * 128 * 2);
  ushort* Wt_nj  = (ushort*)alloc(128 * 128 * 2);
  ushort* Wt_f   = (ushort*)alloc(128 * 128 * 2);
  ushort* Wt_nd  = (ushort*)alloc(128 * 128 * 2);
  // ---- contiguous zero region: cntP, cntR, SnP, SnR, SeP, SeR ----
  size_t zoff0 = off;
  int*    cntP   = (int*)alloc((size_t)N * 4);
  int*    cntR   = (int*)alloc((size_t)N * 4);
  float*  SnP    = (float*)alloc((size_t)G * 128 * 4);
  float*  SnR    = (float*)alloc((size_t)G * 128 * 4);
  float*  SeP    = (float*)alloc((size_t)G * 128 * 4);
  float*  SeR    = (float*)alloc((size_t)G * 128 * 4);
  size_t zoff1 = off;
  float*  Gf     = (float*)alloc((size_t)G * 256 * 4);
  float*  x1     = (float*)alloc((size_t)G * 512 * 4);
  float*  x2     = (float*)alloc((size_t)G * 256 * 4);
  int*    cnt_n  = (int*)alloc((size_t)G * 4);
  int*    cnt_e  = (int*)alloc((size_t)G * 4);
  if (off > ws_size) return;  // graceful fail

  const int EB = (E + 255) / 256;   // 938
  const int NB = (N + 255) / 256;   // 235 <= 256, fits scan_block

  // ---- 1: zero cntP/cntR + all S accumulators in one launch ----
  int n16 = (int)((zoff1 - zoff0) / 16);
  fillz16<<<(n16 + 255) / 256, 256, 0, stream>>>((uint4*)(base + zoff0), n16);

  // ---- 2-6: CSR builds, P and R in parallel grids ----
  hist_dst2<<<2 * EB, 256, 0, stream>>>(dstP, cntP, dstR, cntR, E, EB);
  scan_local2<<<2 * NB, 256, 0, stream>>>(cntP, rowptrP, blocksumP, cntR, rowptrR, blocksumR, N, NB);
  scan_block2<<<2, 256, 0, stream>>>(blocksumP, blocksumR, NB);
  scan_add2<<<2 * NB, 256, 0, stream>>>(rowptrP, cursorP, blocksumP, rowptrR, cursorR, blocksumR, N, E, NB);
  scatter_idx2<<<2 * EB, 256, 0, stream>>>(dstP, srcP, cursorP, epermP, invpermP, srcpermP, dstpermP,
                                           dstR, srcR, cursorR, epermR, invpermR, srcpermR, dstpermR, E, EB);

  // ---- 7: prep egat2 weights ----
  prep_w4<<<4, 256, 0, stream>>>(w2.Wni, w2.Wnj, w2.Wf, w2.Wnode, Wt_ni, Wt_nj, Wt_f, Wt_nd);

  // ---- 8: per-graph counts (node + edge) ----
  const int GB1 = (G + 255) / 256;
  seg_cnt2<<<2 * GB1, 256, 0, stream>>>(nid, N, cnt_n, eid, E, cnt_e, G, GB1);

  const int GB  = (N + 3) / 4;       // gather grids
  const int NBn = (N + 127) / 128;   // segsum node blocks
  const int NBe = (E + 63) / 64;     // segsum edge blocks

  auto layer1 = [&](const float* h, const float* e, const int* eperm,
                    const int* src_perm, const int* rowptr) {
    lin3_small<17><<<(N + 15) / 16, 128, 0, stream>>>(h, w1.Wni, w1.bni, w1.Wnj, w1.bnj,
                                                      w1.Wnode, w1.bnode, f_nin, f_nj, N);
    lin1_perm<15><<<(E + 15) / 16, 128, 0, stream>>>(e, w1.Wf, w1.bf, eperm, ebp, E);
    egat_gather<<<GB, 256, 0, stream>>>(f_nin, f_nj, ebp, src_perm, rowptr, w1.attn, nb, N);
  };
  auto layer2 = [&](const int* src_perm, const int* dst_perm, const int* rowptr) {
    gemm3_k128<<<(N + 127) / 128, 256, 0, stream>>>(nb,
        Wt_ni, w2.bni,   f_nin,       256,
        Wt_nd, w2.bnode, f_nin + 128, 256,
        Wt_nj, w2.bnj,   f_nj,        128, N);
    gemm_edge_fused<<<(E + 63) / 64, 256, 0, stream>>>(ebp, Wt_f, w2.bf, f_nin, f_nj,
                                                       src_perm, dst_perm, w2.attn, ex, E);
    egat_gather2<<<GB, 256, 0, stream>>>(f_nin, ex, src_perm, rowptr, nb, N);
  };

  // ---- P branch ----
  layer1(hP, eP, epermP, srcpermP, rowptrP);
  segsum_both<<<NBn + NBe, 256, 0, stream>>>(nb, nid, N, SnP, ebp, invpermP, eid, E, SeP, NBn);

  // ---- R branch: egat1 + egat2 x2 ----
  layer1(hR, eR, epermR, srcpermR, rowptrR);
  layer2(srcpermR, dstpermR, rowptrR);
  layer2(srcpermR, dstpermR, rowptrR);
  segsum_both<<<NBn + NBe, 256, 0, stream>>>(nb, nid, N, SnR, ebp, invpermR, eid, E, SeR, NBn);

  // ---- Diff aggregate (node + edge in one launch) ----
  diff_linear2<<<2 * G, 128, 0, stream>>>(SnP, SnR, cnt_n, Wa_n, ba_n,
                                          SeP, SeR, cnt_e, Wa_e, ba_e, Gf, G);

  // ---- MLP head ----
  mlp_linear<256, 512, true><<<G, 512, 0, stream>>>(Gf, Wm1, bm1, x1);
  mlp_linear<512, 256, true><<<G, 256, 0, stream>>>(x1, Wm2, bm2, x2);
  mlp_final<<<(G + 255) / 256, 256, 0, stream>>>(x2, Wm3, bm3, (float*)d_out, G);
}

// Round 23
// 583.417 us; speedup vs baseline: 1.1656x; 1.0105x over previous
//
#include <hip/hip_runtime.h>
#include <cstddef>
#include <cstdint>

typedef unsigned int uint;
typedef unsigned short ushort;
typedef __attribute__((ext_vector_type(4))) float f32x4;
typedef __attribute__((ext_vector_type(8))) short short8;

// ---------- bf16 helpers (storage = ushort) ----------
__device__ __forceinline__ ushort f2b(float v) {
  uint x = __float_as_uint(v);
  return (ushort)((x + 0x7fffu + ((x >> 16) & 1u)) >> 16);  // RNE
}
__device__ __forceinline__ float b2f(ushort u) { return __uint_as_float(((uint)u) << 16); }
__device__ __forceinline__ float b2f_lo(uint u) { return __uint_as_float(u << 16); }
__device__ __forceinline__ float b2f_hi(uint u) { return __uint_as_float(u & 0xffff0000u); }
__device__ __forceinline__ uint pk2(float lo, float hi) {
  return (uint)f2b(lo) | ((uint)f2b(hi) << 16);
}
__device__ __forceinline__ uint pkadd(uint a, uint b) {
  return pk2(b2f_lo(a) + b2f_lo(b), b2f_hi(a) + b2f_hi(b));
}

__device__ __forceinline__ int lowerb(const int* __restrict__ ids, int M, int v) {
  int lo = 0, hi = M;
  while (lo < hi) { int mid = (lo + hi) >> 1; if (ids[mid] < v) lo = mid + 1; else hi = mid; }
  return lo;
}

// zero a contiguous 16B-aligned region
__global__ void fillz16(uint4* p, int n16) {
  int i = blockIdx.x * 256 + threadIdx.x;
  if (i < n16) p[i] = make_uint4(0, 0, 0, 0);
}

// ---------- CSR build, P and R merged per phase ----------
__global__ void hist_dst2(const int* __restrict__ dstP, int* __restrict__ cntP,
                          const int* __restrict__ dstR, int* __restrict__ cntR,
                          int E, int EB) {
  int b = blockIdx.x;
  const int* dst; int* cnt;
  if (b < EB) { dst = dstP; cnt = cntP; } else { dst = dstR; cnt = cntR; b -= EB; }
  int e = b * 256 + threadIdx.x;
  if (e < E) atomicAdd(&cnt[dst[e]], 1);
}

__global__ void scan_local2(const int* __restrict__ cntP, int* __restrict__ rowP, int* __restrict__ bsP,
                            const int* __restrict__ cntR, int* __restrict__ rowR, int* __restrict__ bsR,
                            int N, int NB) {
  __shared__ int tmp[256];
  int b = blockIdx.x;
  const int* cnt; int* rowptr; int* bs;
  if (b < NB) { cnt = cntP; rowptr = rowP; bs = bsP; }
  else        { cnt = cntR; rowptr = rowR; bs = bsR; b -= NB; }
  int t = threadIdx.x;
  int i = b * 256 + t;
  int v = (i < N) ? cnt[i] : 0;
  tmp[t] = v;
  __syncthreads();
  for (int ofs = 1; ofs < 256; ofs <<= 1) {
    int u = (t >= ofs) ? tmp[t - ofs] : 0;
    __syncthreads();
    tmp[t] += u;
    __syncthreads();
  }
  if (i < N) rowptr[i] = tmp[t] - v;          // exclusive
  if (t == 255) bs[b] = tmp[255];
}

__global__ void scan_block2(int* __restrict__ bsP, int* __restrict__ bsR, int n) {
  __shared__ int tmp[256];
  int* bs = (blockIdx.x == 0) ? bsP : bsR;
  int t = threadIdx.x;
  int v = (t < n) ? bs[t] : 0;
  tmp[t] = v;
  __syncthreads();
  for (int ofs = 1; ofs < 256; ofs <<= 1) {
    int u = (t >= ofs) ? tmp[t - ofs] : 0;
    __syncthreads();
    tmp[t] += u;
    __syncthreads();
  }
  if (t < n) bs[t] = tmp[t] - v;              // exclusive
}

__global__ void scan_add2(int* __restrict__ rowP, int* __restrict__ curP, const int* __restrict__ bsP,
                          int* __restrict__ rowR, int* __restrict__ curR, const int* __restrict__ bsR,
                          int N, int E, int NB) {
  int b = blockIdx.x;
  int* rowptr; int* cursor; const int* bs;
  if (b < NB) { rowptr = rowP; cursor = curP; bs = bsP; }
  else        { rowptr = rowR; cursor = curR; bs = bsR; b -= NB; }
  int i = b * 256 + threadIdx.x;
  if (i < N) {
    int v = rowptr[i] + bs[b];
    rowptr[i] = v;
    cursor[i] = v;
  }
  if (i == 0) rowptr[N] = E;
}

__global__ void scatter_idx2(
    const int* __restrict__ dstP, const int* __restrict__ srcP, int* __restrict__ curP,
    int* __restrict__ epP, int* __restrict__ ivP, int* __restrict__ spP, int* __restrict__ dpP,
    const int* __restrict__ dstR, const int* __restrict__ srcR, int* __restrict__ curR,
    int* __restrict__ epR, int* __restrict__ ivR, int* __restrict__ spR, int* __restrict__ dpR,
    int E, int EB) {
  int b = blockIdx.x;
  const int *dst, *src; int *cur, *ep, *iv, *sp, *dp;
  if (b < EB) { dst = dstP; src = srcP; cur = curP; ep = epP; iv = ivP; sp = spP; dp = dpP; }
  else { dst = dstR; src = srcR; cur = curR; ep = epR; iv = ivR; sp = spR; dp = dpR; b -= EB; }
  int e = b * 256 + threadIdx.x;
  if (e < E) {
    int d = dst[e];
    int p = atomicAdd(&cur[d], 1);
    ep[p] = e;
    iv[e] = p;
    sp[p] = src[e];
    dp[p] = d;
  }
}

// ---------- prep: 4x W[128][128] fp32 -> transposed, bf16, XOR-swizzled ----------
__global__ void prep_w4(const float* __restrict__ W0, const float* __restrict__ W1,
                        const float* __restrict__ W2, const float* __restrict__ W3,
                        ushort* __restrict__ T0, ushort* __restrict__ T1,
                        ushort* __restrict__ T2, ushort* __restrict__ T3) {
  const float* W = (blockIdx.x == 0) ? W0 : (blockIdx.x == 1) ? W1 : (blockIdx.x == 2) ? W2 : W3;
  ushort* T      = (blockIdx.x == 0) ? T0 : (blockIdx.x == 1) ? T1 : (blockIdx.x == 2) ? T2 : T3;
  int t = threadIdx.x;        // 256 threads
  int n = t >> 1;
  int k0 = (t & 1) * 64;
  uint sw = (uint)(n & 7) << 3;
  for (int kk = 0; kk < 64; ++kk) {
    int k = k0 + kk;
    T[n * 128 + (k ^ sw)] = f2b(W[k * 128 + n]);
  }
}

// ---------- per-graph counts, node+edge merged ----------
__global__ void seg_cnt2(const int* __restrict__ nid, int N, int* __restrict__ cn,
                         const int* __restrict__ eid, int E, int* __restrict__ ce,
                         int G, int GB1) {
  int b = blockIdx.x;
  if (b < GB1) {
    int g = b * 256 + threadIdx.x;
    if (g < G) cn[g] = lowerb(nid, N, g + 1) - lowerb(nid, N, g);
  } else {
    int g = (b - GB1) * 256 + threadIdx.x;
    if (g < G) ce[g] = lowerb(eid, E, g + 1) - lowerb(eid, E, g);
  }
}

// ---------- fused triple GEMM (node linears): stage A once, 3 weights ----------
__global__ __launch_bounds__(256) void gemm3_k128(
    const ushort* __restrict__ X,
    const ushort* __restrict__ Wt0, const float* __restrict__ b0, ushort* __restrict__ Y0, int ldy0,
    const ushort* __restrict__ Wt1, const float* __restrict__ b1, ushort* __restrict__ Y1, int ldy1,
    const ushort* __restrict__ Wt2, const float* __restrict__ b2, ushort* __restrict__ Y2, int ldy2,
    int M) {
  __shared__ ushort As[128 * 128];
  int t = threadIdx.x;
  int row0 = blockIdx.x * 128;

  { // stage A: linear bf16 copy, swizzled store
    int r = t >> 1;
    int k0h = (t & 1) * 64;
    int grow = row0 + r;
    uint sw = (uint)(r & 7) << 3;
    if (grow < M) {
      const ushort* xr = X + (size_t)grow * 128;
#pragma unroll
      for (int c = 0; c < 8; ++c) {
        int k0 = k0h + c * 8;
        *(uint4*)(As + r * 128 + (k0 ^ sw)) = *(const uint4*)(xr + k0);
      }
    } else {
      uint4 z = make_uint4(0, 0, 0, 0);
#pragma unroll
      for (int c = 0; c < 8; ++c) {
        int k0 = k0h + c * 8;
        *(uint4*)(As + r * 128 + (k0 ^ sw)) = z;
      }
    }
  }
  __syncthreads();

  int lane = t & 63;
  int wid = t >> 6;
  int wr = wid >> 1, wc = wid & 1;
  uint swl = (uint)(lane & 7) << 3;

#pragma unroll
  for (int w = 0; w < 3; ++w) {
    const ushort* Wt = (w == 0) ? Wt0 : (w == 1) ? Wt1 : Wt2;
    const float* bb  = (w == 0) ? b0  : (w == 1) ? b1  : b2;
    ushort* Y        = (w == 0) ? Y0  : (w == 1) ? Y1  : Y2;
    int ldy          = (w == 0) ? ldy0 : (w == 1) ? ldy1 : ldy2;

    f32x4 acc[4][4];
#pragma unroll
    for (int n4 = 0; n4 < 4; ++n4) {
      float bv = bb[wc * 64 + n4 * 16 + (lane & 15)];
#pragma unroll
      for (int m4 = 0; m4 < 4; ++m4) acc[m4][n4] = (f32x4){bv, bv, bv, bv};
    }
#pragma unroll
    for (int kk = 0; kk < 4; ++kk) {
      int kidx = kk * 32 + 8 * (lane >> 4);
      short8 af[4], bfr[4];
#pragma unroll
      for (int m4 = 0; m4 < 4; ++m4) {
        int rm = wr * 64 + m4 * 16 + (lane & 15);
        af[m4] = *(const short8*)(As + rm * 128 + (kidx ^ swl));
      }
#pragma unroll
      for (int n4 = 0; n4 < 4; ++n4) {
        int cn = wc * 64 + n4 * 16 + (lane & 15);
        bfr[n4] = *(const short8*)(Wt + cn * 128 + (kidx ^ swl));   // direct from L2
      }
#pragma unroll
      for (int m4 = 0; m4 < 4; ++m4)
#pragma unroll
        for (int n4 = 0; n4 < 4; ++n4)
          acc[m4][n4] = __builtin_amdgcn_mfma_f32_16x16x32_bf16(af[m4], bfr[n4], acc[m4][n4], 0, 0, 0);
    }
    int coln = wc * 64 + (lane & 15);
#pragma unroll
    for (int m4 = 0; m4 < 4; ++m4) {
      int rb = row0 + wr * 64 + m4 * 16 + ((lane >> 4) << 2);
#pragma unroll
      for (int n4 = 0; n4 < 4; ++n4) {
        int cc = coln + n4 * 16;
#pragma unroll
        for (int i = 0; i < 4; ++i)
          if (rb + i < M) Y[(size_t)(rb + i) * ldy + cc] = f2b(acc[m4][n4][i]);
      }
    }
  }
}

// ---------- fused edge GEMM + edge-stage (egat2), LDS time-shared ----------
static constexpr int NST = 132;
__global__ __launch_bounds__(256) void gemm_edge_fused(
    ushort* ebp, const ushort* __restrict__ Wt, const float* __restrict__ b,
    const ushort* __restrict__ f_nin, const ushort* __restrict__ f_nj,
    const int* __restrict__ src_perm, const int* __restrict__ dst_perm,
    const float* __restrict__ attn, float* __restrict__ ex, int E) {
  __shared__ ushort Buf[64 * NST];   // 16.9 KB, As then NN
  int t = threadIdx.x;
  int row0 = blockIdx.x * 64;
  int r = t >> 2, q = t & 3;
  int grow_st = row0 + r;
  uint sw = (uint)(r & 7) << 3;

  // issue phase-B gather loads EARLY (hide latency under As stage + MFMA)
  uint4 ua[4], ub[4];
  if (grow_st < E) {
    int s = src_perm[grow_st], d = dst_perm[grow_st];
    const ushort* nir = f_nin + (size_t)s * 256;
    const ushort* njr = f_nj + (size_t)d * 128;
#pragma unroll
    for (int c = 0; c < 4; ++c) {
      int k0 = q * 32 + c * 8;
      ua[c] = *(const uint4*)(nir + k0);
      ub[c] = *(const uint4*)(njr + k0);
    }
  }

  { // phase A: stage As (swizzled, stride 128)
    if (grow_st < E) {
      const ushort* xr = ebp + (size_t)grow_st * 128;
#pragma unroll
      for (int c = 0; c < 4; ++c) {
        int k0 = q * 32 + c * 8;
        *(uint4*)(Buf + r * 128 + (k0 ^ sw)) = *(const uint4*)(xr + k0);
      }
    } else {
      uint4 z = make_uint4(0, 0, 0, 0);
#pragma unroll
      for (int c = 0; c < 4; ++c) {
        int k0 = q * 32 + c * 8;
        *(uint4*)(Buf + r * 128 + (k0 ^ sw)) = z;
      }
    }
  }
  __syncthreads();

  int lane = t & 63;
  int wid = t >> 6;
  int wr = wid >> 1, wc = wid & 1;     // 2x2 waves of 32 rows x 64 cols
  uint swl = (uint)(lane & 7) << 3;

  f32x4 acc[2][4];
#pragma unroll
  for (int n4 = 0; n4 < 4; ++n4) {
    float bv = b[wc * 64 + n4 * 16 + (lane & 15)];
#pragma unroll
    for (int m4 = 0; m4 < 2; ++m4) acc[m4][n4] = (f32x4){bv, bv, bv, bv};
  }
#pragma unroll
  for (int kk = 0; kk < 4; ++kk) {
    int kidx = kk * 32 + 8 * (lane >> 4);
    short8 af[2], bfr[4];
#pragma unroll
    for (int m4 = 0; m4 < 2; ++m4) {
      int rm = wr * 32 + m4 * 16 + (lane & 15);
      af[m4] = *(const short8*)(Buf + rm * 128 + (kidx ^ swl));
    }
#pragma unroll
    for (int n4 = 0; n4 < 4; ++n4) {
      int cn = wc * 64 + n4 * 16 + (lane & 15);
      bfr[n4] = *(const short8*)(Wt + cn * 128 + (kidx ^ swl));   // direct from L2
    }
#pragma unroll
    for (int m4 = 0; m4 < 2; ++m4)
#pragma unroll
      for (int n4 = 0; n4 < 4; ++n4)
        acc[m4][n4] = __builtin_amdgcn_mfma_f32_16x16x32_bf16(af[m4], bfr[n4], acc[m4][n4], 0, 0, 0);
  }
  __syncthreads();                      // As reads done

  { // phase B (write-late): NN = bf16(ni+nj) from prefetched regs, stride NST
    if (grow_st < E) {
#pragma unroll
      for (int c = 0; c < 4; ++c) {
        int k0 = q * 32 + c * 8;
        uint4 o;
        o.x = pkadd(ua[c].x, ub[c].x); o.y = pkadd(ua[c].y, ub[c].y);
        o.z = pkadd(ua[c].z, ub[c].z); o.w = pkadd(ua[c].w, ub[c].w);
        *(uint4*)(Buf + r * NST + k0) = o;
      }
    }
  }
  __syncthreads();

  float at4[4];
#pragma unroll
  for (int n4 = 0; n4 < 4; ++n4) at4[n4] = attn[wc * 64 + n4 * 16 + (lane & 15)];

#pragma unroll
  for (int m4 = 0; m4 < 2; ++m4) {
#pragma unroll
    for (int i = 0; i < 4; ++i) {
      int row = wr * 32 + m4 * 16 + ((lane >> 4) << 2) + i;
      int grow = row0 + row;
      float ph0 = 0.f, ph1 = 0.f;
      if (grow < E) {
#pragma unroll
        for (int n4 = 0; n4 < 4; ++n4) {
          int col = wc * 64 + n4 * 16 + (lane & 15);
          float v = acc[m4][n4][i] + b2f(Buf[row * NST + col]);
          v = v >= 0.f ? v : 0.01f * v;
          ebp[(size_t)grow * 128 + col] = f2b(v);
          float p = v * at4[n4];
          if (n4 < 2) ph0 += p; else ph1 += p;
        }
      }
      ph0 += __shfl_xor(ph0, 1); ph0 += __shfl_xor(ph0, 2);
      ph0 += __shfl_xor(ph0, 4); ph0 += __shfl_xor(ph0, 8);
      ph1 += __shfl_xor(ph1, 1); ph1 += __shfl_xor(ph1, 2);
      ph1 += __shfl_xor(ph1, 4); ph1 += __shfl_xor(ph1, 8);
      if ((lane & 15) == 0 && grow < E) {
        ex[(size_t)grow * 4 + wc * 2 + 0] = __expf(ph0);
        ex[(size_t)grow * 4 + wc * 2 + 1] = __expf(ph1);
      }
    }
  }
}

// ---------- layer-1 fused node linears (R15-proven) ----------
template<int K>
__global__ __launch_bounds__(128) void lin3_small(const float* __restrict__ X,
    const float* __restrict__ W1, const float* __restrict__ b1,
    const float* __restrict__ W2, const float* __restrict__ b2,
    const float* __restrict__ W3, const float* __restrict__ b3,
    ushort* __restrict__ Ynin, ushort* __restrict__ Ynj, int M) {
  constexpr int ROWS = 16;
  __shared__ float xs[ROWS * K];
  int t = threadIdx.x;
  int row0 = blockIdx.x * ROWS;
  int nr = M - row0; if (nr > ROWS) nr = ROWS;
  for (int i = t; i < nr * K; i += 128) xs[i] = X[(size_t)row0 * K + i];
  __syncthreads();
  float a1[ROWS], a2[ROWS], a3[ROWS];
  float v1 = b1[t], v2 = b2[t], v3 = b3[t];
#pragma unroll
  for (int r = 0; r < ROWS; ++r) { a1[r] = v1; a2[r] = v2; a3[r] = v3; }
#pragma unroll
  for (int k = 0; k < K; ++k) {
    float w1 = W1[k * 128 + t], w2 = W2[k * 128 + t], w3 = W3[k * 128 + t];
#pragma unroll
    for (int r = 0; r < ROWS; ++r) {
      float x = xs[r * K + k];
      a1[r] = fmaf(x, w1, a1[r]);
      a2[r] = fmaf(x, w2, a2[r]);
      a3[r] = fmaf(x, w3, a3[r]);
    }
  }
  for (int r = 0; r < nr; ++r) {
    size_t n = (size_t)(row0 + r);
    Ynin[n * 256 + t] = f2b(a1[r]);        // f_ni
    Ynin[n * 256 + 128 + t] = f2b(a3[r]);  // f_node
    Ynj[n * 128 + t] = f2b(a2[r]);
  }
}

// ---------- layer-1 edge linear (K=15), perm order (R15-proven) ----------
template<int K>
__global__ __launch_bounds__(128) void lin1_perm(const float* __restrict__ X,
    const float* __restrict__ W, const float* __restrict__ b,
    const int* __restrict__ eperm, ushort* __restrict__ Y, int M) {
  constexpr int ROWS = 16;
  __shared__ float xs[ROWS * K];
  __shared__ int es[ROWS];
  int t = threadIdx.x;
  int row0 = blockIdx.x * ROWS;
  int nr = M - row0; if (nr > ROWS) nr = ROWS;
  if (t < nr) es[t] = eperm[row0 + t];
  __syncthreads();
  for (int i = t; i < nr * K; i += 128) {
    int r = i / K, c = i - r * K;
    xs[i] = X[(size_t)es[r] * K + c];
  }
  __syncthreads();
  float acc[ROWS];
  float bias = b[t];
#pragma unroll
  for (int r = 0; r < ROWS; ++r) acc[r] = bias;
#pragma unroll
  for (int k = 0; k < K; ++k) {
    float w = W[k * 128 + t];
#pragma unroll
    for (int r = 0; r < ROWS; ++r) acc[r] = fmaf(xs[r * K + k], w, acc[r]);
  }
  for (int r = 0; r < nr; ++r) Y[(size_t)(row0 + r) * 128 + t] = f2b(acc[r]);
}

// ---------- layer-1 fused edge+aggregate (CSR over dst), 4-edge pipelined ----------
__global__ void egat_gather(const ushort* __restrict__ f_nin,   // [N][256] = ni | node
                            const ushort* __restrict__ f_nj,    // [N][128]
                            ushort* ebp,                         // [E][128] perm order, in/out
                            const int* __restrict__ src_perm,
                            const int* __restrict__ rowptr,
                            const float* __restrict__ attn,
                            ushort* __restrict__ nb, int N) {
  int d = blockIdx.x * 4 + (threadIdx.x >> 6);
  if (d >= N) return;
  int lane = threadIdx.x & 63;
  int lo = rowptr[d], hi = rowptr[d + 1];
  int h = lane >> 4;
  float2 at = *(const float2*)(attn + h * 32 + (lane & 15) * 2);
  uint unj = *((const uint*)(f_nj + (size_t)d * 128) + lane);
  float nj0 = b2f_lo(unj), nj1 = b2f_hi(unj);
  float acc0 = 0.f, acc1 = 0.f, exsum = 0.f;

  int i = lo;
  for (; i + 3 < hi; i += 4) {
    // issue all 4 edges' loads up front (4x memory-level parallelism)
    uint uni[4], und[4], ue[4];
    uint* ep[4];
#pragma unroll
    for (int j = 0; j < 4; ++j) {
      int s = src_perm[i + j];
      const uint* pn = (const uint*)(f_nin + (size_t)s * 256);
      uni[j] = pn[lane];
      und[j] = pn[64 + lane];
      ep[j] = (uint*)(ebp + (size_t)(i + j) * 128) + lane;
      ue[j] = *ep[j];
    }
#pragma unroll
    for (int j = 0; j < 4; ++j) {
      float v0 = b2f_lo(ue[j]) + b2f_lo(uni[j]) + nj0;
      float v1 = b2f_hi(ue[j]) + b2f_hi(uni[j]) + nj1;
      v0 = v0 >= 0.f ? v0 : 0.01f * v0;
      v1 = v1 >= 0.f ? v1 : 0.01f * v1;
      *ep[j] = pk2(v0, v1);
      float p = v0 * at.x + v1 * at.y;
      p += __shfl_xor(p, 1); p += __shfl_xor(p, 2);
      p += __shfl_xor(p, 4); p += __shfl_xor(p, 8);
      float ev = __expf(p);
      exsum += ev;
      acc0 = fmaf(b2f_lo(und[j]), ev, acc0);
      acc1 = fmaf(b2f_hi(und[j]), ev, acc1);
    }
  }
  for (; i + 1 < hi; i += 2) {
    int s0 = src_perm[i], s1 = src_perm[i + 1];
    const uint* pn0 = (const uint*)(f_nin + (size_t)s0 * 256);
    const uint* pn1 = (const uint*)(f_nin + (size_t)s1 * 256);
    uint uniA = pn0[lane];
    uint undA = pn0[64 + lane];
    uint uniB = pn1[lane];
    uint undB = pn1[64 + lane];
    uint* epA = (uint*)(ebp + (size_t)i * 128) + lane;
    uint* epB = (uint*)(ebp + (size_t)(i + 1) * 128) + lane;
    uint ueA = *epA;
    uint ueB = *epB;

    float v0 = b2f_lo(ueA) + b2f_lo(uniA) + nj0;
    float v1 = b2f_hi(ueA) + b2f_hi(uniA) + nj1;
    v0 = v0 >= 0.f ? v0 : 0.01f * v0;
    v1 = v1 >= 0.f ? v1 : 0.01f * v1;
    *epA = pk2(v0, v1);
    float p = v0 * at.x + v1 * at.y;
    p += __shfl_xor(p, 1); p += __shfl_xor(p, 2);
    p += __shfl_xor(p, 4); p += __shfl_xor(p, 8);
    float ev = __expf(p);
    exsum += ev;
    acc0 = fmaf(b2f_lo(undA), ev, acc0);
    acc1 = fmaf(b2f_hi(undA), ev, acc1);

    v0 = b2f_lo(ueB) + b2f_lo(uniB) + nj0;
    v1 = b2f_hi(ueB) + b2f_hi(uniB) + nj1;
    v0 = v0 >= 0.f ? v0 : 0.01f * v0;
    v1 = v1 >= 0.f ? v1 : 0.01f * v1;
    *epB = pk2(v0, v1);
    p = v0 * at.x + v1 * at.y;
    p += __shfl_xor(p, 1); p += __shfl_xor(p, 2);
    p += __shfl_xor(p, 4); p += __shfl_xor(p, 8);
    ev = __expf(p);
    exsum += ev;
    acc0 = fmaf(b2f_lo(undB), ev, acc0);
    acc1 = fmaf(b2f_hi(undB), ev, acc1);
  }
  if (i < hi) {
    int s = src_perm[i];
    const uint* pn = (const uint*)(f_nin + (size_t)s * 256);
    uint uni = pn[lane];
    uint und = pn[64 + lane];
    uint* ep = (uint*)(ebp + (size_t)i * 128) + lane;
    uint ue = *ep;
    float v0 = b2f_lo(ue) + b2f_lo(uni) + nj0;
    float v1 = b2f_hi(ue) + b2f_hi(uni) + nj1;
    v0 = v0 >= 0.f ? v0 : 0.01f * v0;
    v1 = v1 >= 0.f ? v1 : 0.01f * v1;
    *ep = pk2(v0, v1);
    float p = v0 * at.x + v1 * at.y;
    p += __shfl_xor(p, 1); p += __shfl_xor(p, 2);
    p += __shfl_xor(p, 4); p += __shfl_xor(p, 8);
    float ev = __expf(p);
    exsum += ev;
    acc0 = fmaf(b2f_lo(und), ev, acc0);
    acc1 = fmaf(b2f_hi(und), ev, acc1);
  }
  float inv = exsum > 0.f ? 1.f / exsum : 0.f;
  ((uint*)(nb + (size_t)d * 128))[lane] = pk2(acc0 * inv, acc1 * inv);
}

// ---------- light per-node combine (egat2), 4-edge pipelined ----------
__global__ void egat_gather2(const ushort* __restrict__ f_nin,
                             const float* __restrict__ ex,
                             const int* __restrict__ src_perm,
                             const int* __restrict__ rowptr,
                             ushort* __restrict__ nb, int N) {
  int d = blockIdx.x * 4 + (threadIdx.x >> 6);
  if (d >= N) return;
  int lane = threadIdx.x & 63;
  int lo = rowptr[d], hi = rowptr[d + 1];
  int h = lane >> 4;
  float acc0 = 0.f, acc1 = 0.f, exsum = 0.f;

  int i = lo;
  for (; i + 3 < hi; i += 4) {
    float ev[4];
    uint und[4];
#pragma unroll
    for (int j = 0; j < 4; ++j) {
      ev[j] = ex[(size_t)(i + j) * 4 + h];
      int s = src_perm[i + j];
      und[j] = *((const uint*)(f_nin + (size_t)s * 256 + 128) + lane);
    }
#pragma unroll
    for (int j = 0; j < 4; ++j) {
      exsum += ev[j];
      acc0 = fmaf(b2f_lo(und[j]), ev[j], acc0);
      acc1 = fmaf(b2f_hi(und[j]), ev[j], acc1);
    }
  }
  for (; i + 1 < hi; i += 2) {
    float evA = ex[(size_t)i * 4 + h];
    float evB = ex[(size_t)(i + 1) * 4 + h];
    int s0 = src_perm[i], s1 = src_perm[i + 1];
    uint undA = *((const uint*)(f_nin + (size_t)s0 * 256 + 128) + lane);
    uint undB = *((const uint*)(f_nin + (size_t)s1 * 256 + 128) + lane);
    exsum += evA;
    acc0 = fmaf(b2f_lo(undA), evA, acc0);
    acc1 = fmaf(b2f_hi(undA), evA, acc1);
    exsum += evB;
    acc0 = fmaf(b2f_lo(undB), evB, acc0);
    acc1 = fmaf(b2f_hi(undB), evB, acc1);
  }
  if (i < hi) {
    float ev = ex[(size_t)i * 4 + h];
    int s = src_perm[i];
    uint und = *((const uint*)(f_nin + (size_t)s * 256 + 128) + lane);
    exsum += ev;
    acc0 = fmaf(b2f_lo(und), ev, acc0);
    acc1 = fmaf(b2f_hi(und), ev, acc1);
  }
  float inv = exsum > 0.f ? 1.f / exsum : 0.f;
  ((uint*)(nb + (size_t)d * 128))[lane] = pk2(acc0 * inv, acc1 * inv);
}

// ---------- node segsum (seq) + edge segsum (invperm gather), MERGED ----------
__global__ __launch_bounds__(256) void segsum_both(
    const ushort* __restrict__ nbX, const int* __restrict__ nid, int N, float* __restrict__ Sn,
    const ushort* __restrict__ ebX, const int* __restrict__ invperm,
    const int* __restrict__ eid, int E, float* __restrict__ Se, int NBn) {
  int t = threadIdx.x & 63;
  int wv = threadIdx.x >> 6;
  if ((int)blockIdx.x < NBn) {
    int r0 = (blockIdx.x * 4 + wv) * 32;
    if (r0 >= N) return;
    int r1 = r0 + 32; if (r1 > N) r1 = N;
    float a0 = 0.f, a1 = 0.f;
    int cur = nid[r0];
    for (int r = r0; r < r1; ++r) {
      int id = nid[r];
      if (id != cur) {
        atomicAdd(&Sn[(size_t)cur * 128 + 2 * t], a0);
        atomicAdd(&Sn[(size_t)cur * 128 + 2 * t + 1], a1);
        a0 = a1 = 0.f; cur = id;
      }
      uint u = *((const uint*)(nbX + (size_t)r * 128) + t);
      a0 += b2f_lo(u); a1 += b2f_hi(u);
    }
    atomicAdd(&Sn[(size_t)cur * 128 + 2 * t], a0);
    atomicAdd(&Sn[(size_t)cur * 128 + 2 * t + 1], a1);
  } else {
    int b = blockIdx.x - NBn;
    int r0 = (b * 4 + wv) * 16;
    if (r0 >= E) return;
    int r1 = r0 + 16; if (r1 > E) r1 = E;
    float a0 = 0.f, a1 = 0.f;
    int cur = eid[r0];
    for (int r = r0; r < r1; ++r) {
      int id = eid[r];
      if (id != cur) {
        atomicAdd(&Se[(size_t)cur * 128 + 2 * t], a0);
        atomicAdd(&Se[(size_t)cur * 128 + 2 * t + 1], a1);
        a0 = a1 = 0.f; cur = id;
      }
      uint u = *((const uint*)(ebX + (size_t)invperm[r] * 128) + t);
      a0 += b2f_lo(u); a1 += b2f_hi(u);
    }
    atomicAdd(&Se[(size_t)cur * 128 + 2 * t], a0);
    atomicAdd(&Se[(size_t)cur * 128 + 2 * t + 1], a1);
  }
}

// ---------- diff linears, node+edge MERGED: out[g] = (SP-SR)@W + cnt*b ----------
__global__ void diff_linear2(const float* __restrict__ SnP, const float* __restrict__ SnR,
                             const int* __restrict__ cn,
                             const float* __restrict__ Wn, const float* __restrict__ bn,
                             const float* __restrict__ SeP, const float* __restrict__ SeR,
                             const int* __restrict__ ce,
                             const float* __restrict__ We, const float* __restrict__ be,
                             float* __restrict__ out, int G) {
  int g = blockIdx.x;
  int t = threadIdx.x;
  bool is_e = g >= G; if (is_e) g -= G;
  const float* SP = is_e ? SeP : SnP;
  const float* SR = is_e ? SeR : SnR;
  const int* cnt  = is_e ? ce  : cn;
  const float* W  = is_e ? We  : Wn;
  const float* b  = is_e ? be  : bn;
  int coloff = is_e ? 128 : 0;
  __shared__ float xs[128];
  xs[t] = SP[(size_t)g * 128 + t] - SR[(size_t)g * 128 + t];
  __syncthreads();
  float acc = (float)cnt[g] * b[t];
  for (int k = 0; k < 128; ++k) acc = fmaf(xs[k], W[k * 128 + t], acc);
  out[(size_t)g * 256 + coloff + t] = acc;
}

template<int K, int NC, bool RELU>
__global__ void mlp_linear(const float* __restrict__ X, const float* __restrict__ W,
                           const float* __restrict__ b, float* __restrict__ Y) {
  int g = blockIdx.x;
  int t = threadIdx.x;
  __shared__ float xs[K];
  for (int i = t; i < K; i += NC) xs[i] = X[(size_t)g * K + i];
  __syncthreads();
  float acc = b[t];
  for (int k = 0; k < K; ++k) acc = fmaf(xs[k], W[k * NC + t], acc);
  if (RELU) acc = fmaxf(acc, 0.f);
  Y[(size_t)g * NC + t] = acc;
}

__global__ void mlp_final(const float* __restrict__ X, const float* __restrict__ W,
                          const float* __restrict__ b, float* __restrict__ out, int G) {
  int g = blockIdx.x * blockDim.x + threadIdx.x;
  if (g >= G) return;
  float acc = b[0];
  for (int k = 0; k < 256; ++k) acc = fmaf(X[(size_t)g * 256 + k], W[k], acc);
  out[g] = acc;
}

struct LayerW {
  const float *Wni, *bni, *Wnj, *bnj, *Wf, *bf, *Wnode, *bnode, *attn;
};

extern "C" void kernel_launch(void* const* d_in, const int* in_sizes, int n_in,
                              void* d_out, int out_size, void* d_ws, size_t ws_size,
                              hipStream_t stream) {
  const float* hR = (const float*)d_in[0];
  const float* eR = (const float*)d_in[1];
  const float* hP = (const float*)d_in[2];
  const float* eP = (const float*)d_in[3];
  const int* srcR = (const int*)d_in[4];
  const int* dstR = (const int*)d_in[5];
  const int* srcP = (const int*)d_in[6];
  const int* dstP = (const int*)d_in[7];
  const int* nid  = (const int*)d_in[8];
  const int* eid  = (const int*)d_in[9];
  LayerW w1 { (const float*)d_in[10], (const float*)d_in[11], (const float*)d_in[12],
              (const float*)d_in[13], (const float*)d_in[14], (const float*)d_in[15],
              (const float*)d_in[16], (const float*)d_in[17], (const float*)d_in[18] };
  LayerW w2 { (const float*)d_in[19], (const float*)d_in[20], (const float*)d_in[21],
              (const float*)d_in[22], (const float*)d_in[23], (const float*)d_in[24],
              (const float*)d_in[25], (const float*)d_in[26], (const float*)d_in[27] };
  const float* Wa_n = (const float*)d_in[28];
  const float* ba_n = (const float*)d_in[29];
  const float* Wa_e = (const float*)d_in[30];
  const float* ba_e = (const float*)d_in[31];
  const float* Wm1  = (const float*)d_in[32];
  const float* bm1  = (const float*)d_in[33];
  const float* Wm2  = (const float*)d_in[34];
  const float* bm2  = (const float*)d_in[35];
  const float* Wm3  = (const float*)d_in[36];
  const float* bm3  = (const float*)d_in[37];

  const int N = in_sizes[0] / 17;   // 60000
  const int E = in_sizes[4];        // 240000
  const int G = out_size;           // 1024

  // ---- workspace carve-up ----
  char* base = (char*)d_ws;
  size_t off = 0;
  auto alloc = [&](size_t bytes) { char* p = base + off; off += (bytes + 255) & ~(size_t)255; return p; };
  ushort* nb     = (ushort*)alloc((size_t)N * 128 * 2);   // node state bf16
  ushort* f_nin  = (ushort*)alloc((size_t)N * 256 * 2);   // [ni | node] fused rows
  ushort* f_nj   = (ushort*)alloc((size_t)N * 128 * 2);
  ushort* ebp    = (ushort*)alloc((size_t)E * 128 * 2);   // edge state bf16, dst-CSR order
  float*  ex     = (float*)alloc((size_t)E * 4 * 4);      // per-edge exp(logit), egat2 path
  int*    rowptrP = (int*)alloc((size_t)(N + 1) * 4);
  int*    rowptrR = (int*)alloc((size_t)(N + 1) * 4);
  int*    epermP  = (int*)alloc((size_t)E * 4);
  int*    epermR  = (int*)alloc((size_t)E * 4);
  int*    invpermP = (int*)alloc((size_t)E * 4);
  int*    invpermR = (int*)alloc((size_t)E * 4);
  int*    srcpermP = (int*)alloc((size_t)E * 4);
  int*    srcpermR = (int*)alloc((size_t)E * 4);
  int*    dstpermP = (int*)alloc((size_t)E * 4);
  int*    dstpermR = (int*)alloc((size_t)E * 4);
  int*    cursorP = (int*)alloc((size_t)N * 4);
  int*    cursorR = (int*)alloc((size_t)N * 4);
  int*    blocksumP = (int*)alloc(1024 * 4);
  int*    blocksumR = (int*)alloc(1024 * 4);
  ushort* Wt_ni  = (ushort*)alloc(128 * 128 * 2);
  ushort* Wt_nj  = (ushort*)alloc(128 * 128 * 2);
  ushort* Wt_f   = (ushort*)alloc(128 * 128 * 2);
  ushort* Wt_nd  = (ushort*)alloc(128 * 128 * 2);
  // ---- contiguous zero region: cntP, cntR, SnP, SnR, SeP, SeR ----
  size_t zoff0 = off;
  int*    cntP   = (int*)alloc((size_t)N * 4);
  int*    cntR   = (int*)alloc((size_t)N * 4);
  float*  SnP    = (float*)alloc((size_t)G * 128 * 4);
  float*  SnR    = (float*)alloc((size_t)G * 128 * 4);
  float*  SeP    = (float*)alloc((size_t)G * 128 * 4);
  float*  SeR    = (float*)alloc((size_t)G * 128 * 4);
  size_t zoff1 = off;
  float*  Gf     = (float*)alloc((size_t)G * 256 * 4);
  float*  x1     = (float*)alloc((size_t)G * 512 * 4);
  float*  x2     = (float*)alloc((size_t)G * 256 * 4);
  int*    cnt_n  = (int*)alloc((size_t)G * 4);
  int*    cnt_e  = (int*)alloc((size_t)G * 4);
  if (off > ws_size) return;  // graceful fail

  const int EB = (E + 255) / 256;   // 938
  const int NB = (N + 255) / 256;   // 235 <= 256, fits scan_block

  // ---- 1: zero cntP/cntR + all S accumulators in one launch ----
  int n16 = (int)((zoff1 - zoff0) / 16);
  fillz16<<<(n16 + 255) / 256, 256, 0, stream>>>((uint4*)(base + zoff0), n16);

  // ---- 2-6: CSR builds, P and R in parallel grids ----
  hist_dst2<<<2 * EB, 256, 0, stream>>>(dstP, cntP, dstR, cntR, E, EB);
  scan_local2<<<2 * NB, 256, 0, stream>>>(cntP, rowptrP, blocksumP, cntR, rowptrR, blocksumR, N, NB);
  scan_block2<<<2, 256, 0, stream>>>(blocksumP, blocksumR, NB);
  scan_add2<<<2 * NB, 256, 0, stream>>>(rowptrP, cursorP, blocksumP, rowptrR, cursorR, blocksumR, N, E, NB);
  scatter_idx2<<<2 * EB, 256, 0, stream>>>(dstP, srcP, cursorP, epermP, invpermP, srcpermP, dstpermP,
                                           dstR, srcR, cursorR, epermR, invpermR, srcpermR, dstpermR, E, EB);

  // ---- 7: prep egat2 weights ----
  prep_w4<<<4, 256, 0, stream>>>(w2.Wni, w2.Wnj, w2.Wf, w2.Wnode, Wt_ni, Wt_nj, Wt_f, Wt_nd);

  // ---- 8: per-graph counts (node + edge) ----
  const int GB1 = (G + 255) / 256;
  seg_cnt2<<<2 * GB1, 256, 0, stream>>>(nid, N, cnt_n, eid, E, cnt_e, G, GB1);

  const int GB  = (N + 3) / 4;       // gather grids
  const int NBn = (N + 127) / 128;   // segsum node blocks
  const int NBe = (E + 63) / 64;     // segsum edge blocks

  auto layer1 = [&](const float* h, const float* e, const int* eperm,
                    const int* src_perm, const int* rowptr) {
    lin3_small<17><<<(N + 15) / 16, 128, 0, stream>>>(h, w1.Wni, w1.bni, w1.Wnj, w1.bnj,
                                                      w1.Wnode, w1.bnode, f_nin, f_nj, N);
    lin1_perm<15><<<(E + 15) / 16, 128, 0, stream>>>(e, w1.Wf, w1.bf, eperm, ebp, E);
    egat_gather<<<GB, 256, 0, stream>>>(f_nin, f_nj, ebp, src_perm, rowptr, w1.attn, nb, N);
  };
  auto layer2 = [&](const int* src_perm, const int* dst_perm, const int* rowptr) {
    gemm3_k128<<<(N + 127) / 128, 256, 0, stream>>>(nb,
        Wt_ni, w2.bni,   f_nin,       256,
        Wt_nd, w2.bnode, f_nin + 128, 256,
        Wt_nj, w2.bnj,   f_nj,        128, N);
    gemm_edge_fused<<<(E + 63) / 64, 256, 0, stream>>>(ebp, Wt_f, w2.bf, f_nin, f_nj,
                                                       src_perm, dst_perm, w2.attn, ex, E);
    egat_gather2<<<GB, 256, 0, stream>>>(f_nin, ex, src_perm, rowptr, nb, N);
  };

  // ---- P branch ----
  layer1(hP, eP, epermP, srcpermP, rowptrP);
  segsum_both<<<NBn + NBe, 256, 0, stream>>>(nb, nid, N, SnP, ebp, invpermP, eid, E, SeP, NBn);

  // ---- R branch: egat1 + egat2 x2 ----
  layer1(hR, eR, epermR, srcpermR, rowptrR);
  layer2(srcpermR, dstpermR, rowptrR);
  layer2(srcpermR, dstpermR, rowptrR);
  segsum_both<<<NBn + NBe, 256, 0, stream>>>(nb, nid, N, SnR, ebp, invpermR, eid, E, SeR, NBn);

  // ---- Diff aggregate (node + edge in one launch) ----
  diff_linear2<<<2 * G, 128, 0, stream>>>(SnP, SnR, cnt_n, Wa_n, ba_n,
                                          SeP, SeR, cnt_e, Wa_e, ba_e, Gf, G);

  // ---- MLP head ----
  mlp_linear<256, 512, true><<<G, 512, 0, stream>>>(Gf, Wm1, bm1, x1);
  mlp_linear<512, 256, true><<<G, 256, 0, stream>>>(x1, Wm2, bm2, x2);
  mlp_final<<<(G + 255) / 256, 256, 0, stream>>>(x2, Wm3, bm3, (float*)d_out, G);
}